// Round 1
// baseline (3872.856 us; speedup 1.0000x reference)
//
#include <hip/hip_runtime.h>
#include <math.h>

#define LRELU_ATT 0.2f
#define LRELU_ACT 0.01f

__device__ __forceinline__ float lrelu(float x, float s) { return x > 0.f ? x : x * s; }

__device__ __forceinline__ void atomicMaxF(float* addr, float val) {
    int* ai = (int*)addr;
    int old = *(volatile int*)ai;
    while (__int_as_float(old) < val) {
        int assumed = old;
        old = atomicCAS(ai, assumed, __float_as_int(val));
        if (old == assumed) break;
    }
}

// ---------------- GEMM: Hout[n,128] = X[n,128] @ W[128,128] (fp32) ----------------
// 32 rows/block, W fully in LDS, X tile padded (stride 132) for bank-conflict-free
// scalar row reads. Thread tile: 1 row x 16 cols as 4x float4 at col stride 32 so
// each wave's ds_read_b128 covers all 32 banks exactly once.
__global__ __launch_bounds__(256) void gemm_k(const float* __restrict__ X,
                                              const float* __restrict__ Wm,
                                              float* __restrict__ Hout, int n) {
    __shared__ float sW[128 * 128];
    __shared__ float sX[32 * 132];
    for (int i = threadIdx.x * 4; i < 128 * 128; i += 1024)
        *(float4*)&sW[i] = *(const float4*)&Wm[i];
    int row0 = blockIdx.x * 32;
    for (int i = threadIdx.x * 4; i < 32 * 128; i += 1024) {
        int r = i >> 7, c = i & 127;
        int gr = row0 + r;
        float4 v = make_float4(0.f, 0.f, 0.f, 0.f);
        if (gr < n) v = *(const float4*)&X[gr * 128 + c];
        *(float4*)&sX[r * 132 + c] = v;
    }
    __syncthreads();
    int r = threadIdx.x >> 3;
    int c0 = (threadIdx.x & 7) * 4;
    float4 acc[4];
#pragma unroll
    for (int i = 0; i < 4; i++) acc[i] = make_float4(0.f, 0.f, 0.f, 0.f);
    const float* xr = &sX[r * 132];
#pragma unroll 2
    for (int k = 0; k < 128; k++) {
        float xv = xr[k];
#pragma unroll
        for (int i = 0; i < 4; i++) {
            float4 w = *(const float4*)&sW[k * 128 + c0 + 32 * i];
            acc[i].x = fmaf(xv, w.x, acc[i].x);
            acc[i].y = fmaf(xv, w.y, acc[i].y);
            acc[i].z = fmaf(xv, w.z, acc[i].z);
            acc[i].w = fmaf(xv, w.w, acc[i].w);
        }
    }
    int gr = row0 + r;
    if (gr < n) {
#pragma unroll
        for (int i = 0; i < 4; i++)
            *(float4*)&Hout[gr * 128 + c0 + 32 * i] = acc[i];
    }
}

// ---------------- s/d per (node, head) ----------------
__global__ void sd_k(const float* __restrict__ Hh, const float* __restrict__ a_src,
                     const float* __restrict__ a_dst, float* __restrict__ S,
                     float* __restrict__ D, int n) {
    __shared__ float sa[128], sb[128];
    if (threadIdx.x < 128) {
        sa[threadIdx.x] = a_src[threadIdx.x];
        sb[threadIdx.x] = a_dst[threadIdx.x];
    }
    __syncthreads();
    int idx = blockIdx.x * blockDim.x + threadIdx.x;
    if (idx >= n * 4) return;
    int node = idx >> 2, hd = idx & 3;
    const float* hp = Hh + node * 128 + hd * 32;
    float ss = 0.f, dd = 0.f;
#pragma unroll
    for (int i = 0; i < 32; i += 4) {
        float4 hv = *(const float4*)&hp[i];
        float4 av = *(const float4*)&sa[hd * 32 + i];
        float4 bv = *(const float4*)&sb[hd * 32 + i];
        ss += hv.x * av.x + hv.y * av.y + hv.z * av.z + hv.w * av.w;
        dd += hv.x * bv.x + hv.y * bv.y + hv.z * bv.z + hv.w * bv.w;
    }
    S[idx] = ss;
    D[idx] = dd;
}

__global__ void fill_k(float* __restrict__ p, float v, int cnt) {
    int i = blockIdx.x * blockDim.x + threadIdx.x;
    if (i < cnt) p[i] = v;
}

// ---------------- edge pass 1: e = lrelu(s[src]+d[dst]); atomicMax per (dst,head) ----
__global__ void edge_max_k(const int* __restrict__ ei, const float* __restrict__ S,
                           const float* __restrict__ D, float* __restrict__ Ebuf,
                           float* __restrict__ M, int ne, int e0) {
    int e = blockIdx.x * blockDim.x + threadIdx.x;
    if (e >= ne) return;
    int src, dst;
    if (e < e0) { src = ei[e]; dst = ei[e0 + e]; }
    else { src = e - e0; dst = src; }
    float4 sv = *(const float4*)&S[src * 4];
    float4 dv = *(const float4*)&D[dst * 4];
    float4 ev;
    ev.x = lrelu(sv.x + dv.x, LRELU_ATT);
    ev.y = lrelu(sv.y + dv.y, LRELU_ATT);
    ev.z = lrelu(sv.z + dv.z, LRELU_ATT);
    ev.w = lrelu(sv.w + dv.w, LRELU_ATT);
    *(float4*)&Ebuf[e * 4] = ev;
    atomicMaxF(&M[dst * 4 + 0], ev.x);
    atomicMaxF(&M[dst * 4 + 1], ev.y);
    atomicMaxF(&M[dst * 4 + 2], ev.z);
    atomicMaxF(&M[dst * 4 + 3], ev.w);
}

// ---------------- edge pass 2: ex = exp(e - m[dst]); denom += ex ----------------
__global__ void edge_exp_k(const int* __restrict__ ei, float* __restrict__ Ebuf,
                           const float* __restrict__ M, float* __restrict__ Den,
                           int ne, int e0) {
    int e = blockIdx.x * blockDim.x + threadIdx.x;
    if (e >= ne) return;
    int dst = (e < e0) ? ei[e0 + e] : (e - e0);
    float4 ev = *(const float4*)&Ebuf[e * 4];
    float4 mv = *(const float4*)&M[dst * 4];
    float4 ex;
    ex.x = expf(ev.x - mv.x);
    ex.y = expf(ev.y - mv.y);
    ex.z = expf(ev.z - mv.z);
    ex.w = expf(ev.w - mv.w);
    *(float4*)&Ebuf[e * 4] = ex;
    atomicAdd(&Den[dst * 4 + 0], ex.x);
    atomicAdd(&Den[dst * 4 + 1], ex.y);
    atomicAdd(&Den[dst * 4 + 2], ex.z);
    atomicAdd(&Den[dst * 4 + 3], ex.w);
}

// ---------------- edge pass 3: out[dst] += alpha * h[src]  (wave per edge) ----------
__global__ __launch_bounds__(256) void edge_agg_k(const int* __restrict__ ei,
                                                  const float* __restrict__ Hh,
                                                  const float* __restrict__ Ebuf,
                                                  const float* __restrict__ Den,
                                                  float* __restrict__ Out, int ne, int e0) {
    int wid = threadIdx.x >> 6;
    int lane = threadIdx.x & 63;
    int e = blockIdx.x * 4 + wid;
    if (e >= ne) return;
    int src, dst;
    if (e < e0) { src = ei[e]; dst = ei[e0 + e]; }
    else { src = e - e0; dst = src; }
    int c = lane * 2;
    int hd = c >> 5;
    float alpha = Ebuf[e * 4 + hd] / Den[dst * 4 + hd];
    float2 hv = *(const float2*)&Hh[src * 128 + c];
    atomicAdd(&Out[dst * 128 + c], hv.x * alpha);
    atomicAdd(&Out[dst * 128 + c + 1], hv.y * alpha);
}

// ---------------- bias + activation ----------------
__global__ void bias_act_k(const float* __restrict__ A, const float* __restrict__ b,
                           float* __restrict__ O, int total) {
    int i = (blockIdx.x * blockDim.x + threadIdx.x) * 4;
    if (i >= total) return;
    float4 v = *(const float4*)&A[i];
    int c = i & 127;
    float4 bv = *(const float4*)&b[c];
    v.x = lrelu(v.x + bv.x, LRELU_ACT);
    v.y = lrelu(v.y + bv.y, LRELU_ACT);
    v.z = lrelu(v.z + bv.z, LRELU_ACT);
    v.w = lrelu(v.w + bv.w, LRELU_ACT);
    *(float4*)&O[i] = v;
}

// ---------------- graph embedding: segment max over batch ----------------
__global__ void ge_max_k(const float* __restrict__ Hf, const int* __restrict__ batch,
                         float* __restrict__ ge, int n) {
    int idx = blockIdx.x * blockDim.x + threadIdx.x;
    if (idx >= n * 128) return;
    int node = idx >> 7, c = idx & 127;
    atomicMaxF(&ge[batch[node] * 128 + c], Hf[idx]);
}

// ---------------- edge_index passthrough (as float) ----------------
__global__ void ei_copy_k(const int* __restrict__ ei, float* __restrict__ out, int m) {
    int i = blockIdx.x * blockDim.x + threadIdx.x;
    if (i < m) out[i] = (float)ei[i];
}

extern "C" void kernel_launch(void* const* d_in, const int* in_sizes, int n_in,
                              void* d_out, int out_size, void* d_ws, size_t ws_size,
                              hipStream_t stream) {
    const float* x = (const float*)d_in[0];
    const int* ei = (const int*)d_in[1];
    const int* batch = (const int*)d_in[2];
    const float* Wm[3]   = {(const float*)d_in[3], (const float*)d_in[7],  (const float*)d_in[11]};
    const float* asrc[3] = {(const float*)d_in[4], (const float*)d_in[8],  (const float*)d_in[12]};
    const float* adst[3] = {(const float*)d_in[5], (const float*)d_in[9],  (const float*)d_in[13]};
    const float* bias[3] = {(const float*)d_in[6], (const float*)d_in[10], (const float*)d_in[14]};

    const int n = in_sizes[2];          // 50000 nodes
    const int E = in_sizes[1] / 2;      // 800000 edges
    const int ne = E + n;               // + self loops
    const int G = (out_size - n * 128 - 2 * E) / 128;  // 64 graphs

    // workspace layout
    char* w = (char*)d_ws;
    float* Hh   = (float*)w; w += (size_t)n * 128 * 4;
    float* Outa = (float*)w; w += (size_t)n * 128 * 4;
    float* Xact = (float*)w; w += (size_t)n * 128 * 4;
    float* S    = (float*)w; w += (size_t)n * 4 * 4;
    float* D    = (float*)w; w += (size_t)n * 4 * 4;
    float* M    = (float*)w; w += (size_t)n * 4 * 4;
    float* Den  = (float*)w; w += (size_t)n * 4 * 4;
    float* Ebuf = (float*)w; w += (size_t)ne * 4 * 4;

    float* out   = (float*)d_out;
    float* ge    = out;
    float* hout  = out + (size_t)G * 128;
    float* eiout = out + (size_t)G * 128 + (size_t)n * 128;

    const float* xin = x;
    for (int L = 0; L < 3; L++) {
        gemm_k<<<(n + 31) / 32, 256, 0, stream>>>(xin, Wm[L], Hh, n);
        sd_k<<<(n * 4 + 255) / 256, 256, 0, stream>>>(Hh, asrc[L], adst[L], S, D, n);
        hipMemsetAsync(Den, 0, (size_t)n * 4 * 4, stream);
        hipMemsetAsync(Outa, 0, (size_t)n * 128 * 4, stream);
        fill_k<<<(n * 4 + 255) / 256, 256, 0, stream>>>(M, -INFINITY, n * 4);
        edge_max_k<<<(ne + 255) / 256, 256, 0, stream>>>(ei, S, D, Ebuf, M, ne, E);
        edge_exp_k<<<(ne + 255) / 256, 256, 0, stream>>>(ei, Ebuf, M, Den, ne, E);
        edge_agg_k<<<(ne + 3) / 4, 256, 0, stream>>>(ei, Hh, Ebuf, Den, Outa, ne, E);
        float* xnext = (L == 2) ? hout : Xact;
        bias_act_k<<<(n * 128 / 4 + 255) / 256, 256, 0, stream>>>(Outa, bias[L], xnext, n * 128);
        xin = xnext;
    }
    fill_k<<<(G * 128 + 255) / 256, 256, 0, stream>>>(ge, -INFINITY, G * 128);
    ge_max_k<<<(n * 128 + 255) / 256, 256, 0, stream>>>(hout, batch, ge, n);
    ei_copy_k<<<(2 * E + 255) / 256, 256, 0, stream>>>(ei, eiout, 2 * E);
}

// Round 2
// 740.555 us; speedup vs baseline: 5.2297x; 5.2297x over previous
//
#include <hip/hip_runtime.h>
#include <math.h>
#include <limits.h>

#define LRELU_ATT 0.2f
#define LRELU_ACT 0.01f

__device__ __forceinline__ float lrelu(float x, float s) { return x > 0.f ? x : x * s; }

__device__ __forceinline__ void atomicMaxF(float* addr, float val) {
    int* ai = (int*)addr;
    int old = *(volatile int*)ai;
    while (__int_as_float(old) < val) {
        int assumed = old;
        old = atomicCAS(ai, assumed, __float_as_int(val));
        if (old == assumed) break;
    }
}

__device__ __forceinline__ float sel4(float4 v, int hd) {
    float lo = (hd & 1) ? v.y : v.x;
    float hi = (hd & 1) ? v.w : v.z;
    return (hd & 2) ? hi : lo;
}

// ---------------- GEMM: Hout[n,128] = X[n,128] @ W[128,128] (fp32) ----------------
__global__ __launch_bounds__(256) void gemm_k(const float* __restrict__ X,
                                              const float* __restrict__ Wm,
                                              float* __restrict__ Hout, int n) {
    __shared__ float sW[128 * 128];
    __shared__ float sX[32 * 132];
    for (int i = threadIdx.x * 4; i < 128 * 128; i += 1024)
        *(float4*)&sW[i] = *(const float4*)&Wm[i];
    int row0 = blockIdx.x * 32;
    for (int i = threadIdx.x * 4; i < 32 * 128; i += 1024) {
        int r = i >> 7, c = i & 127;
        int gr = row0 + r;
        float4 v = make_float4(0.f, 0.f, 0.f, 0.f);
        if (gr < n) v = *(const float4*)&X[gr * 128 + c];
        *(float4*)&sX[r * 132 + c] = v;
    }
    __syncthreads();
    int r = threadIdx.x >> 3;
    int c0 = (threadIdx.x & 7) * 4;
    float4 acc[4];
#pragma unroll
    for (int i = 0; i < 4; i++) acc[i] = make_float4(0.f, 0.f, 0.f, 0.f);
    const float* xr = &sX[r * 132];
#pragma unroll 2
    for (int k = 0; k < 128; k++) {
        float xv = xr[k];
#pragma unroll
        for (int i = 0; i < 4; i++) {
            float4 w = *(const float4*)&sW[k * 128 + c0 + 32 * i];
            acc[i].x = fmaf(xv, w.x, acc[i].x);
            acc[i].y = fmaf(xv, w.y, acc[i].y);
            acc[i].z = fmaf(xv, w.z, acc[i].z);
            acc[i].w = fmaf(xv, w.w, acc[i].w);
        }
    }
    int gr = row0 + r;
    if (gr < n) {
#pragma unroll
        for (int i = 0; i < 4; i++)
            *(float4*)&Hout[gr * 128 + c0 + 32 * i] = acc[i];
    }
}

// ---------------- s/d per (node, head) ----------------
__global__ void sd_k(const float* __restrict__ Hh, const float* __restrict__ a_src,
                     const float* __restrict__ a_dst, float* __restrict__ S,
                     float* __restrict__ D, int n) {
    __shared__ float sa[128], sb[128];
    if (threadIdx.x < 128) {
        sa[threadIdx.x] = a_src[threadIdx.x];
        sb[threadIdx.x] = a_dst[threadIdx.x];
    }
    __syncthreads();
    int idx = blockIdx.x * blockDim.x + threadIdx.x;
    if (idx >= n * 4) return;
    int node = idx >> 2, hd = idx & 3;
    const float* hp = Hh + node * 128 + hd * 32;
    float ss = 0.f, dd = 0.f;
#pragma unroll
    for (int i = 0; i < 32; i += 4) {
        float4 hv = *(const float4*)&hp[i];
        float4 av = *(const float4*)&sa[hd * 32 + i];
        float4 bv = *(const float4*)&sb[hd * 32 + i];
        ss += hv.x * av.x + hv.y * av.y + hv.z * av.z + hv.w * av.w;
        dd += hv.x * bv.x + hv.y * bv.y + hv.z * bv.z + hv.w * bv.w;
    }
    S[idx] = ss;
    D[idx] = dd;
}

__global__ void fill_f_k(float* __restrict__ p, float v, int cnt) {
    int i = blockIdx.x * blockDim.x + threadIdx.x;
    if (i < cnt) p[i] = v;
}
__global__ void fill_i_k(int* __restrict__ p, int v, int cnt) {
    int i = blockIdx.x * blockDim.x + threadIdx.x;
    if (i < cnt) p[i] = v;
}

// ---------------- CSR build ----------------
__global__ void hist_k(const int* __restrict__ ei, int* __restrict__ counts, int E) {
    int e = blockIdx.x * blockDim.x + threadIdx.x;
    if (e < E) atomicAdd(&counts[ei[E + e]], 1);
}

// inclusive scan, 256/block, two-level
__global__ void scan1_k(const int* __restrict__ in, int* __restrict__ pre,
                        int* __restrict__ bsum, int n) {
    __shared__ int s[256];
    int i = blockIdx.x * 256 + threadIdx.x;
    int v = (i < n) ? in[i] : 0;
    s[threadIdx.x] = v;
    __syncthreads();
    for (int o = 1; o < 256; o <<= 1) {
        int t = (threadIdx.x >= o) ? s[threadIdx.x - o] : 0;
        __syncthreads();
        s[threadIdx.x] += t;
        __syncthreads();
    }
    if (i < n) pre[i] = s[threadIdx.x];
    if (threadIdx.x == 255) bsum[blockIdx.x] = s[255];
}
__global__ void scan2_k(int* __restrict__ bsum, int nb) {
    __shared__ int s[256];
    int v = (threadIdx.x < nb) ? bsum[threadIdx.x] : 0;
    s[threadIdx.x] = v;
    __syncthreads();
    for (int o = 1; o < 256; o <<= 1) {
        int t = (threadIdx.x >= o) ? s[threadIdx.x - o] : 0;
        __syncthreads();
        s[threadIdx.x] += t;
        __syncthreads();
    }
    if (threadIdx.x < nb) bsum[threadIdx.x] = s[threadIdx.x];
}
__global__ void scan3_k(const int* __restrict__ pre, const int* __restrict__ bsum,
                        int* __restrict__ rowptr, int n) {
    int i = blockIdx.x * 256 + threadIdx.x;
    if (i < n) {
        int off = blockIdx.x ? bsum[blockIdx.x - 1] : 0;
        rowptr[i + 1] = pre[i] + off;
        if (i == 0) rowptr[0] = 0;
    }
}

__global__ void csr_init_k(const int* __restrict__ rowptr, int* __restrict__ csr,
                           int* __restrict__ cursor, int n) {
    int i = blockIdx.x * blockDim.x + threadIdx.x;
    if (i < n) {
        int p = rowptr[i];
        csr[p] = i;          // self loop
        cursor[i] = p + 1;
    }
}
__global__ void scatter_k(const int* __restrict__ ei, int* __restrict__ cursor,
                          int* __restrict__ csr, int E) {
    int e = blockIdx.x * blockDim.x + threadIdx.x;
    if (e < E) {
        int dst = ei[E + e];
        int pos = atomicAdd(&cursor[dst], 1);
        csr[pos] = ei[e];
    }
}
// canonicalize segment order (ascending src) for deterministic fp sums
__global__ __launch_bounds__(256) void sort_k(const int* __restrict__ rowptr,
                                              int* __restrict__ csr, int n) {
    int wid = (blockIdx.x * blockDim.x + threadIdx.x) >> 6;
    int lane = threadIdx.x & 63;
    if (wid >= n) return;
    int st = rowptr[wid], en = rowptr[wid + 1];
    int deg = en - st;
    if (deg <= 1) return;
    if (deg <= 64) {
        int v = (lane < deg) ? csr[st + lane] : INT_MAX;
        for (int p = 0; p < deg; p++) {
            int par;
            if ((p & 1) == 0) par = lane ^ 1;
            else {
                if (lane & 1) par = (lane == 63) ? lane : lane + 1;
                else par = (lane == 0) ? lane : lane - 1;
            }
            int o = __shfl(v, par, 64);
            if (par != lane) v = (lane < par) ? min(v, o) : max(v, o);
        }
        if (lane < deg) csr[st + lane] = v;
    } else if (lane == 0) {
        for (int i = st + 1; i < en; i++) {
            int key = csr[i];
            int j = i - 1;
            while (j >= st && csr[j] > key) { csr[j + 1] = csr[j]; j--; }
            csr[j + 1] = key;
        }
    }
}

// ---------------- fused softmax + aggregate + bias + act: one wave per dst ----------
__global__ __launch_bounds__(256) void attn_agg_k(const int* __restrict__ rowptr,
                                                  const int* __restrict__ csr,
                                                  const float* __restrict__ S,
                                                  const float* __restrict__ Dv,
                                                  const float* __restrict__ Hh,
                                                  const float* __restrict__ bias,
                                                  float* __restrict__ Out, int n) {
    int wid = blockIdx.x * 4 + (threadIdx.x >> 6);
    int lane = threadIdx.x & 63;
    if (wid >= n) return;
    int st = rowptr[wid], en = rowptr[wid + 1];
    float4 dv = *(const float4*)&Dv[wid * 4];

    // pass 1: per-head max (strided + wave reduce)
    float4 m = make_float4(-INFINITY, -INFINITY, -INFINITY, -INFINITY);
    for (int i = st + lane; i < en; i += 64) {
        int src = csr[i];
        float4 sv = *(const float4*)&S[src * 4];
        m.x = fmaxf(m.x, lrelu(sv.x + dv.x, LRELU_ATT));
        m.y = fmaxf(m.y, lrelu(sv.y + dv.y, LRELU_ATT));
        m.z = fmaxf(m.z, lrelu(sv.z + dv.z, LRELU_ATT));
        m.w = fmaxf(m.w, lrelu(sv.w + dv.w, LRELU_ATT));
    }
#pragma unroll
    for (int o = 32; o; o >>= 1) {
        m.x = fmaxf(m.x, __shfl_xor(m.x, o, 64));
        m.y = fmaxf(m.y, __shfl_xor(m.y, o, 64));
        m.z = fmaxf(m.z, __shfl_xor(m.z, o, 64));
        m.w = fmaxf(m.w, __shfl_xor(m.w, o, 64));
    }
    // pass 2: denom (strided + wave reduce)
    float4 den = make_float4(0.f, 0.f, 0.f, 0.f);
    for (int i = st + lane; i < en; i += 64) {
        int src = csr[i];
        float4 sv = *(const float4*)&S[src * 4];
        den.x += expf(lrelu(sv.x + dv.x, LRELU_ATT) - m.x);
        den.y += expf(lrelu(sv.y + dv.y, LRELU_ATT) - m.y);
        den.z += expf(lrelu(sv.z + dv.z, LRELU_ATT) - m.z);
        den.w += expf(lrelu(sv.w + dv.w, LRELU_ATT) - m.w);
    }
#pragma unroll
    for (int o = 32; o; o >>= 1) {
        den.x += __shfl_xor(den.x, o, 64);
        den.y += __shfl_xor(den.y, o, 64);
        den.z += __shfl_xor(den.z, o, 64);
        den.w += __shfl_xor(den.w, o, 64);
    }
    // pass 3: sequential edges, lanes = 2 channels each
    int c = lane * 2;
    int hd = c >> 5;
    float mh = sel4(m, hd);
    float dh = sel4(dv, hd);
    float denh = sel4(den, hd);
    float2 acc = make_float2(0.f, 0.f);
    for (int i = st; i < en; i++) {
        int src = csr[i];
        float e = lrelu(S[src * 4 + hd] + dh, LRELU_ATT);
        float p = expf(e - mh);
        float2 hv = *(const float2*)&Hh[src * 128 + c];
        acc.x = fmaf(p, hv.x, acc.x);
        acc.y = fmaf(p, hv.y, acc.y);
    }
    float r = 1.f / denh;
    float2 bv = *(const float2*)&bias[c];
    float2 o;
    o.x = lrelu(acc.x * r + bv.x, LRELU_ACT);
    o.y = lrelu(acc.y * r + bv.y, LRELU_ACT);
    *(float2*)&Out[wid * 128 + c] = o;
}

// ---------------- graph embedding: block-reduced segment max over sorted batch -------
__global__ void ge_max_k(const float* __restrict__ Hf, const int* __restrict__ batch,
                         float* __restrict__ ge, int n) {
    int c = threadIdx.x & 127;
    int rh = threadIdx.x >> 7;  // 0..1
    int node0 = blockIdx.x * 128;
    int hi = min(node0 + 128, n);
    int gid = -1;
    float mv = -INFINITY;
    for (int r = node0 + rh; r < hi; r += 2) {
        int g = batch[r];
        if (g != gid) {
            if (gid >= 0) atomicMaxF(&ge[gid * 128 + c], mv);
            gid = g;
            mv = -INFINITY;
        }
        mv = fmaxf(mv, Hf[r * 128 + c]);
    }
    if (gid >= 0) atomicMaxF(&ge[gid * 128 + c], mv);
}

__global__ void ei_copy_k(const int* __restrict__ ei, float* __restrict__ out, int m) {
    int i = blockIdx.x * blockDim.x + threadIdx.x;
    if (i < m) out[i] = (float)ei[i];
}

extern "C" void kernel_launch(void* const* d_in, const int* in_sizes, int n_in,
                              void* d_out, int out_size, void* d_ws, size_t ws_size,
                              hipStream_t stream) {
    const float* x = (const float*)d_in[0];
    const int* ei = (const int*)d_in[1];
    const int* batch = (const int*)d_in[2];
    const float* Wm[3]   = {(const float*)d_in[3], (const float*)d_in[7],  (const float*)d_in[11]};
    const float* asrc[3] = {(const float*)d_in[4], (const float*)d_in[8],  (const float*)d_in[12]};
    const float* adst[3] = {(const float*)d_in[5], (const float*)d_in[9],  (const float*)d_in[13]};
    const float* bias[3] = {(const float*)d_in[6], (const float*)d_in[10], (const float*)d_in[14]};

    const int n = in_sizes[2];          // 50000 nodes
    const int E = in_sizes[1] / 2;      // 800000 edges
    const int ne = E + n;               // + self loops
    const int G = (out_size - n * 128 - 2 * E) / 128;  // 64 graphs

    // workspace layout
    char* w = (char*)d_ws;
    float* Hh   = (float*)w; w += (size_t)n * 128 * 4;
    float* Xact = (float*)w; w += (size_t)n * 128 * 4;
    float* S    = (float*)w; w += (size_t)n * 4 * 4;
    float* D    = (float*)w; w += (size_t)n * 4 * 4;
    int* counts = (int*)w;   w += (size_t)n * 4;
    int* pre    = (int*)w;   w += (size_t)n * 4;
    int* rowptr = (int*)w;   w += (size_t)(n + 1) * 4;
    int* cursor = (int*)w;   w += (size_t)n * 4;
    int* bsum   = (int*)w;   w += 256 * 4;
    int* csr    = (int*)w;   w += (size_t)ne * 4;

    float* out   = (float*)d_out;
    float* ge    = out;
    float* hout  = out + (size_t)G * 128;
    float* eiout = out + (size_t)G * 128 + (size_t)n * 128;

    // ---- CSR build (once) ----
    int nb = (n + 255) / 256;
    fill_i_k<<<nb, 256, 0, stream>>>(counts, 1, n);   // self-loops
    hist_k<<<(E + 255) / 256, 256, 0, stream>>>(ei, counts, E);
    scan1_k<<<nb, 256, 0, stream>>>(counts, pre, bsum, n);
    scan2_k<<<1, 256, 0, stream>>>(bsum, nb);
    scan3_k<<<nb, 256, 0, stream>>>(pre, bsum, rowptr, n);
    csr_init_k<<<nb, 256, 0, stream>>>(rowptr, csr, cursor, n);
    scatter_k<<<(E + 255) / 256, 256, 0, stream>>>(ei, cursor, csr, E);
    sort_k<<<(n + 3) / 4, 256, 0, stream>>>(rowptr, csr, n);

    // ---- 3 GAT layers ----
    const float* xin = x;
    for (int L = 0; L < 3; L++) {
        gemm_k<<<(n + 31) / 32, 256, 0, stream>>>(xin, Wm[L], Hh, n);
        sd_k<<<(n * 4 + 255) / 256, 256, 0, stream>>>(Hh, asrc[L], adst[L], S, D, n);
        float* xnext = (L == 2) ? hout : Xact;
        attn_agg_k<<<(n + 3) / 4, 256, 0, stream>>>(rowptr, csr, S, D, Hh, bias[L], xnext, n);
        xin = xnext;
    }

    // ---- readout ----
    fill_f_k<<<(G * 128 + 255) / 256, 256, 0, stream>>>(ge, -INFINITY, G * 128);
    ge_max_k<<<(n + 127) / 128, 256, 0, stream>>>(hout, batch, ge, n);
    ei_copy_k<<<(2 * E + 255) / 256, 256, 0, stream>>>(ei, eiout, 2 * E);
}

// Round 3
// 586.353 us; speedup vs baseline: 6.6050x; 1.2630x over previous
//
#include <hip/hip_runtime.h>
#include <math.h>
#include <limits.h>

#define LRELU_ATT 0.2f
#define LRELU_ACT 0.01f
#define CAP 128   // cached edges per dst in LDS (deg > CAP falls back to recompute)

__device__ __forceinline__ float lrelu(float x, float s) { return x > 0.f ? x : x * s; }

__device__ __forceinline__ void atomicMaxF(float* addr, float val) {
    int* ai = (int*)addr;
    int old = *(volatile int*)ai;
    while (__int_as_float(old) < val) {
        int assumed = old;
        old = atomicCAS(ai, assumed, __float_as_int(val));
        if (old == assumed) break;
    }
}

__device__ __forceinline__ float sel4(float4 v, int hd) {
    float lo = (hd & 1) ? v.y : v.x;
    float hi = (hd & 1) ? v.w : v.z;
    return (hd & 2) ? hi : lo;
}

__device__ __forceinline__ unsigned short f2bf(float f) {
    union { float f; unsigned u; } v; v.f = f;
    unsigned r = v.u + 0x7FFF + ((v.u >> 16) & 1);   // RNE
    return (unsigned short)(r >> 16);
}
__device__ __forceinline__ float bf2f(unsigned short u) {
    union { unsigned u; float f; } v; v.u = ((unsigned)u) << 16;
    return v.f;
}

// ---- GEMM + fused s/d epilogue: Hb[n,128](bf16) = X@W;  S,D[n,4] = head-dots ----
__global__ __launch_bounds__(256) void gemm_k(const float* __restrict__ X,
                                              const float* __restrict__ Wm,
                                              const float* __restrict__ a_src,
                                              const float* __restrict__ a_dst,
                                              unsigned short* __restrict__ Hb,
                                              float* __restrict__ S,
                                              float* __restrict__ D, int n) {
    __shared__ float sW[128 * 128];
    __shared__ float sX[32 * 132];
    __shared__ float sa[128], sb[128];
    if (threadIdx.x < 128) {
        sa[threadIdx.x] = a_src[threadIdx.x];
        sb[threadIdx.x] = a_dst[threadIdx.x];
    }
    for (int i = threadIdx.x * 4; i < 128 * 128; i += 1024)
        *(float4*)&sW[i] = *(const float4*)&Wm[i];
    int row0 = blockIdx.x * 32;
    for (int i = threadIdx.x * 4; i < 32 * 128; i += 1024) {
        int r = i >> 7, c = i & 127;
        int gr = row0 + r;
        float4 v = make_float4(0.f, 0.f, 0.f, 0.f);
        if (gr < n) v = *(const float4*)&X[gr * 128 + c];
        *(float4*)&sX[r * 132 + c] = v;
    }
    __syncthreads();
    int r = threadIdx.x >> 3;
    int c0 = (threadIdx.x & 7) * 4;
    float4 acc[4];
#pragma unroll
    for (int i = 0; i < 4; i++) acc[i] = make_float4(0.f, 0.f, 0.f, 0.f);
    const float* xr = &sX[r * 132];
#pragma unroll 2
    for (int k = 0; k < 128; k++) {
        float xv = xr[k];
#pragma unroll
        for (int i = 0; i < 4; i++) {
            float4 w = *(const float4*)&sW[k * 128 + c0 + 32 * i];
            acc[i].x = fmaf(xv, w.x, acc[i].x);
            acc[i].y = fmaf(xv, w.y, acc[i].y);
            acc[i].z = fmaf(xv, w.z, acc[i].z);
            acc[i].w = fmaf(xv, w.w, acc[i].w);
        }
    }
    int gr = row0 + r;
    // fused s/d: thread has channels c0..c0+3 of each head i
    float sp[4], dp[4];
#pragma unroll
    for (int i = 0; i < 4; i++) {
        const float* ap = &sa[32 * i + c0];
        const float* bp = &sb[32 * i + c0];
        sp[i] = acc[i].x * ap[0] + acc[i].y * ap[1] + acc[i].z * ap[2] + acc[i].w * ap[3];
        dp[i] = acc[i].x * bp[0] + acc[i].y * bp[1] + acc[i].z * bp[2] + acc[i].w * bp[3];
    }
#pragma unroll
    for (int o = 1; o < 8; o <<= 1) {
#pragma unroll
        for (int i = 0; i < 4; i++) {
            sp[i] += __shfl_xor(sp[i], o, 64);
            dp[i] += __shfl_xor(dp[i], o, 64);
        }
    }
    if (gr < n) {
        if ((threadIdx.x & 7) == 0) {
            *(float4*)&S[gr * 4] = make_float4(sp[0], sp[1], sp[2], sp[3]);
            *(float4*)&D[gr * 4] = make_float4(dp[0], dp[1], dp[2], dp[3]);
        }
#pragma unroll
        for (int i = 0; i < 4; i++) {
            ushort4 hb;
            hb.x = f2bf(acc[i].x); hb.y = f2bf(acc[i].y);
            hb.z = f2bf(acc[i].z); hb.w = f2bf(acc[i].w);
            *(ushort4*)&Hb[gr * 128 + c0 + 32 * i] = hb;
        }
    }
}

__global__ void fill_f_k(float* __restrict__ p, float v, int cnt) {
    int i = blockIdx.x * blockDim.x + threadIdx.x;
    if (i < cnt) p[i] = v;
}
__global__ void fill_i_k(int* __restrict__ p, int v, int cnt) {
    int i = blockIdx.x * blockDim.x + threadIdx.x;
    if (i < cnt) p[i] = v;
}

// ---------------- CSR build ----------------
__global__ void hist_k(const int* __restrict__ ei, int* __restrict__ counts, int E) {
    int e = blockIdx.x * blockDim.x + threadIdx.x;
    if (e < E) atomicAdd(&counts[ei[E + e]], 1);
}
__global__ void scan1_k(const int* __restrict__ in, int* __restrict__ pre,
                        int* __restrict__ bsum, int n) {
    __shared__ int s[256];
    int i = blockIdx.x * 256 + threadIdx.x;
    int v = (i < n) ? in[i] : 0;
    s[threadIdx.x] = v;
    __syncthreads();
    for (int o = 1; o < 256; o <<= 1) {
        int t = (threadIdx.x >= o) ? s[threadIdx.x - o] : 0;
        __syncthreads();
        s[threadIdx.x] += t;
        __syncthreads();
    }
    if (i < n) pre[i] = s[threadIdx.x];
    if (threadIdx.x == 255) bsum[blockIdx.x] = s[255];
}
__global__ void scan2_k(int* __restrict__ bsum, int nb) {
    __shared__ int s[256];
    int v = (threadIdx.x < nb) ? bsum[threadIdx.x] : 0;
    s[threadIdx.x] = v;
    __syncthreads();
    for (int o = 1; o < 256; o <<= 1) {
        int t = (threadIdx.x >= o) ? s[threadIdx.x - o] : 0;
        __syncthreads();
        s[threadIdx.x] += t;
        __syncthreads();
    }
    if (threadIdx.x < nb) bsum[threadIdx.x] = s[threadIdx.x];
}
__global__ void scan3_k(const int* __restrict__ pre, const int* __restrict__ bsum,
                        int* __restrict__ rowptr, int n) {
    int i = blockIdx.x * 256 + threadIdx.x;
    if (i < n) {
        int off = blockIdx.x ? bsum[blockIdx.x - 1] : 0;
        rowptr[i + 1] = pre[i] + off;
        if (i == 0) rowptr[0] = 0;
    }
}
__global__ void csr_init_k(const int* __restrict__ rowptr, int* __restrict__ csr,
                           int* __restrict__ cursor, int n) {
    int i = blockIdx.x * blockDim.x + threadIdx.x;
    if (i < n) {
        int p = rowptr[i];
        csr[p] = i;          // self loop
        cursor[i] = p + 1;
    }
}
__global__ void scatter_k(const int* __restrict__ ei, int* __restrict__ cursor,
                          int* __restrict__ csr, int E) {
    int e = blockIdx.x * blockDim.x + threadIdx.x;
    if (e < E) {
        int dst = ei[E + e];
        int pos = atomicAdd(&cursor[dst], 1);
        csr[pos] = ei[e];
    }
}
// canonicalize segment order for deterministic fp sums
__global__ __launch_bounds__(256) void sort_k(const int* __restrict__ rowptr,
                                              int* __restrict__ csr, int n) {
    int wid = (blockIdx.x * blockDim.x + threadIdx.x) >> 6;
    int lane = threadIdx.x & 63;
    if (wid >= n) return;
    int st = rowptr[wid], en = rowptr[wid + 1];
    int deg = en - st;
    if (deg <= 1) return;
    if (deg <= 64) {
        int v = (lane < deg) ? csr[st + lane] : INT_MAX;
        for (int p = 0; p < deg; p++) {
            int par;
            if ((p & 1) == 0) par = lane ^ 1;
            else {
                if (lane & 1) par = (lane == 63) ? lane : lane + 1;
                else par = (lane == 0) ? lane : lane - 1;
            }
            int o = __shfl(v, par, 64);
            if (par != lane) v = (lane < par) ? min(v, o) : max(v, o);
        }
        if (lane < deg) csr[st + lane] = v;
    } else if (lane == 0) {
        for (int i = st + 1; i < en; i++) {
            int key = csr[i];
            int j = i - 1;
            while (j >= st && csr[j] > key) { csr[j + 1] = csr[j]; j--; }
            csr[j + 1] = key;
        }
    }
}

// ---- fused softmax + aggregate + bias + act: one wave per dst, LDS-cached weights ---
__global__ __launch_bounds__(256) void attn_agg_k(const int* __restrict__ rowptr,
                                                  const int* __restrict__ csr,
                                                  const float* __restrict__ S,
                                                  const float* __restrict__ Dv,
                                                  const unsigned short* __restrict__ Hb,
                                                  const float* __restrict__ bias,
                                                  float* __restrict__ Out, int n) {
    __shared__ float exs[4][CAP * 4];
    int wv = threadIdx.x >> 6;
    int wid = blockIdx.x * 4 + wv;
    if (wid >= n) return;
    int lane = threadIdx.x & 63;
    int st = rowptr[wid], en = rowptr[wid + 1];
    float4 dv = *(const float4*)&Dv[wid * 4];

    // pass 1: e per edge (lane-strided), raw e -> reg (iter 0) / LDS; track max
    float4 m = make_float4(-INFINITY, -INFINITY, -INFINITY, -INFINITY);
    float4 e0;
    int nit = 0;
    for (int i = st + lane; i < en; i += 64) {
        int src = csr[i];
        float4 sv = *(const float4*)&S[src * 4];
        float4 e;
        e.x = lrelu(sv.x + dv.x, LRELU_ATT);
        e.y = lrelu(sv.y + dv.y, LRELU_ATT);
        e.z = lrelu(sv.z + dv.z, LRELU_ATT);
        e.w = lrelu(sv.w + dv.w, LRELU_ATT);
        int pos = i - st;
        if (nit == 0) e0 = e;
        else if (pos < CAP) *(float4*)&exs[wv][pos * 4] = e;
        m.x = fmaxf(m.x, e.x); m.y = fmaxf(m.y, e.y);
        m.z = fmaxf(m.z, e.z); m.w = fmaxf(m.w, e.w);
        nit++;
    }
#pragma unroll
    for (int o = 32; o; o >>= 1) {
        m.x = fmaxf(m.x, __shfl_xor(m.x, o, 64));
        m.y = fmaxf(m.y, __shfl_xor(m.y, o, 64));
        m.z = fmaxf(m.z, __shfl_xor(m.z, o, 64));
        m.w = fmaxf(m.w, __shfl_xor(m.w, o, 64));
    }
    // pass 2: ex = exp(e - m) -> LDS; accumulate denom
    float4 den = make_float4(0.f, 0.f, 0.f, 0.f);
    int k = 0;
    for (int i = st + lane; i < en; i += 64) {
        int pos = i - st;
        float4 e;
        if (k == 0) e = e0;
        else if (pos < CAP) e = *(const float4*)&exs[wv][pos * 4];
        else {
            int src = csr[i];
            float4 sv = *(const float4*)&S[src * 4];
            e.x = lrelu(sv.x + dv.x, LRELU_ATT);
            e.y = lrelu(sv.y + dv.y, LRELU_ATT);
            e.z = lrelu(sv.z + dv.z, LRELU_ATT);
            e.w = lrelu(sv.w + dv.w, LRELU_ATT);
        }
        float4 ex;
        ex.x = __expf(e.x - m.x); ex.y = __expf(e.y - m.y);
        ex.z = __expf(e.z - m.z); ex.w = __expf(e.w - m.w);
        den.x += ex.x; den.y += ex.y; den.z += ex.z; den.w += ex.w;
        if (pos < CAP) *(float4*)&exs[wv][pos * 4] = ex;
        k++;
    }
#pragma unroll
    for (int o = 32; o; o >>= 1) {
        den.x += __shfl_xor(den.x, o, 64);
        den.y += __shfl_xor(den.y, o, 64);
        den.z += __shfl_xor(den.z, o, 64);
        den.w += __shfl_xor(den.w, o, 64);
    }
    // pass 3: 2 edges per iter; half-wave per edge, 4 channels per lane
    int half = lane >> 5;
    int cl = (lane & 31) * 4;
    int hd = (lane & 31) >> 3;
    float mh = sel4(m, hd), dh = sel4(dv, hd), denh = sel4(den, hd);
    float4 acc = make_float4(0.f, 0.f, 0.f, 0.f);
    for (int i = st; i < en; i += 2) {
        int e_i = i + half;
        if (e_i < en) {
            int pos = e_i - st;
            int src = csr[e_i];
            float p;
            if (pos < CAP) p = exs[wv][pos * 4 + hd];
            else p = __expf(lrelu(S[src * 4 + hd] + dh, LRELU_ATT) - mh);
            ushort4 hv = *(const ushort4*)&Hb[src * 128 + cl];
            acc.x = fmaf(p, bf2f(hv.x), acc.x);
            acc.y = fmaf(p, bf2f(hv.y), acc.y);
            acc.z = fmaf(p, bf2f(hv.z), acc.z);
            acc.w = fmaf(p, bf2f(hv.w), acc.w);
        }
    }
    acc.x += __shfl_xor(acc.x, 32, 64);
    acc.y += __shfl_xor(acc.y, 32, 64);
    acc.z += __shfl_xor(acc.z, 32, 64);
    acc.w += __shfl_xor(acc.w, 32, 64);
    if (lane < 32) {
        float r = 1.f / denh;
        float4 bv = *(const float4*)&bias[cl];
        float4 o;
        o.x = lrelu(acc.x * r + bv.x, LRELU_ACT);
        o.y = lrelu(acc.y * r + bv.y, LRELU_ACT);
        o.z = lrelu(acc.z * r + bv.z, LRELU_ACT);
        o.w = lrelu(acc.w * r + bv.w, LRELU_ACT);
        *(float4*)&Out[wid * 128 + cl] = o;
    }
}

// ---------------- graph embedding: segment max over sorted batch ----------------
__global__ void ge_max_k(const float* __restrict__ Hf, const int* __restrict__ batch,
                         float* __restrict__ ge, int n) {
    int c = threadIdx.x & 127;
    int rh = threadIdx.x >> 7;  // 0..1
    int node0 = blockIdx.x * 128;
    int hi = min(node0 + 128, n);
    int gid = -1;
    float mv = -INFINITY;
    for (int r = node0 + rh; r < hi; r += 2) {
        int g = batch[r];
        if (g != gid) {
            if (gid >= 0) atomicMaxF(&ge[gid * 128 + c], mv);
            gid = g;
            mv = -INFINITY;
        }
        mv = fmaxf(mv, Hf[r * 128 + c]);
    }
    if (gid >= 0) atomicMaxF(&ge[gid * 128 + c], mv);
}

__global__ void ei_copy_k(const int* __restrict__ ei, float* __restrict__ out, int m) {
    int i = (blockIdx.x * blockDim.x + threadIdx.x) * 4;
    if (i + 3 < m) {
        int4 v = *(const int4*)&ei[i];
        float4 o = make_float4((float)v.x, (float)v.y, (float)v.z, (float)v.w);
        *(float4*)&out[i] = o;
    } else {
        for (; i < m; i++) out[i] = (float)ei[i];
    }
}

extern "C" void kernel_launch(void* const* d_in, const int* in_sizes, int n_in,
                              void* d_out, int out_size, void* d_ws, size_t ws_size,
                              hipStream_t stream) {
    const float* x = (const float*)d_in[0];
    const int* ei = (const int*)d_in[1];
    const int* batch = (const int*)d_in[2];
    const float* Wm[3]   = {(const float*)d_in[3], (const float*)d_in[7],  (const float*)d_in[11]};
    const float* asrc[3] = {(const float*)d_in[4], (const float*)d_in[8],  (const float*)d_in[12]};
    const float* adst[3] = {(const float*)d_in[5], (const float*)d_in[9],  (const float*)d_in[13]};
    const float* bias[3] = {(const float*)d_in[6], (const float*)d_in[10], (const float*)d_in[14]};

    const int n = in_sizes[2];          // 50000 nodes
    const int E = in_sizes[1] / 2;      // 800000 edges
    const int ne = E + n;               // + self loops
    const int G = (out_size - n * 128 - 2 * E) / 128;  // 64 graphs

    // workspace layout
    char* w = (char*)d_ws;
    float* Xact = (float*)w;          w += (size_t)n * 128 * 4;
    unsigned short* Hb = (unsigned short*)w; w += (size_t)n * 128 * 2;
    float* S    = (float*)w; w += (size_t)n * 4 * 4;
    float* D    = (float*)w; w += (size_t)n * 4 * 4;
    int* counts = (int*)w;   w += (size_t)n * 4;
    int* pre    = (int*)w;   w += (size_t)n * 4;
    int* rowptr = (int*)w;   w += (size_t)(n + 1) * 4;
    int* cursor = (int*)w;   w += (size_t)n * 4;
    int* bsum   = (int*)w;   w += 256 * 4;
    int* csr    = (int*)w;   w += (size_t)ne * 4;

    float* out   = (float*)d_out;
    float* ge    = out;
    float* hout  = out + (size_t)G * 128;
    float* eiout = out + (size_t)G * 128 + (size_t)n * 128;

    // ---- CSR build (once) ----
    int nb = (n + 255) / 256;
    fill_i_k<<<nb, 256, 0, stream>>>(counts, 1, n);   // self-loops
    hist_k<<<(E + 255) / 256, 256, 0, stream>>>(ei, counts, E);
    scan1_k<<<nb, 256, 0, stream>>>(counts, pre, bsum, n);
    scan2_k<<<1, 256, 0, stream>>>(bsum, nb);
    scan3_k<<<nb, 256, 0, stream>>>(pre, bsum, rowptr, n);
    csr_init_k<<<nb, 256, 0, stream>>>(rowptr, csr, cursor, n);
    scatter_k<<<(E + 255) / 256, 256, 0, stream>>>(ei, cursor, csr, E);
    sort_k<<<(n + 3) / 4, 256, 0, stream>>>(rowptr, csr, n);

    // ---- 3 GAT layers ----
    const float* xin = x;
    for (int L = 0; L < 3; L++) {
        gemm_k<<<(n + 31) / 32, 256, 0, stream>>>(xin, Wm[L], asrc[L], adst[L], Hb, S, D, n);
        float* xnext = (L == 2) ? hout : Xact;
        attn_agg_k<<<(n + 3) / 4, 256, 0, stream>>>(rowptr, csr, S, D, Hb, bias[L], xnext, n);
        xin = xnext;
    }

    // ---- readout ----
    fill_f_k<<<(G * 128 + 255) / 256, 256, 0, stream>>>(ge, -INFINITY, G * 128);
    ge_max_k<<<(n + 127) / 128, 256, 0, stream>>>(hout, batch, ge, n);
    ei_copy_k<<<(2 * E / 4 + 255) / 256, 256, 0, stream>>>(ei, eiout, 2 * E);
}

// Round 4
// 458.799 us; speedup vs baseline: 8.4413x; 1.2780x over previous
//
#include <hip/hip_runtime.h>
#include <math.h>
#include <limits.h>

#define LRELU_ATT 0.2f
#define LRELU_ACT 0.01f
#define CAP 128   // cached edges per dst in LDS (deg > CAP falls back to recompute)

__device__ __forceinline__ float lrelu(float x, float s) { return x > 0.f ? x : x * s; }

__device__ __forceinline__ void atomicMaxF(float* addr, float val) {
    int* ai = (int*)addr;
    int old = *(volatile int*)ai;
    while (__int_as_float(old) < val) {
        int assumed = old;
        old = atomicCAS(ai, assumed, __float_as_int(val));
        if (old == assumed) break;
    }
}

__device__ __forceinline__ float sel4(float4 v, int hd) {
    float lo = (hd & 1) ? v.y : v.x;
    float hi = (hd & 1) ? v.w : v.z;
    return (hd & 2) ? hi : lo;
}

__device__ __forceinline__ unsigned short f2bf(float f) {
    union { float f; unsigned u; } v; v.f = f;
    unsigned r = v.u + 0x7FFF + ((v.u >> 16) & 1);   // RNE
    return (unsigned short)(r >> 16);
}
__device__ __forceinline__ float bf2f(unsigned short u) {
    union { unsigned u; float f; } v; v.u = ((unsigned)u) << 16;
    return v.f;
}

// ---- GEMM + fused s/d epilogue: Hb[n,128](bf16) = X@W;  S,D[n,4] = head-dots ----
// 32 rows/block, K tiled by 32: LDS = 16K (W tile) + 4K (X tile) + 1K -> ~21 KB
// => ~6 blocks/CU resident (latency-hiding), vs 81 KB/1 block before.
// Thread tile: 4 rows x 4 cols. X-row LDS reads are 32-lane broadcasts.
__global__ __launch_bounds__(256) void gemm_k(const float* __restrict__ X,
                                              const float* __restrict__ Wm,
                                              const float* __restrict__ a_src,
                                              const float* __restrict__ a_dst,
                                              unsigned short* __restrict__ Hb,
                                              float* __restrict__ S,
                                              float* __restrict__ D, int n) {
    __shared__ float sW[32 * 128];
    __shared__ float sX[32 * 32];
    __shared__ float sa[128], sb[128];
    if (threadIdx.x < 128) {
        sa[threadIdx.x] = a_src[threadIdx.x];
        sb[threadIdx.x] = a_dst[threadIdx.x];
    }
    int row0 = blockIdx.x * 32;
    int rt = threadIdx.x >> 5;   // 0..7 -> rows rt*4..rt*4+3
    int ct = threadIdx.x & 31;   // cols ct*4..ct*4+3
    int c0 = ct * 4;
    float4 acc[4];
#pragma unroll
    for (int i = 0; i < 4; i++) acc[i] = make_float4(0.f, 0.f, 0.f, 0.f);

    for (int k0 = 0; k0 < 128; k0 += 32) {
        __syncthreads();
        for (int i = threadIdx.x * 4; i < 32 * 128; i += 1024)
            *(float4*)&sW[i] = *(const float4*)&Wm[(k0 + (i >> 7)) * 128 + (i & 127)];
        {
            int i = threadIdx.x * 4;   // covers 32*32 exactly
            int r = i >> 5, kk = i & 31;
            int gr = row0 + r;
            float4 v = make_float4(0.f, 0.f, 0.f, 0.f);
            if (gr < n) v = *(const float4*)&X[gr * 128 + k0 + kk];
            *(float4*)&sX[i] = v;
        }
        __syncthreads();
#pragma unroll
        for (int kk = 0; kk < 32; kk += 4) {
            float4 w0 = *(const float4*)&sW[(kk + 0) * 128 + c0];
            float4 w1 = *(const float4*)&sW[(kk + 1) * 128 + c0];
            float4 w2 = *(const float4*)&sW[(kk + 2) * 128 + c0];
            float4 w3 = *(const float4*)&sW[(kk + 3) * 128 + c0];
#pragma unroll
            for (int i = 0; i < 4; i++) {
                float4 xv = *(const float4*)&sX[(rt * 4 + i) * 32 + kk];
                acc[i].x = fmaf(xv.x, w0.x, acc[i].x);
                acc[i].y = fmaf(xv.x, w0.y, acc[i].y);
                acc[i].z = fmaf(xv.x, w0.z, acc[i].z);
                acc[i].w = fmaf(xv.x, w0.w, acc[i].w);
                acc[i].x = fmaf(xv.y, w1.x, acc[i].x);
                acc[i].y = fmaf(xv.y, w1.y, acc[i].y);
                acc[i].z = fmaf(xv.y, w1.z, acc[i].z);
                acc[i].w = fmaf(xv.y, w1.w, acc[i].w);
                acc[i].x = fmaf(xv.z, w2.x, acc[i].x);
                acc[i].y = fmaf(xv.z, w2.y, acc[i].y);
                acc[i].z = fmaf(xv.z, w2.z, acc[i].z);
                acc[i].w = fmaf(xv.z, w2.w, acc[i].w);
                acc[i].x = fmaf(xv.w, w3.x, acc[i].x);
                acc[i].y = fmaf(xv.w, w3.y, acc[i].y);
                acc[i].z = fmaf(xv.w, w3.z, acc[i].z);
                acc[i].w = fmaf(xv.w, w3.w, acc[i].w);
            }
        }
    }
    // fused s/d epilogue: reduce over the 8 lanes sharing a head (ct bits 0..2)
    float sp[4], dp[4];
    const float* ap = &sa[c0];
    const float* bp = &sb[c0];
#pragma unroll
    for (int i = 0; i < 4; i++) {
        sp[i] = acc[i].x * ap[0] + acc[i].y * ap[1] + acc[i].z * ap[2] + acc[i].w * ap[3];
        dp[i] = acc[i].x * bp[0] + acc[i].y * bp[1] + acc[i].z * bp[2] + acc[i].w * bp[3];
    }
#pragma unroll
    for (int o = 1; o < 8; o <<= 1) {
#pragma unroll
        for (int i = 0; i < 4; i++) {
            sp[i] += __shfl_xor(sp[i], o, 64);
            dp[i] += __shfl_xor(dp[i], o, 64);
        }
    }
    int hd = ct >> 3;
#pragma unroll
    for (int i = 0; i < 4; i++) {
        int gr = row0 + rt * 4 + i;
        if (gr < n) {
            ushort4 hb;
            hb.x = f2bf(acc[i].x); hb.y = f2bf(acc[i].y);
            hb.z = f2bf(acc[i].z); hb.w = f2bf(acc[i].w);
            *(ushort4*)&Hb[gr * 128 + c0] = hb;
            if ((ct & 7) == 0) {
                S[gr * 4 + hd] = sp[i];
                D[gr * 4 + hd] = dp[i];
            }
        }
    }
}

__global__ void fill_f_k(float* __restrict__ p, float v, int cnt) {
    int i = blockIdx.x * blockDim.x + threadIdx.x;
    if (i < cnt) p[i] = v;
}
__global__ void fill_i_k(int* __restrict__ p, int v, int cnt) {
    int i = blockIdx.x * blockDim.x + threadIdx.x;
    if (i < cnt) p[i] = v;
}

// ---------------- CSR build ----------------
__global__ void hist_k(const int* __restrict__ ei, int* __restrict__ counts, int E) {
    int e = blockIdx.x * blockDim.x + threadIdx.x;
    if (e < E) atomicAdd(&counts[ei[E + e]], 1);
}
__global__ void scan1_k(const int* __restrict__ in, int* __restrict__ pre,
                        int* __restrict__ bsum, int n) {
    __shared__ int s[256];
    int i = blockIdx.x * 256 + threadIdx.x;
    int v = (i < n) ? in[i] : 0;
    s[threadIdx.x] = v;
    __syncthreads();
    for (int o = 1; o < 256; o <<= 1) {
        int t = (threadIdx.x >= o) ? s[threadIdx.x - o] : 0;
        __syncthreads();
        s[threadIdx.x] += t;
        __syncthreads();
    }
    if (i < n) pre[i] = s[threadIdx.x];
    if (threadIdx.x == 255) bsum[blockIdx.x] = s[255];
}
__global__ void scan2_k(int* __restrict__ bsum, int nb) {
    __shared__ int s[256];
    int v = (threadIdx.x < nb) ? bsum[threadIdx.x] : 0;
    s[threadIdx.x] = v;
    __syncthreads();
    for (int o = 1; o < 256; o <<= 1) {
        int t = (threadIdx.x >= o) ? s[threadIdx.x - o] : 0;
        __syncthreads();
        s[threadIdx.x] += t;
        __syncthreads();
    }
    if (threadIdx.x < nb) bsum[threadIdx.x] = s[threadIdx.x];
}
__global__ void scan3_k(const int* __restrict__ pre, const int* __restrict__ bsum,
                        int* __restrict__ rowptr, int n) {
    int i = blockIdx.x * 256 + threadIdx.x;
    if (i < n) {
        int off = blockIdx.x ? bsum[blockIdx.x - 1] : 0;
        rowptr[i + 1] = pre[i] + off;
        if (i == 0) rowptr[0] = 0;
    }
}
__global__ void csr_init_k(const int* __restrict__ rowptr, int* __restrict__ csr,
                           int* __restrict__ cursor, int n) {
    int i = blockIdx.x * blockDim.x + threadIdx.x;
    if (i < n) {
        int p = rowptr[i];
        csr[p] = i;          // self loop
        cursor[i] = p + 1;
    }
}
__global__ void scatter_k(const int* __restrict__ ei, int* __restrict__ cursor,
                          int* __restrict__ csr, int E) {
    int e = blockIdx.x * blockDim.x + threadIdx.x;
    if (e < E) {
        int dst = ei[E + e];
        int pos = atomicAdd(&cursor[dst], 1);
        csr[pos] = ei[e];
    }
}
// canonicalize segment order for deterministic fp sums
__global__ __launch_bounds__(256) void sort_k(const int* __restrict__ rowptr,
                                              int* __restrict__ csr, int n) {
    int wid = (blockIdx.x * blockDim.x + threadIdx.x) >> 6;
    int lane = threadIdx.x & 63;
    if (wid >= n) return;
    int st = rowptr[wid], en = rowptr[wid + 1];
    int deg = en - st;
    if (deg <= 1) return;
    if (deg <= 64) {
        int v = (lane < deg) ? csr[st + lane] : INT_MAX;
        for (int p = 0; p < deg; p++) {
            int par;
            if ((p & 1) == 0) par = lane ^ 1;
            else {
                if (lane & 1) par = (lane == 63) ? lane : lane + 1;
                else par = (lane == 0) ? lane : lane - 1;
            }
            int o = __shfl(v, par, 64);
            if (par != lane) v = (lane < par) ? min(v, o) : max(v, o);
        }
        if (lane < deg) csr[st + lane] = v;
    } else if (lane == 0) {
        for (int i = st + 1; i < en; i++) {
            int key = csr[i];
            int j = i - 1;
            while (j >= st && csr[j] > key) { csr[j + 1] = csr[j]; j--; }
            csr[j + 1] = key;
        }
    }
}

// ---- fused softmax + aggregate + bias + act: one wave per dst, LDS-cached weights ---
__global__ __launch_bounds__(256) void attn_agg_k(const int* __restrict__ rowptr,
                                                  const int* __restrict__ csr,
                                                  const float* __restrict__ S,
                                                  const float* __restrict__ Dv,
                                                  const unsigned short* __restrict__ Hb,
                                                  const float* __restrict__ bias,
                                                  float* __restrict__ Out, int n) {
    __shared__ float exs[4][CAP * 4];
    int wv = threadIdx.x >> 6;
    int wid = blockIdx.x * 4 + wv;
    if (wid >= n) return;
    int lane = threadIdx.x & 63;
    int st = rowptr[wid], en = rowptr[wid + 1];
    float4 dv = *(const float4*)&Dv[wid * 4];

    // pass 1: e per edge (lane-strided), raw e -> reg (iter 0) / LDS; track max
    float4 m = make_float4(-INFINITY, -INFINITY, -INFINITY, -INFINITY);
    float4 e0;
    int nit = 0;
    for (int i = st + lane; i < en; i += 64) {
        int src = csr[i];
        float4 sv = *(const float4*)&S[src * 4];
        float4 e;
        e.x = lrelu(sv.x + dv.x, LRELU_ATT);
        e.y = lrelu(sv.y + dv.y, LRELU_ATT);
        e.z = lrelu(sv.z + dv.z, LRELU_ATT);
        e.w = lrelu(sv.w + dv.w, LRELU_ATT);
        int pos = i - st;
        if (nit == 0) e0 = e;
        else if (pos < CAP) *(float4*)&exs[wv][pos * 4] = e;
        m.x = fmaxf(m.x, e.x); m.y = fmaxf(m.y, e.y);
        m.z = fmaxf(m.z, e.z); m.w = fmaxf(m.w, e.w);
        nit++;
    }
#pragma unroll
    for (int o = 32; o; o >>= 1) {
        m.x = fmaxf(m.x, __shfl_xor(m.x, o, 64));
        m.y = fmaxf(m.y, __shfl_xor(m.y, o, 64));
        m.z = fmaxf(m.z, __shfl_xor(m.z, o, 64));
        m.w = fmaxf(m.w, __shfl_xor(m.w, o, 64));
    }
    // pass 2: ex = exp(e - m) -> LDS; accumulate denom
    float4 den = make_float4(0.f, 0.f, 0.f, 0.f);
    int k = 0;
    for (int i = st + lane; i < en; i += 64) {
        int pos = i - st;
        float4 e;
        if (k == 0) e = e0;
        else if (pos < CAP) e = *(const float4*)&exs[wv][pos * 4];
        else {
            int src = csr[i];
            float4 sv = *(const float4*)&S[src * 4];
            e.x = lrelu(sv.x + dv.x, LRELU_ATT);
            e.y = lrelu(sv.y + dv.y, LRELU_ATT);
            e.z = lrelu(sv.z + dv.z, LRELU_ATT);
            e.w = lrelu(sv.w + dv.w, LRELU_ATT);
        }
        float4 ex;
        ex.x = __expf(e.x - m.x); ex.y = __expf(e.y - m.y);
        ex.z = __expf(e.z - m.z); ex.w = __expf(e.w - m.w);
        den.x += ex.x; den.y += ex.y; den.z += ex.z; den.w += ex.w;
        if (pos < CAP) *(float4*)&exs[wv][pos * 4] = ex;
        k++;
    }
#pragma unroll
    for (int o = 32; o; o >>= 1) {
        den.x += __shfl_xor(den.x, o, 64);
        den.y += __shfl_xor(den.y, o, 64);
        den.z += __shfl_xor(den.z, o, 64);
        den.w += __shfl_xor(den.w, o, 64);
    }
    // pass 3: 2 edges per iter; half-wave per edge, 4 channels per lane
    int half = lane >> 5;
    int cl = (lane & 31) * 4;
    int hd = (lane & 31) >> 3;
    float mh = sel4(m, hd), dh = sel4(dv, hd), denh = sel4(den, hd);
    float4 acc = make_float4(0.f, 0.f, 0.f, 0.f);
    for (int i = st; i < en; i += 2) {
        int e_i = i + half;
        if (e_i < en) {
            int pos = e_i - st;
            int src = csr[e_i];
            float p;
            if (pos < CAP) p = exs[wv][pos * 4 + hd];
            else p = __expf(lrelu(S[src * 4 + hd] + dh, LRELU_ATT) - mh);
            ushort4 hv = *(const ushort4*)&Hb[src * 128 + cl];
            acc.x = fmaf(p, bf2f(hv.x), acc.x);
            acc.y = fmaf(p, bf2f(hv.y), acc.y);
            acc.z = fmaf(p, bf2f(hv.z), acc.z);
            acc.w = fmaf(p, bf2f(hv.w), acc.w);
        }
    }
    acc.x += __shfl_xor(acc.x, 32, 64);
    acc.y += __shfl_xor(acc.y, 32, 64);
    acc.z += __shfl_xor(acc.z, 32, 64);
    acc.w += __shfl_xor(acc.w, 32, 64);
    if (lane < 32) {
        float r = 1.f / denh;
        float4 bv = *(const float4*)&bias[cl];
        float4 o;
        o.x = lrelu(acc.x * r + bv.x, LRELU_ACT);
        o.y = lrelu(acc.y * r + bv.y, LRELU_ACT);
        o.z = lrelu(acc.z * r + bv.z, LRELU_ACT);
        o.w = lrelu(acc.w * r + bv.w, LRELU_ACT);
        *(float4*)&Out[wid * 128 + cl] = o;
    }
}

// ---------------- graph embedding: segment max over sorted batch ----------------
__global__ void ge_max_k(const float* __restrict__ Hf, const int* __restrict__ batch,
                         float* __restrict__ ge, int n) {
    int c = threadIdx.x & 127;
    int rh = threadIdx.x >> 7;  // 0..1
    int node0 = blockIdx.x * 128;
    int hi = min(node0 + 128, n);
    int gid = -1;
    float mv = -INFINITY;
    for (int r = node0 + rh; r < hi; r += 2) {
        int g = batch[r];
        if (g != gid) {
            if (gid >= 0) atomicMaxF(&ge[gid * 128 + c], mv);
            gid = g;
            mv = -INFINITY;
        }
        mv = fmaxf(mv, Hf[r * 128 + c]);
    }
    if (gid >= 0) atomicMaxF(&ge[gid * 128 + c], mv);
}

__global__ void ei_copy_k(const int* __restrict__ ei, float* __restrict__ out, int m) {
    int i = (blockIdx.x * blockDim.x + threadIdx.x) * 4;
    if (i + 3 < m) {
        int4 v = *(const int4*)&ei[i];
        float4 o = make_float4((float)v.x, (float)v.y, (float)v.z, (float)v.w);
        *(float4*)&out[i] = o;
    } else {
        for (; i < m; i++) out[i] = (float)ei[i];
    }
}

extern "C" void kernel_launch(void* const* d_in, const int* in_sizes, int n_in,
                              void* d_out, int out_size, void* d_ws, size_t ws_size,
                              hipStream_t stream) {
    const float* x = (const float*)d_in[0];
    const int* ei = (const int*)d_in[1];
    const int* batch = (const int*)d_in[2];
    const float* Wm[3]   = {(const float*)d_in[3], (const float*)d_in[7],  (const float*)d_in[11]};
    const float* asrc[3] = {(const float*)d_in[4], (const float*)d_in[8],  (const float*)d_in[12]};
    const float* adst[3] = {(const float*)d_in[5], (const float*)d_in[9],  (const float*)d_in[13]};
    const float* bias[3] = {(const float*)d_in[6], (const float*)d_in[10], (const float*)d_in[14]};

    const int n = in_sizes[2];          // 50000 nodes
    const int E = in_sizes[1] / 2;      // 800000 edges
    const int ne = E + n;               // + self loops
    const int G = (out_size - n * 128 - 2 * E) / 128;  // 64 graphs

    // workspace layout
    char* w = (char*)d_ws;
    float* Xact = (float*)w;          w += (size_t)n * 128 * 4;
    unsigned short* Hb = (unsigned short*)w; w += (size_t)n * 128 * 2;
    float* S    = (float*)w; w += (size_t)n * 4 * 4;
    float* D    = (float*)w; w += (size_t)n * 4 * 4;
    int* counts = (int*)w;   w += (size_t)n * 4;
    int* pre    = (int*)w;   w += (size_t)n * 4;
    int* rowptr = (int*)w;   w += (size_t)(n + 1) * 4;
    int* cursor = (int*)w;   w += (size_t)n * 4;
    int* bsum   = (int*)w;   w += 256 * 4;
    int* csr    = (int*)w;   w += (size_t)ne * 4;

    float* out   = (float*)d_out;
    float* ge    = out;
    float* hout  = out + (size_t)G * 128;
    float* eiout = out + (size_t)G * 128 + (size_t)n * 128;

    // ---- CSR build (once) ----
    int nb = (n + 255) / 256;
    fill_i_k<<<nb, 256, 0, stream>>>(counts, 1, n);   // self-loops
    hist_k<<<(E + 255) / 256, 256, 0, stream>>>(ei, counts, E);
    scan1_k<<<nb, 256, 0, stream>>>(counts, pre, bsum, n);
    scan2_k<<<1, 256, 0, stream>>>(bsum, nb);
    scan3_k<<<nb, 256, 0, stream>>>(pre, bsum, rowptr, n);
    csr_init_k<<<nb, 256, 0, stream>>>(rowptr, csr, cursor, n);
    scatter_k<<<(E + 255) / 256, 256, 0, stream>>>(ei, cursor, csr, E);
    sort_k<<<(n + 3) / 4, 256, 0, stream>>>(rowptr, csr, n);

    // ---- 3 GAT layers ----
    const float* xin = x;
    for (int L = 0; L < 3; L++) {
        gemm_k<<<(n + 31) / 32, 256, 0, stream>>>(xin, Wm[L], asrc[L], adst[L], Hb, S, D, n);
        float* xnext = (L == 2) ? hout : Xact;
        attn_agg_k<<<(n + 3) / 4, 256, 0, stream>>>(rowptr, csr, S, D, Hb, bias[L], xnext, n);
        xin = xnext;
    }

    // ---- readout ----
    fill_f_k<<<(G * 128 + 255) / 256, 256, 0, stream>>>(ge, -INFINITY, G * 128);
    ge_max_k<<<(n + 127) / 128, 256, 0, stream>>>(hout, batch, ge, n);
    ei_copy_k<<<(2 * E / 4 + 255) / 256, 256, 0, stream>>>(ei, eiout, 2 * E);
}

// Round 5
// 396.036 us; speedup vs baseline: 9.7791x; 1.1585x over previous
//
#include <hip/hip_runtime.h>
#include <math.h>
#include <limits.h>

#define LRELU_ATT 0.2f
#define LRELU_ACT 0.01f
#define CAP 64    // cached alphas per dst in LDS (deg > CAP falls back to recompute)
#define DPB 16    // dsts per block in attn_agg

__device__ __forceinline__ float lrelu(float x, float s) { return x > 0.f ? x : x * s; }

__device__ __forceinline__ void atomicMaxF(float* addr, float val) {
    int* ai = (int*)addr;
    int old = *(volatile int*)ai;
    while (__int_as_float(old) < val) {
        int assumed = old;
        old = atomicCAS(ai, assumed, __float_as_int(val));
        if (old == assumed) break;
    }
}

__device__ __forceinline__ unsigned short f2bf(float f) {
    union { float f; unsigned u; } v; v.f = f;
    unsigned r = v.u + 0x7FFF + ((v.u >> 16) & 1);   // RNE
    return (unsigned short)(r >> 16);
}
__device__ __forceinline__ float bflo(unsigned u) {
    union { unsigned u; float f; } v; v.u = u << 16;
    return v.f;
}
__device__ __forceinline__ float bfhi(unsigned u) {
    union { unsigned u; float f; } v; v.u = u & 0xffff0000u;
    return v.f;
}

// ---- GEMM + fused s/d epilogue: Hb[n,128](bf16) = X@W;  S,D[n,4] = head-dots ----
__global__ __launch_bounds__(256) void gemm_k(const float* __restrict__ X,
                                              const float* __restrict__ Wm,
                                              const float* __restrict__ a_src,
                                              const float* __restrict__ a_dst,
                                              unsigned short* __restrict__ Hb,
                                              float* __restrict__ S,
                                              float* __restrict__ D, int n) {
    __shared__ float sW[32 * 128];
    __shared__ float sX[32 * 32];
    __shared__ float sa[128], sb[128];
    if (threadIdx.x < 128) {
        sa[threadIdx.x] = a_src[threadIdx.x];
        sb[threadIdx.x] = a_dst[threadIdx.x];
    }
    int row0 = blockIdx.x * 32;
    int rt = threadIdx.x >> 5;   // 0..7 -> rows rt*4..rt*4+3
    int ct = threadIdx.x & 31;   // cols ct*4..ct*4+3
    int c0 = ct * 4;
    float4 acc[4];
#pragma unroll
    for (int i = 0; i < 4; i++) acc[i] = make_float4(0.f, 0.f, 0.f, 0.f);

    for (int k0 = 0; k0 < 128; k0 += 32) {
        __syncthreads();
        for (int i = threadIdx.x * 4; i < 32 * 128; i += 1024)
            *(float4*)&sW[i] = *(const float4*)&Wm[(k0 + (i >> 7)) * 128 + (i & 127)];
        {
            int i = threadIdx.x * 4;   // covers 32*32 exactly
            int r = i >> 5, kk = i & 31;
            int gr = row0 + r;
            float4 v = make_float4(0.f, 0.f, 0.f, 0.f);
            if (gr < n) v = *(const float4*)&X[gr * 128 + k0 + kk];
            *(float4*)&sX[i] = v;
        }
        __syncthreads();
#pragma unroll
        for (int kk = 0; kk < 32; kk += 4) {
            float4 w0 = *(const float4*)&sW[(kk + 0) * 128 + c0];
            float4 w1 = *(const float4*)&sW[(kk + 1) * 128 + c0];
            float4 w2 = *(const float4*)&sW[(kk + 2) * 128 + c0];
            float4 w3 = *(const float4*)&sW[(kk + 3) * 128 + c0];
#pragma unroll
            for (int i = 0; i < 4; i++) {
                float4 xv = *(const float4*)&sX[(rt * 4 + i) * 32 + kk];
                acc[i].x = fmaf(xv.x, w0.x, acc[i].x);
                acc[i].y = fmaf(xv.x, w0.y, acc[i].y);
                acc[i].z = fmaf(xv.x, w0.z, acc[i].z);
                acc[i].w = fmaf(xv.x, w0.w, acc[i].w);
                acc[i].x = fmaf(xv.y, w1.x, acc[i].x);
                acc[i].y = fmaf(xv.y, w1.y, acc[i].y);
                acc[i].z = fmaf(xv.y, w1.z, acc[i].z);
                acc[i].w = fmaf(xv.y, w1.w, acc[i].w);
                acc[i].x = fmaf(xv.z, w2.x, acc[i].x);
                acc[i].y = fmaf(xv.z, w2.y, acc[i].y);
                acc[i].z = fmaf(xv.z, w2.z, acc[i].z);
                acc[i].w = fmaf(xv.z, w2.w, acc[i].w);
                acc[i].x = fmaf(xv.w, w3.x, acc[i].x);
                acc[i].y = fmaf(xv.w, w3.y, acc[i].y);
                acc[i].z = fmaf(xv.w, w3.z, acc[i].z);
                acc[i].w = fmaf(xv.w, w3.w, acc[i].w);
            }
        }
    }
    // fused s/d epilogue: reduce over the 8 lanes sharing a head (ct bits 0..2)
    float sp[4], dp[4];
    const float* ap = &sa[c0];
    const float* bp = &sb[c0];
#pragma unroll
    for (int i = 0; i < 4; i++) {
        sp[i] = acc[i].x * ap[0] + acc[i].y * ap[1] + acc[i].z * ap[2] + acc[i].w * ap[3];
        dp[i] = acc[i].x * bp[0] + acc[i].y * bp[1] + acc[i].z * bp[2] + acc[i].w * bp[3];
    }
#pragma unroll
    for (int o = 1; o < 8; o <<= 1) {
#pragma unroll
        for (int i = 0; i < 4; i++) {
            sp[i] += __shfl_xor(sp[i], o, 64);
            dp[i] += __shfl_xor(dp[i], o, 64);
        }
    }
    int hd = ct >> 3;
#pragma unroll
    for (int i = 0; i < 4; i++) {
        int gr = row0 + rt * 4 + i;
        if (gr < n) {
            ushort4 hb;
            hb.x = f2bf(acc[i].x); hb.y = f2bf(acc[i].y);
            hb.z = f2bf(acc[i].z); hb.w = f2bf(acc[i].w);
            *(ushort4*)&Hb[gr * 128 + c0] = hb;
            if ((ct & 7) == 0) {
                S[gr * 4 + hd] = sp[i];
                D[gr * 4 + hd] = dp[i];
            }
        }
    }
}

__global__ void fill_f_k(float* __restrict__ p, float v, int cnt) {
    int i = blockIdx.x * blockDim.x + threadIdx.x;
    if (i < cnt) p[i] = v;
}
__global__ void fill_i_k(int* __restrict__ p, int v, int cnt) {
    int i = blockIdx.x * blockDim.x + threadIdx.x;
    if (i < cnt) p[i] = v;
}

// ---------------- CSR build ----------------
__global__ void hist_k(const int* __restrict__ ei, int* __restrict__ counts, int E) {
    int e = blockIdx.x * blockDim.x + threadIdx.x;
    if (e < E) atomicAdd(&counts[ei[E + e]], 1);
}
__global__ void scan1_k(const int* __restrict__ in, int* __restrict__ pre,
                        int* __restrict__ bsum, int n) {
    __shared__ int s[256];
    int i = blockIdx.x * 256 + threadIdx.x;
    int v = (i < n) ? in[i] : 0;
    s[threadIdx.x] = v;
    __syncthreads();
    for (int o = 1; o < 256; o <<= 1) {
        int t = (threadIdx.x >= o) ? s[threadIdx.x - o] : 0;
        __syncthreads();
        s[threadIdx.x] += t;
        __syncthreads();
    }
    if (i < n) pre[i] = s[threadIdx.x];
    if (threadIdx.x == 255) bsum[blockIdx.x] = s[255];
}
__global__ void scan2_k(int* __restrict__ bsum, int nb) {
    __shared__ int s[256];
    int v = (threadIdx.x < nb) ? bsum[threadIdx.x] : 0;
    s[threadIdx.x] = v;
    __syncthreads();
    for (int o = 1; o < 256; o <<= 1) {
        int t = (threadIdx.x >= o) ? s[threadIdx.x - o] : 0;
        __syncthreads();
        s[threadIdx.x] += t;
        __syncthreads();
    }
    if (threadIdx.x < nb) bsum[threadIdx.x] = s[threadIdx.x];
}
__global__ void scan3_k(const int* __restrict__ pre, const int* __restrict__ bsum,
                        int* __restrict__ rowptr, int n) {
    int i = blockIdx.x * 256 + threadIdx.x;
    if (i < n) {
        int off = blockIdx.x ? bsum[blockIdx.x - 1] : 0;
        rowptr[i + 1] = pre[i] + off;
        if (i == 0) rowptr[0] = 0;
    }
}
__global__ void csr_init_k(const int* __restrict__ rowptr, int* __restrict__ csr,
                           int* __restrict__ cursor, int n) {
    int i = blockIdx.x * blockDim.x + threadIdx.x;
    if (i < n) {
        int p = rowptr[i];
        csr[p] = i;          // self loop
        cursor[i] = p + 1;
    }
}
__global__ void scatter_k(const int* __restrict__ ei, int* __restrict__ cursor,
                          int* __restrict__ csr, int E) {
    int e = blockIdx.x * blockDim.x + threadIdx.x;
    if (e < E) {
        int dst = ei[E + e];
        int pos = atomicAdd(&cursor[dst], 1);
        csr[pos] = ei[e];
    }
}
// canonicalize segment order for deterministic fp sums
__global__ __launch_bounds__(256) void sort_k(const int* __restrict__ rowptr,
                                              int* __restrict__ csr, int n) {
    int wid = (blockIdx.x * blockDim.x + threadIdx.x) >> 6;
    int lane = threadIdx.x & 63;
    if (wid >= n) return;
    int st = rowptr[wid], en = rowptr[wid + 1];
    int deg = en - st;
    if (deg <= 1) return;
    if (deg <= 64) {
        int v = (lane < deg) ? csr[st + lane] : INT_MAX;
        for (int p = 0; p < deg; p++) {
            int par;
            if ((p & 1) == 0) par = lane ^ 1;
            else {
                if (lane & 1) par = (lane == 63) ? lane : lane + 1;
                else par = (lane == 0) ? lane : lane - 1;
            }
            int o = __shfl(v, par, 64);
            if (par != lane) v = (lane < par) ? min(v, o) : max(v, o);
        }
        if (lane < deg) csr[st + lane] = v;
    } else if (lane == 0) {
        for (int i = st + 1; i < en; i++) {
            int key = csr[i];
            int j = i - 1;
            while (j >= st && csr[j] > key) { csr[j + 1] = csr[j]; j--; }
            csr[j + 1] = key;
        }
    }
}

// ---- fused softmax + aggregate + bias + act ----
// Phase 1: 16 dsts/block, 16-lane group per dst -> alpha (pre-divided) in LDS.
// Phase 2: each wave aggregates 4 dsts, 4 edges in flight, ushort8/lane.
__global__ __launch_bounds__(256) void attn_agg_k(const int* __restrict__ rowptr,
                                                  const int* __restrict__ csr,
                                                  const float* __restrict__ S,
                                                  const float* __restrict__ Dv,
                                                  const unsigned short* __restrict__ Hb,
                                                  const float* __restrict__ bias,
                                                  float* __restrict__ Out, int n) {
    __shared__ float al[DPB][CAP * 4];
    __shared__ float sm[DPB][4], srd[DPB][4], sdv[DPB][4];
    __shared__ int srp[DPB + 1];
    int base = blockIdx.x * DPB;
    if (threadIdx.x <= DPB) {
        int idx = base + threadIdx.x;
        srp[threadIdx.x] = rowptr[idx > n ? n : idx];
    }
    __syncthreads();

    // ---- phase 1: stats ----
    {
        int g = threadIdx.x >> 4;     // 0..15
        int l = threadIdx.x & 15;
        int dst = base + g;
        if (dst < n) {
            int st = srp[g], en = srp[g + 1];
            int deg = en - st;
            float4 dv = *(const float4*)&Dv[dst * 4];
            float4 m = make_float4(-INFINITY, -INFINITY, -INFINITY, -INFINITY);
            for (int pos = l; pos < deg; pos += 16) {
                int src = csr[st + pos];
                float4 sv = *(const float4*)&S[src * 4];
                float4 e;
                e.x = lrelu(sv.x + dv.x, LRELU_ATT);
                e.y = lrelu(sv.y + dv.y, LRELU_ATT);
                e.z = lrelu(sv.z + dv.z, LRELU_ATT);
                e.w = lrelu(sv.w + dv.w, LRELU_ATT);
                if (pos < CAP) *(float4*)&al[g][pos * 4] = e;
                m.x = fmaxf(m.x, e.x); m.y = fmaxf(m.y, e.y);
                m.z = fmaxf(m.z, e.z); m.w = fmaxf(m.w, e.w);
            }
#pragma unroll
            for (int o = 1; o < 16; o <<= 1) {
                m.x = fmaxf(m.x, __shfl_xor(m.x, o, 64));
                m.y = fmaxf(m.y, __shfl_xor(m.y, o, 64));
                m.z = fmaxf(m.z, __shfl_xor(m.z, o, 64));
                m.w = fmaxf(m.w, __shfl_xor(m.w, o, 64));
            }
            float4 den = make_float4(0.f, 0.f, 0.f, 0.f);
            for (int pos = l; pos < deg; pos += 16) {
                float4 e;
                if (pos < CAP) e = *(const float4*)&al[g][pos * 4];
                else {
                    int src = csr[st + pos];
                    float4 sv = *(const float4*)&S[src * 4];
                    e.x = lrelu(sv.x + dv.x, LRELU_ATT);
                    e.y = lrelu(sv.y + dv.y, LRELU_ATT);
                    e.z = lrelu(sv.z + dv.z, LRELU_ATT);
                    e.w = lrelu(sv.w + dv.w, LRELU_ATT);
                }
                float4 ex;
                ex.x = __expf(e.x - m.x); ex.y = __expf(e.y - m.y);
                ex.z = __expf(e.z - m.z); ex.w = __expf(e.w - m.w);
                den.x += ex.x; den.y += ex.y; den.z += ex.z; den.w += ex.w;
                if (pos < CAP) *(float4*)&al[g][pos * 4] = ex;
            }
#pragma unroll
            for (int o = 1; o < 16; o <<= 1) {
                den.x += __shfl_xor(den.x, o, 64);
                den.y += __shfl_xor(den.y, o, 64);
                den.z += __shfl_xor(den.z, o, 64);
                den.w += __shfl_xor(den.w, o, 64);
            }
            float4 rd;
            rd.x = 1.f / den.x; rd.y = 1.f / den.y;
            rd.z = 1.f / den.z; rd.w = 1.f / den.w;
            int lim = deg < CAP ? deg : CAP;
            for (int pos = l; pos < lim; pos += 16) {
                float4 ex = *(const float4*)&al[g][pos * 4];
                ex.x *= rd.x; ex.y *= rd.y; ex.z *= rd.z; ex.w *= rd.w;
                *(float4*)&al[g][pos * 4] = ex;
            }
            if (l == 0) {
                *(float4*)&sm[g][0] = m;
                *(float4*)&srd[g][0] = rd;
                *(float4*)&sdv[g][0] = dv;
            }
        }
    }
    __syncthreads();

    // ---- phase 2: aggregation, 4 dsts per wave, 4 edges/iter ----
    int w = threadIdx.x >> 6;
    int lane = threadIdx.x & 63;
    int slot = lane >> 4;        // edge slot 0..3
    int l16 = lane & 15;
    int ch0 = l16 * 8;           // 8 channels per lane
    int hd = l16 >> 2;           // head of this lane's channels
#pragma unroll
    for (int j = 0; j < 4; j++) {
        int g2 = w * 4 + j;
        int dst = base + g2;
        if (dst >= n) break;
        int st = srp[g2], en = srp[g2 + 1];
        int deg = en - st;
        float4 a0 = make_float4(0.f, 0.f, 0.f, 0.f);
        float4 a1 = make_float4(0.f, 0.f, 0.f, 0.f);
        for (int pos = slot; pos < deg; pos += 4) {
            int src = csr[st + pos];
            float a;
            if (pos < CAP) a = al[g2][pos * 4 + hd];
            else a = __expf(lrelu(S[src * 4 + hd] + sdv[g2][hd], LRELU_ATT) - sm[g2][hd]) * srd[g2][hd];
            uint4 hv = *(const uint4*)&Hb[src * 128 + ch0];
            a0.x = fmaf(a, bflo(hv.x), a0.x);
            a0.y = fmaf(a, bfhi(hv.x), a0.y);
            a0.z = fmaf(a, bflo(hv.y), a0.z);
            a0.w = fmaf(a, bfhi(hv.y), a0.w);
            a1.x = fmaf(a, bflo(hv.z), a1.x);
            a1.y = fmaf(a, bfhi(hv.z), a1.y);
            a1.z = fmaf(a, bflo(hv.w), a1.z);
            a1.w = fmaf(a, bfhi(hv.w), a1.w);
        }
#pragma unroll
        for (int o = 16; o <= 32; o <<= 1) {
            a0.x += __shfl_xor(a0.x, o, 64);
            a0.y += __shfl_xor(a0.y, o, 64);
            a0.z += __shfl_xor(a0.z, o, 64);
            a0.w += __shfl_xor(a0.w, o, 64);
            a1.x += __shfl_xor(a1.x, o, 64);
            a1.y += __shfl_xor(a1.y, o, 64);
            a1.z += __shfl_xor(a1.z, o, 64);
            a1.w += __shfl_xor(a1.w, o, 64);
        }
        if (slot == 0) {
            float4 b0 = *(const float4*)&bias[ch0];
            float4 b1 = *(const float4*)&bias[ch0 + 4];
            float4 o0, o1;
            o0.x = lrelu(a0.x + b0.x, LRELU_ACT);
            o0.y = lrelu(a0.y + b0.y, LRELU_ACT);
            o0.z = lrelu(a0.z + b0.z, LRELU_ACT);
            o0.w = lrelu(a0.w + b0.w, LRELU_ACT);
            o1.x = lrelu(a1.x + b1.x, LRELU_ACT);
            o1.y = lrelu(a1.y + b1.y, LRELU_ACT);
            o1.z = lrelu(a1.z + b1.z, LRELU_ACT);
            o1.w = lrelu(a1.w + b1.w, LRELU_ACT);
            *(float4*)&Out[dst * 128 + ch0] = o0;
            *(float4*)&Out[dst * 128 + ch0 + 4] = o1;
        }
    }
}

// ---------------- graph embedding: segment max over sorted batch ----------------
__global__ void ge_max_k(const float* __restrict__ Hf, const int* __restrict__ batch,
                         float* __restrict__ ge, int n) {
    int c = threadIdx.x & 127;
    int rh = threadIdx.x >> 7;  // 0..1
    int node0 = blockIdx.x * 128;
    int hi = min(node0 + 128, n);
    int gid = -1;
    float mv = -INFINITY;
    for (int r = node0 + rh; r < hi; r += 2) {
        int g = batch[r];
        if (g != gid) {
            if (gid >= 0) atomicMaxF(&ge[gid * 128 + c], mv);
            gid = g;
            mv = -INFINITY;
        }
        mv = fmaxf(mv, Hf[r * 128 + c]);
    }
    if (gid >= 0) atomicMaxF(&ge[gid * 128 + c], mv);
}

__global__ void ei_copy_k(const int* __restrict__ ei, float* __restrict__ out, int m) {
    int i = (blockIdx.x * blockDim.x + threadIdx.x) * 4;
    if (i + 3 < m) {
        int4 v = *(const int4*)&ei[i];
        float4 o = make_float4((float)v.x, (float)v.y, (float)v.z, (float)v.w);
        *(float4*)&out[i] = o;
    } else {
        for (; i < m; i++) out[i] = (float)ei[i];
    }
}

extern "C" void kernel_launch(void* const* d_in, const int* in_sizes, int n_in,
                              void* d_out, int out_size, void* d_ws, size_t ws_size,
                              hipStream_t stream) {
    const float* x = (const float*)d_in[0];
    const int* ei = (const int*)d_in[1];
    const int* batch = (const int*)d_in[2];
    const float* Wm[3]   = {(const float*)d_in[3], (const float*)d_in[7],  (const float*)d_in[11]};
    const float* asrc[3] = {(const float*)d_in[4], (const float*)d_in[8],  (const float*)d_in[12]};
    const float* adst[3] = {(const float*)d_in[5], (const float*)d_in[9],  (const float*)d_in[13]};
    const float* bias[3] = {(const float*)d_in[6], (const float*)d_in[10], (const float*)d_in[14]};

    const int n = in_sizes[2];          // 50000 nodes
    const int E = in_sizes[1] / 2;      // 800000 edges
    const int ne = E + n;               // + self loops
    const int G = (out_size - n * 128 - 2 * E) / 128;  // 64 graphs

    // workspace layout
    char* w = (char*)d_ws;
    float* Xact = (float*)w;          w += (size_t)n * 128 * 4;
    unsigned short* Hb = (unsigned short*)w; w += (size_t)n * 128 * 2;
    float* S    = (float*)w; w += (size_t)n * 4 * 4;
    float* D    = (float*)w; w += (size_t)n * 4 * 4;
    int* counts = (int*)w;   w += (size_t)n * 4;
    int* pre    = (int*)w;   w += (size_t)n * 4;
    int* rowptr = (int*)w;   w += (size_t)(n + 1) * 4;
    int* cursor = (int*)w;   w += (size_t)n * 4;
    int* bsum   = (int*)w;   w += 256 * 4;
    int* csr    = (int*)w;   w += (size_t)ne * 4;

    float* out   = (float*)d_out;
    float* ge    = out;
    float* hout  = out + (size_t)G * 128;
    float* eiout = out + (size_t)G * 128 + (size_t)n * 128;

    // ---- CSR build (once) ----
    int nb = (n + 255) / 256;
    fill_i_k<<<nb, 256, 0, stream>>>(counts, 1, n);   // self-loops
    hist_k<<<(E + 255) / 256, 256, 0, stream>>>(ei, counts, E);
    scan1_k<<<nb, 256, 0, stream>>>(counts, pre, bsum, n);
    scan2_k<<<1, 256, 0, stream>>>(bsum, nb);
    scan3_k<<<nb, 256, 0, stream>>>(pre, bsum, rowptr, n);
    csr_init_k<<<nb, 256, 0, stream>>>(rowptr, csr, cursor, n);
    scatter_k<<<(E + 255) / 256, 256, 0, stream>>>(ei, cursor, csr, E);
    sort_k<<<(n + 3) / 4, 256, 0, stream>>>(rowptr, csr, n);

    // ---- 3 GAT layers ----
    const float* xin = x;
    for (int L = 0; L < 3; L++) {
        gemm_k<<<(n + 31) / 32, 256, 0, stream>>>(xin, Wm[L], asrc[L], adst[L], Hb, S, D, n);
        float* xnext = (L == 2) ? hout : Xact;
        attn_agg_k<<<(n + DPB - 1) / DPB, 256, 0, stream>>>(rowptr, csr, S, D, Hb, bias[L], xnext, n);
        xin = xnext;
    }

    // ---- readout ----
    fill_f_k<<<(G * 128 + 255) / 256, 256, 0, stream>>>(ge, -INFINITY, G * 128);
    ge_max_k<<<(n + 127) / 128, 256, 0, stream>>>(hout, batch, ge, n);
    ei_copy_k<<<(2 * E / 4 + 255) / 256, 256, 0, stream>>>(ei, eiout, 2 * E);
}

// Round 6
// 362.080 us; speedup vs baseline: 10.6961x; 1.0938x over previous
//
#include <hip/hip_runtime.h>
#include <math.h>
#include <limits.h>

#define LRELU_ATT 0.2f
#define LRELU_ACT 0.01f
#define CAP 64    // cached alphas per dst in LDS (deg > CAP falls back to recompute)
#define DPB 16    // dsts per block in attn_agg
#define NBMAX 512 // max buckets (n <= 65536, 128 dsts/bucket)
#define TILE 8192 // edges per bin_scatter block
#define BCAP 6528 // LDS capacity per bucket in bucket_csr (edges + selfs)

__device__ __forceinline__ float lrelu(float x, float s) { return x > 0.f ? x : x * s; }

__device__ __forceinline__ void atomicMaxF(float* addr, float val) {
    int* ai = (int*)addr;
    int old = *(volatile int*)ai;
    while (__int_as_float(old) < val) {
        int assumed = old;
        old = atomicCAS(ai, assumed, __float_as_int(val));
        if (old == assumed) break;
    }
}

__device__ __forceinline__ unsigned short f2bf(float f) {
    union { float f; unsigned u; } v; v.f = f;
    unsigned r = v.u + 0x7FFF + ((v.u >> 16) & 1);   // RNE
    return (unsigned short)(r >> 16);
}
__device__ __forceinline__ float bflo(unsigned u) {
    union { unsigned u; float f; } v; v.u = u << 16;
    return v.f;
}
__device__ __forceinline__ float bfhi(unsigned u) {
    union { unsigned u; float f; } v; v.u = u & 0xffff0000u;
    return v.f;
}

// inclusive scan of 512 ints in LDS with 256 threads; returns buffer holding result.
// caller must __syncthreads() after filling `a` and before calling.
__device__ __forceinline__ int* scan_incl_512(int* a, int* b, int tid) {
    int* in = a; int* out = b;
    for (int off = 1; off < 512; off <<= 1) {
        for (int i = tid; i < 512; i += 256)
            out[i] = in[i] + (i >= off ? in[i - off] : 0);
        __syncthreads();
        int* t = in; in = out; out = t;
    }
    return in;
}

// ---- GEMM + fused s/d epilogue: Hb[n,128](bf16) = X@W;  S,D[n,4] = head-dots ----
__global__ __launch_bounds__(256) void gemm_k(const float* __restrict__ X,
                                              const float* __restrict__ Wm,
                                              const float* __restrict__ a_src,
                                              const float* __restrict__ a_dst,
                                              unsigned short* __restrict__ Hb,
                                              float* __restrict__ S,
                                              float* __restrict__ D, int n) {
    __shared__ float sW[32 * 128];
    __shared__ float sX[32 * 32];
    __shared__ float sa[128], sb[128];
    if (threadIdx.x < 128) {
        sa[threadIdx.x] = a_src[threadIdx.x];
        sb[threadIdx.x] = a_dst[threadIdx.x];
    }
    int row0 = blockIdx.x * 32;
    int rt = threadIdx.x >> 5;   // 0..7 -> rows rt*4..rt*4+3
    int ct = threadIdx.x & 31;   // cols ct*4..ct*4+3
    int c0 = ct * 4;
    float4 acc[4];
#pragma unroll
    for (int i = 0; i < 4; i++) acc[i] = make_float4(0.f, 0.f, 0.f, 0.f);

    for (int k0 = 0; k0 < 128; k0 += 32) {
        __syncthreads();
        for (int i = threadIdx.x * 4; i < 32 * 128; i += 1024)
            *(float4*)&sW[i] = *(const float4*)&Wm[(k0 + (i >> 7)) * 128 + (i & 127)];
        {
            int i = threadIdx.x * 4;   // covers 32*32 exactly
            int r = i >> 5, kk = i & 31;
            int gr = row0 + r;
            float4 v = make_float4(0.f, 0.f, 0.f, 0.f);
            if (gr < n) v = *(const float4*)&X[gr * 128 + k0 + kk];
            *(float4*)&sX[i] = v;
        }
        __syncthreads();
#pragma unroll
        for (int kk = 0; kk < 32; kk += 4) {
            float4 w0 = *(const float4*)&sW[(kk + 0) * 128 + c0];
            float4 w1 = *(const float4*)&sW[(kk + 1) * 128 + c0];
            float4 w2 = *(const float4*)&sW[(kk + 2) * 128 + c0];
            float4 w3 = *(const float4*)&sW[(kk + 3) * 128 + c0];
#pragma unroll
            for (int i = 0; i < 4; i++) {
                float4 xv = *(const float4*)&sX[(rt * 4 + i) * 32 + kk];
                acc[i].x = fmaf(xv.x, w0.x, acc[i].x);
                acc[i].y = fmaf(xv.x, w0.y, acc[i].y);
                acc[i].z = fmaf(xv.x, w0.z, acc[i].z);
                acc[i].w = fmaf(xv.x, w0.w, acc[i].w);
                acc[i].x = fmaf(xv.y, w1.x, acc[i].x);
                acc[i].y = fmaf(xv.y, w1.y, acc[i].y);
                acc[i].z = fmaf(xv.y, w1.z, acc[i].z);
                acc[i].w = fmaf(xv.y, w1.w, acc[i].w);
                acc[i].x = fmaf(xv.z, w2.x, acc[i].x);
                acc[i].y = fmaf(xv.z, w2.y, acc[i].y);
                acc[i].z = fmaf(xv.z, w2.z, acc[i].z);
                acc[i].w = fmaf(xv.z, w2.w, acc[i].w);
                acc[i].x = fmaf(xv.w, w3.x, acc[i].x);
                acc[i].y = fmaf(xv.w, w3.y, acc[i].y);
                acc[i].z = fmaf(xv.w, w3.z, acc[i].z);
                acc[i].w = fmaf(xv.w, w3.w, acc[i].w);
            }
        }
    }
    // fused s/d epilogue: reduce over the 8 lanes sharing a head (ct bits 0..2)
    float sp[4], dp[4];
    const float* ap = &sa[c0];
    const float* bp = &sb[c0];
#pragma unroll
    for (int i = 0; i < 4; i++) {
        sp[i] = acc[i].x * ap[0] + acc[i].y * ap[1] + acc[i].z * ap[2] + acc[i].w * ap[3];
        dp[i] = acc[i].x * bp[0] + acc[i].y * bp[1] + acc[i].z * bp[2] + acc[i].w * bp[3];
    }
#pragma unroll
    for (int o = 1; o < 8; o <<= 1) {
#pragma unroll
        for (int i = 0; i < 4; i++) {
            sp[i] += __shfl_xor(sp[i], o, 64);
            dp[i] += __shfl_xor(dp[i], o, 64);
        }
    }
    int hd = ct >> 3;
#pragma unroll
    for (int i = 0; i < 4; i++) {
        int gr = row0 + rt * 4 + i;
        if (gr < n) {
            ushort4 hb;
            hb.x = f2bf(acc[i].x); hb.y = f2bf(acc[i].y);
            hb.z = f2bf(acc[i].z); hb.w = f2bf(acc[i].w);
            *(ushort4*)&Hb[gr * 128 + c0] = hb;
            if ((ct & 7) == 0) {
                S[gr * 4 + hd] = sp[i];
                D[gr * 4 + hd] = dp[i];
            }
        }
    }
}

__global__ void fill_f_k(float* __restrict__ p, float v, int cnt) {
    int i = blockIdx.x * blockDim.x + threadIdx.x;
    if (i < cnt) p[i] = v;
}
__global__ void fill_i_k(int* __restrict__ p, int v, int cnt) {
    int i = blockIdx.x * blockDim.x + threadIdx.x;
    if (i < cnt) p[i] = v;
}

// ---------------- CSR build: binned counting sort ----------------
// bucket = dst >> 7 (128 dsts per bucket)

__global__ void bhist_k(const int* __restrict__ ei, int* __restrict__ bcount, int E) {
    __shared__ int h[NBMAX];
    for (int i = threadIdx.x; i < NBMAX; i += 256) h[i] = 0;
    __syncthreads();
    for (int e = blockIdx.x * blockDim.x + threadIdx.x; e < E; e += gridDim.x * blockDim.x)
        atomicAdd(&h[ei[E + e] >> 7], 1);
    __syncthreads();
    for (int i = threadIdx.x; i < NBMAX; i += 256)
        if (h[i]) atomicAdd(&bcount[i], h[i]);
}

__global__ void bscan_k(const int* __restrict__ bcount, int* __restrict__ bbase,
                        int* __restrict__ cursor, int NB) {
    __shared__ int sa[512], sb[512];
    int tid = threadIdx.x;
    for (int i = tid; i < 512; i += 256) sa[i] = (i < NB) ? bcount[i] : 0;
    __syncthreads();
    int* inc = scan_incl_512(sa, sb, tid);
    for (int i = tid; i < NB; i += 256) {
        int ex = i ? inc[i - 1] : 0;
        bbase[i] = ex;
        cursor[i] = ex;
    }
    if (tid == 0) bbase[NB] = inc[NB - 1];
}

// tile -> LDS counting-sort by bucket -> bucket-grouped coalesced flush
__global__ __launch_bounds__(256) void bin_scatter_k(const int* __restrict__ ei,
                                                     int* __restrict__ cursor,
                                                     unsigned* __restrict__ binned, int E) {
    __shared__ int hist[NBMAX], excl[NBMAX], curl[NBMAX], gbase[NBMAX];
    __shared__ int sa[512], sb[512];
    __shared__ unsigned staged[TILE];
    int tid = threadIdx.x;
    int e0 = blockIdx.x * TILE;
    for (int i = tid; i < NBMAX; i += 256) hist[i] = 0;
    __syncthreads();
    unsigned keys[TILE / 256];
#pragma unroll
    for (int j = 0; j < TILE / 256; j++) {
        int e = e0 + j * 256 + tid;
        if (e < E) {
            unsigned dst = (unsigned)ei[E + e];
            unsigned src = (unsigned)ei[e];
            unsigned k = (dst << 16) | src;
            keys[j] = k;
            atomicAdd(&hist[k >> 23], 1);
        } else keys[j] = 0xFFFFFFFFu;
    }
    __syncthreads();
    for (int i = tid; i < 512; i += 256) sa[i] = hist[i];
    __syncthreads();
    int* inc = scan_incl_512(sa, sb, tid);
    for (int i = tid; i < NBMAX; i += 256) {
        int ex = i ? inc[i - 1] : 0;
        excl[i] = ex;
        curl[i] = ex;
    }
    __syncthreads();
#pragma unroll
    for (int j = 0; j < TILE / 256; j++) {
        unsigned k = keys[j];
        if (k != 0xFFFFFFFFu) {
            int b = k >> 23;
            int p = atomicAdd(&curl[b], 1);
            staged[p] = k;
        }
    }
    __syncthreads();
    for (int i = tid; i < NBMAX; i += 256) {
        int cnt = hist[i];
        if (cnt) gbase[i] = atomicAdd(&cursor[i], cnt);
    }
    __syncthreads();
    int total = inc[511];
    for (int p = tid; p < total; p += 256) {
        unsigned k = staged[p];
        int b = k >> 23;
        binned[gbase[b] + (p - excl[b])] = k;
    }
}

// one block per bucket: build 128 dst segments fully in LDS, canonical (dst,src) order
__global__ __launch_bounds__(256) void bucket_csr_k(const unsigned* __restrict__ binned,
                                                    const int* __restrict__ bbase,
                                                    int* __restrict__ rowptr,
                                                    int* __restrict__ csr,
                                                    int n, int NB) {
    __shared__ int outL[BCAP];
    __shared__ int sa[512], sb[512];
    __shared__ int lbase[130], cur[129];
    int b = blockIdx.x;
    int tid = threadIdx.x;
    int dst0 = b << 7;
    int ndst = min(128, n - dst0);
    int ebase = bbase[b], ecnt = bbase[b + 1] - ebase;
    // hist (+1 for the self loop of each dst)
    for (int i = tid; i < 512; i += 256) sa[i] = (i < ndst) ? 1 : 0;
    __syncthreads();
    for (int p = tid; p < ecnt; p += 256) {
        int ld = (int)(binned[ebase + p] >> 16) - dst0;
        atomicAdd(&sa[ld], 1);
    }
    __syncthreads();
    int* inc = scan_incl_512(sa, sb, tid);
    for (int i = tid; i < ndst; i += 256) {
        int ex = i ? inc[i - 1] : 0;
        lbase[i] = ex;
        cur[i] = ex;
    }
    if (tid == 0) lbase[ndst] = inc[ndst - 1];
    __syncthreads();
    int total = lbase[ndst];
    // append self loops
    for (int i = tid; i < ndst; i += 256) {
        int p = atomicAdd(&cur[i], 1);
        outL[p] = dst0 + i;
    }
    // append edges
    for (int p = tid; p < ecnt; p += 256) {
        unsigned k = binned[ebase + p];
        int ld = (int)(k >> 16) - dst0;
        int pos = atomicAdd(&cur[ld], 1);
        outL[pos] = (int)(k & 0xFFFFu);
    }
    __syncthreads();
    // canonical order: per-dst insertion sort (ascending src)
    for (int i = tid; i < ndst; i += 256) {
        int st = lbase[i], en = lbase[i + 1];
        for (int q = st + 1; q < en; q++) {
            int key = outL[q];
            int r = q - 1;
            while (r >= st && outL[r] > key) { outL[r + 1] = outL[r]; r--; }
            outL[r + 1] = key;
        }
    }
    __syncthreads();
    int gb = ebase + dst0;   // self loops of earlier buckets = dst0
    for (int p = tid; p < total; p += 256) csr[gb + p] = outL[p];
    for (int i = tid; i < ndst; i += 256) rowptr[dst0 + i] = gb + lbase[i];
    if (b == NB - 1 && tid == 0) rowptr[n] = gb + total;
}

// ---- fused softmax + aggregate + bias + act ----
__global__ __launch_bounds__(256) void attn_agg_k(const int* __restrict__ rowptr,
                                                  const int* __restrict__ csr,
                                                  const float* __restrict__ S,
                                                  const float* __restrict__ Dv,
                                                  const unsigned short* __restrict__ Hb,
                                                  const float* __restrict__ bias,
                                                  float* __restrict__ Out, int n) {
    __shared__ float al[DPB][CAP * 4];
    __shared__ float sm[DPB][4], srd[DPB][4], sdv[DPB][4];
    __shared__ int srp[DPB + 1];
    int base = blockIdx.x * DPB;
    if (threadIdx.x <= DPB) {
        int idx = base + threadIdx.x;
        srp[threadIdx.x] = rowptr[idx > n ? n : idx];
    }
    __syncthreads();

    // ---- phase 1: stats (16-lane group per dst) ----
    {
        int g = threadIdx.x >> 4;     // 0..15
        int l = threadIdx.x & 15;
        int dst = base + g;
        if (dst < n) {
            int st = srp[g], en = srp[g + 1];
            int deg = en - st;
            float4 dv = *(const float4*)&Dv[dst * 4];
            float4 m = make_float4(-INFINITY, -INFINITY, -INFINITY, -INFINITY);
            for (int pos = l; pos < deg; pos += 16) {
                int src = csr[st + pos];
                float4 sv = *(const float4*)&S[src * 4];
                float4 e;
                e.x = lrelu(sv.x + dv.x, LRELU_ATT);
                e.y = lrelu(sv.y + dv.y, LRELU_ATT);
                e.z = lrelu(sv.z + dv.z, LRELU_ATT);
                e.w = lrelu(sv.w + dv.w, LRELU_ATT);
                if (pos < CAP) *(float4*)&al[g][pos * 4] = e;
                m.x = fmaxf(m.x, e.x); m.y = fmaxf(m.y, e.y);
                m.z = fmaxf(m.z, e.z); m.w = fmaxf(m.w, e.w);
            }
#pragma unroll
            for (int o = 1; o < 16; o <<= 1) {
                m.x = fmaxf(m.x, __shfl_xor(m.x, o, 64));
                m.y = fmaxf(m.y, __shfl_xor(m.y, o, 64));
                m.z = fmaxf(m.z, __shfl_xor(m.z, o, 64));
                m.w = fmaxf(m.w, __shfl_xor(m.w, o, 64));
            }
            float4 den = make_float4(0.f, 0.f, 0.f, 0.f);
            for (int pos = l; pos < deg; pos += 16) {
                float4 e;
                if (pos < CAP) e = *(const float4*)&al[g][pos * 4];
                else {
                    int src = csr[st + pos];
                    float4 sv = *(const float4*)&S[src * 4];
                    e.x = lrelu(sv.x + dv.x, LRELU_ATT);
                    e.y = lrelu(sv.y + dv.y, LRELU_ATT);
                    e.z = lrelu(sv.z + dv.z, LRELU_ATT);
                    e.w = lrelu(sv.w + dv.w, LRELU_ATT);
                }
                float4 ex;
                ex.x = __expf(e.x - m.x); ex.y = __expf(e.y - m.y);
                ex.z = __expf(e.z - m.z); ex.w = __expf(e.w - m.w);
                den.x += ex.x; den.y += ex.y; den.z += ex.z; den.w += ex.w;
                if (pos < CAP) *(float4*)&al[g][pos * 4] = ex;
            }
#pragma unroll
            for (int o = 1; o < 16; o <<= 1) {
                den.x += __shfl_xor(den.x, o, 64);
                den.y += __shfl_xor(den.y, o, 64);
                den.z += __shfl_xor(den.z, o, 64);
                den.w += __shfl_xor(den.w, o, 64);
            }
            float4 rd;
            rd.x = 1.f / den.x; rd.y = 1.f / den.y;
            rd.z = 1.f / den.z; rd.w = 1.f / den.w;
            int lim = deg < CAP ? deg : CAP;
            for (int pos = l; pos < lim; pos += 16) {
                float4 ex = *(const float4*)&al[g][pos * 4];
                ex.x *= rd.x; ex.y *= rd.y; ex.z *= rd.z; ex.w *= rd.w;
                *(float4*)&al[g][pos * 4] = ex;
            }
            if (l == 0) {
                *(float4*)&sm[g][0] = m;
                *(float4*)&srd[g][0] = rd;
                *(float4*)&sdv[g][0] = dv;
            }
        }
    }
    __syncthreads();

    // ---- phase 2: aggregation, 4 dsts per wave, 4 edges/iter ----
    int w = threadIdx.x >> 6;
    int lane = threadIdx.x & 63;
    int slot = lane >> 4;        // edge slot 0..3
    int l16 = lane & 15;
    int ch0 = l16 * 8;           // 8 channels per lane
    int hd = l16 >> 2;           // head of this lane's channels
#pragma unroll
    for (int j = 0; j < 4; j++) {
        int g2 = w * 4 + j;
        int dst = base + g2;
        if (dst >= n) break;
        int st = srp[g2], en = srp[g2 + 1];
        int deg = en - st;
        float4 a0 = make_float4(0.f, 0.f, 0.f, 0.f);
        float4 a1 = make_float4(0.f, 0.f, 0.f, 0.f);
        for (int pos = slot; pos < deg; pos += 4) {
            int src = csr[st + pos];
            float a;
            if (pos < CAP) a = al[g2][pos * 4 + hd];
            else a = __expf(lrelu(S[src * 4 + hd] + sdv[g2][hd], LRELU_ATT) - sm[g2][hd]) * srd[g2][hd];
            uint4 hv = *(const uint4*)&Hb[src * 128 + ch0];
            a0.x = fmaf(a, bflo(hv.x), a0.x);
            a0.y = fmaf(a, bfhi(hv.x), a0.y);
            a0.z = fmaf(a, bflo(hv.y), a0.z);
            a0.w = fmaf(a, bfhi(hv.y), a0.w);
            a1.x = fmaf(a, bflo(hv.z), a1.x);
            a1.y = fmaf(a, bfhi(hv.z), a1.y);
            a1.z = fmaf(a, bflo(hv.w), a1.z);
            a1.w = fmaf(a, bfhi(hv.w), a1.w);
        }
#pragma unroll
        for (int o = 16; o <= 32; o <<= 1) {
            a0.x += __shfl_xor(a0.x, o, 64);
            a0.y += __shfl_xor(a0.y, o, 64);
            a0.z += __shfl_xor(a0.z, o, 64);
            a0.w += __shfl_xor(a0.w, o, 64);
            a1.x += __shfl_xor(a1.x, o, 64);
            a1.y += __shfl_xor(a1.y, o, 64);
            a1.z += __shfl_xor(a1.z, o, 64);
            a1.w += __shfl_xor(a1.w, o, 64);
        }
        if (slot == 0) {
            float4 b0 = *(const float4*)&bias[ch0];
            float4 b1 = *(const float4*)&bias[ch0 + 4];
            float4 o0, o1;
            o0.x = lrelu(a0.x + b0.x, LRELU_ACT);
            o0.y = lrelu(a0.y + b0.y, LRELU_ACT);
            o0.z = lrelu(a0.z + b0.z, LRELU_ACT);
            o0.w = lrelu(a0.w + b0.w, LRELU_ACT);
            o1.x = lrelu(a1.x + b1.x, LRELU_ACT);
            o1.y = lrelu(a1.y + b1.y, LRELU_ACT);
            o1.z = lrelu(a1.z + b1.z, LRELU_ACT);
            o1.w = lrelu(a1.w + b1.w, LRELU_ACT);
            *(float4*)&Out[dst * 128 + ch0] = o0;
            *(float4*)&Out[dst * 128 + ch0 + 4] = o1;
        }
    }
}

// ---------------- graph embedding: segment max over sorted batch ----------------
__global__ void ge_max_k(const float* __restrict__ Hf, const int* __restrict__ batch,
                         float* __restrict__ ge, int n) {
    int c = threadIdx.x & 127;
    int rh = threadIdx.x >> 7;  // 0..1
    int node0 = blockIdx.x * 128;
    int hi = min(node0 + 128, n);
    int gid = -1;
    float mv = -INFINITY;
    for (int r = node0 + rh; r < hi; r += 2) {
        int g = batch[r];
        if (g != gid) {
            if (gid >= 0) atomicMaxF(&ge[gid * 128 + c], mv);
            gid = g;
            mv = -INFINITY;
        }
        mv = fmaxf(mv, Hf[r * 128 + c]);
    }
    if (gid >= 0) atomicMaxF(&ge[gid * 128 + c], mv);
}

__global__ void ei_copy_k(const int* __restrict__ ei, float* __restrict__ out, int m) {
    int i = (blockIdx.x * blockDim.x + threadIdx.x) * 4;
    if (i + 3 < m) {
        int4 v = *(const int4*)&ei[i];
        float4 o = make_float4((float)v.x, (float)v.y, (float)v.z, (float)v.w);
        *(float4*)&out[i] = o;
    } else {
        for (; i < m; i++) out[i] = (float)ei[i];
    }
}

extern "C" void kernel_launch(void* const* d_in, const int* in_sizes, int n_in,
                              void* d_out, int out_size, void* d_ws, size_t ws_size,
                              hipStream_t stream) {
    const float* x = (const float*)d_in[0];
    const int* ei = (const int*)d_in[1];
    const int* batch = (const int*)d_in[2];
    const float* Wm[3]   = {(const float*)d_in[3], (const float*)d_in[7],  (const float*)d_in[11]};
    const float* asrc[3] = {(const float*)d_in[4], (const float*)d_in[8],  (const float*)d_in[12]};
    const float* adst[3] = {(const float*)d_in[5], (const float*)d_in[9],  (const float*)d_in[13]};
    const float* bias[3] = {(const float*)d_in[6], (const float*)d_in[10], (const float*)d_in[14]};

    const int n = in_sizes[2];          // 50000 nodes
    const int E = in_sizes[1] / 2;      // 800000 edges
    const int ne = E + n;               // + self loops
    const int G = (out_size - n * 128 - 2 * E) / 128;  // 64 graphs
    const int NB = (n + 127) >> 7;      // 391 buckets

    // workspace layout
    char* w = (char*)d_ws;
    float* Xact = (float*)w;          w += (size_t)n * 128 * 4;
    unsigned short* Hb = (unsigned short*)w; w += (size_t)n * 128 * 2;
    float* S    = (float*)w; w += (size_t)n * 4 * 4;
    float* D    = (float*)w; w += (size_t)n * 4 * 4;
    int* bcount = (int*)w;   w += NBMAX * 4;
    int* bbase  = (int*)w;   w += (NBMAX + 1) * 4;
    int* cursor = (int*)w;   w += NBMAX * 4;
    int* rowptr = (int*)w;   w += (size_t)(n + 1) * 4;
    unsigned* binned = (unsigned*)w; w += (size_t)E * 4;
    int* csr    = (int*)w;   w += (size_t)ne * 4;

    float* out   = (float*)d_out;
    float* ge    = out;
    float* hout  = out + (size_t)G * 128;
    float* eiout = out + (size_t)G * 128 + (size_t)n * 128;

    // ---- CSR build: binned counting sort ----
    fill_i_k<<<(NBMAX + 255) / 256, 256, 0, stream>>>(bcount, 0, NBMAX);
    bhist_k<<<256, 256, 0, stream>>>(ei, bcount, E);
    bscan_k<<<1, 256, 0, stream>>>(bcount, bbase, cursor, NB);
    bin_scatter_k<<<(E + TILE - 1) / TILE, 256, 0, stream>>>(ei, cursor, binned, E);
    bucket_csr_k<<<NB, 256, 0, stream>>>(binned, bbase, rowptr, csr, n, NB);

    // ---- 3 GAT layers ----
    const float* xin = x;
    for (int L = 0; L < 3; L++) {
        gemm_k<<<(n + 31) / 32, 256, 0, stream>>>(xin, Wm[L], asrc[L], adst[L], Hb, S, D, n);
        float* xnext = (L == 2) ? hout : Xact;
        attn_agg_k<<<(n + DPB - 1) / DPB, 256, 0, stream>>>(rowptr, csr, S, D, Hb, bias[L], xnext, n);
        xin = xnext;
    }

    // ---- readout ----
    fill_f_k<<<(G * 128 + 255) / 256, 256, 0, stream>>>(ge, -INFINITY, G * 128);
    ge_max_k<<<(n + 127) / 128, 256, 0, stream>>>(hout, batch, ge, n);
    ei_copy_k<<<(2 * E / 4 + 255) / 256, 256, 0, stream>>>(ei, eiout, 2 * E);
}

// Round 7
// 359.327 us; speedup vs baseline: 10.7781x; 1.0077x over previous
//
#include <hip/hip_runtime.h>
#include <math.h>
#include <limits.h>

#define LRELU_ATT 0.2f
#define LRELU_ACT 0.01f
#define CAP 64    // cached alphas per dst in LDS (deg > CAP falls back to recompute)
#define DPB 16    // dsts per block in attn_agg
#define NBMAX 512 // max buckets (n <= 65536, 128 dsts/bucket)
#define TILE 8192 // edges per bin_scatter block
#define BCAP 6528 // LDS capacity per bucket in bucket_csr (edges + selfs)

__device__ __forceinline__ float lrelu(float x, float s) { return x > 0.f ? x : x * s; }

__device__ __forceinline__ void atomicMaxF(float* addr, float val) {
    int* ai = (int*)addr;
    int old = *(volatile int*)ai;
    while (__int_as_float(old) < val) {
        int assumed = old;
        old = atomicCAS(ai, assumed, __float_as_int(val));
        if (old == assumed) break;
    }
}

__device__ __forceinline__ unsigned short f2bf(float f) {
    union { float f; unsigned u; } v; v.f = f;
    unsigned r = v.u + 0x7FFF + ((v.u >> 16) & 1);   // RNE
    return (unsigned short)(r >> 16);
}
__device__ __forceinline__ float bflo(unsigned u) {
    union { unsigned u; float f; } v; v.u = u << 16;
    return v.f;
}
__device__ __forceinline__ float bfhi(unsigned u) {
    union { unsigned u; float f; } v; v.u = u & 0xffff0000u;
    return v.f;
}

// inclusive scan of 512 ints in LDS with 256 threads; returns buffer holding result.
// caller must __syncthreads() after filling `a` and before calling.
__device__ __forceinline__ int* scan_incl_512(int* a, int* b, int tid) {
    int* in = a; int* out = b;
    for (int off = 1; off < 512; off <<= 1) {
        for (int i = tid; i < 512; i += 256)
            out[i] = in[i] + (i >= off ? in[i - off] : 0);
        __syncthreads();
        int* t = in; in = out; out = t;
    }
    return in;
}

// ---- GEMM + fused s/d epilogue: Hb[n,128](bf16) = X@W;  S,D[n,4] = head-dots ----
__global__ __launch_bounds__(256) void gemm_k(const float* __restrict__ X,
                                              const float* __restrict__ Wm,
                                              const float* __restrict__ a_src,
                                              const float* __restrict__ a_dst,
                                              unsigned short* __restrict__ Hb,
                                              float* __restrict__ S,
                                              float* __restrict__ D, int n) {
    __shared__ float sW[32 * 128];
    __shared__ float sX[32 * 32];
    __shared__ float sa[128], sb[128];
    if (threadIdx.x < 128) {
        sa[threadIdx.x] = a_src[threadIdx.x];
        sb[threadIdx.x] = a_dst[threadIdx.x];
    }
    int row0 = blockIdx.x * 32;
    int rt = threadIdx.x >> 5;   // 0..7 -> rows rt*4..rt*4+3
    int ct = threadIdx.x & 31;   // cols ct*4..ct*4+3
    int c0 = ct * 4;
    float4 acc[4];
#pragma unroll
    for (int i = 0; i < 4; i++) acc[i] = make_float4(0.f, 0.f, 0.f, 0.f);

    for (int k0 = 0; k0 < 128; k0 += 32) {
        __syncthreads();
        for (int i = threadIdx.x * 4; i < 32 * 128; i += 1024)
            *(float4*)&sW[i] = *(const float4*)&Wm[(k0 + (i >> 7)) * 128 + (i & 127)];
        {
            int i = threadIdx.x * 4;   // covers 32*32 exactly
            int r = i >> 5, kk = i & 31;
            int gr = row0 + r;
            float4 v = make_float4(0.f, 0.f, 0.f, 0.f);
            if (gr < n) v = *(const float4*)&X[gr * 128 + k0 + kk];
            *(float4*)&sX[i] = v;
        }
        __syncthreads();
#pragma unroll
        for (int kk = 0; kk < 32; kk += 4) {
            float4 w0 = *(const float4*)&sW[(kk + 0) * 128 + c0];
            float4 w1 = *(const float4*)&sW[(kk + 1) * 128 + c0];
            float4 w2 = *(const float4*)&sW[(kk + 2) * 128 + c0];
            float4 w3 = *(const float4*)&sW[(kk + 3) * 128 + c0];
#pragma unroll
            for (int i = 0; i < 4; i++) {
                float4 xv = *(const float4*)&sX[(rt * 4 + i) * 32 + kk];
                acc[i].x = fmaf(xv.x, w0.x, acc[i].x);
                acc[i].y = fmaf(xv.x, w0.y, acc[i].y);
                acc[i].z = fmaf(xv.x, w0.z, acc[i].z);
                acc[i].w = fmaf(xv.x, w0.w, acc[i].w);
                acc[i].x = fmaf(xv.y, w1.x, acc[i].x);
                acc[i].y = fmaf(xv.y, w1.y, acc[i].y);
                acc[i].z = fmaf(xv.y, w1.z, acc[i].z);
                acc[i].w = fmaf(xv.y, w1.w, acc[i].w);
                acc[i].x = fmaf(xv.z, w2.x, acc[i].x);
                acc[i].y = fmaf(xv.z, w2.y, acc[i].y);
                acc[i].z = fmaf(xv.z, w2.z, acc[i].z);
                acc[i].w = fmaf(xv.z, w2.w, acc[i].w);
                acc[i].x = fmaf(xv.w, w3.x, acc[i].x);
                acc[i].y = fmaf(xv.w, w3.y, acc[i].y);
                acc[i].z = fmaf(xv.w, w3.z, acc[i].z);
                acc[i].w = fmaf(xv.w, w3.w, acc[i].w);
            }
        }
    }
    // fused s/d epilogue: reduce over the 8 lanes sharing a head (ct bits 0..2)
    float sp[4], dp[4];
    const float* ap = &sa[c0];
    const float* bp = &sb[c0];
#pragma unroll
    for (int i = 0; i < 4; i++) {
        sp[i] = acc[i].x * ap[0] + acc[i].y * ap[1] + acc[i].z * ap[2] + acc[i].w * ap[3];
        dp[i] = acc[i].x * bp[0] + acc[i].y * bp[1] + acc[i].z * bp[2] + acc[i].w * bp[3];
    }
#pragma unroll
    for (int o = 1; o < 8; o <<= 1) {
#pragma unroll
        for (int i = 0; i < 4; i++) {
            sp[i] += __shfl_xor(sp[i], o, 64);
            dp[i] += __shfl_xor(dp[i], o, 64);
        }
    }
    int hd = ct >> 3;
#pragma unroll
    for (int i = 0; i < 4; i++) {
        int gr = row0 + rt * 4 + i;
        if (gr < n) {
            ushort4 hb;
            hb.x = f2bf(acc[i].x); hb.y = f2bf(acc[i].y);
            hb.z = f2bf(acc[i].z); hb.w = f2bf(acc[i].w);
            *(ushort4*)&Hb[gr * 128 + c0] = hb;
            if ((ct & 7) == 0) {
                S[gr * 4 + hd] = sp[i];
                D[gr * 4 + hd] = dp[i];
            }
        }
    }
}

__global__ void fill_f_k(float* __restrict__ p, float v, int cnt) {
    int i = blockIdx.x * blockDim.x + threadIdx.x;
    if (i < cnt) p[i] = v;
}
__global__ void fill_i_k(int* __restrict__ p, int v, int cnt) {
    int i = blockIdx.x * blockDim.x + threadIdx.x;
    if (i < cnt) p[i] = v;
}

// ---------------- CSR build: binned counting sort ----------------
// bucket = dst >> 7 (128 dsts per bucket)

__global__ void bhist_k(const int* __restrict__ ei, int* __restrict__ bcount, int E) {
    __shared__ int h[NBMAX];
    for (int i = threadIdx.x; i < NBMAX; i += 256) h[i] = 0;
    __syncthreads();
    for (int e = blockIdx.x * blockDim.x + threadIdx.x; e < E; e += gridDim.x * blockDim.x)
        atomicAdd(&h[ei[E + e] >> 7], 1);
    __syncthreads();
    for (int i = threadIdx.x; i < NBMAX; i += 256)
        if (h[i]) atomicAdd(&bcount[i], h[i]);
}

__global__ void bscan_k(const int* __restrict__ bcount, int* __restrict__ bbase,
                        int* __restrict__ cursor, int NB) {
    __shared__ int sa[512], sb[512];
    int tid = threadIdx.x;
    for (int i = tid; i < 512; i += 256) sa[i] = (i < NB) ? bcount[i] : 0;
    __syncthreads();
    int* inc = scan_incl_512(sa, sb, tid);
    for (int i = tid; i < NB; i += 256) {
        int ex = i ? inc[i - 1] : 0;
        bbase[i] = ex;
        cursor[i] = ex;
    }
    if (tid == 0) bbase[NB] = inc[NB - 1];
}

// tile -> LDS counting-sort by bucket -> bucket-grouped coalesced flush
__global__ __launch_bounds__(256) void bin_scatter_k(const int* __restrict__ ei,
                                                     int* __restrict__ cursor,
                                                     unsigned* __restrict__ binned, int E) {
    __shared__ int hist[NBMAX], excl[NBMAX], curl[NBMAX], gbase[NBMAX];
    __shared__ int sa[512], sb[512];
    __shared__ unsigned staged[TILE];
    int tid = threadIdx.x;
    int e0 = blockIdx.x * TILE;
    for (int i = tid; i < NBMAX; i += 256) hist[i] = 0;
    __syncthreads();
    unsigned keys[TILE / 256];
#pragma unroll
    for (int j = 0; j < TILE / 256; j++) {
        int e = e0 + j * 256 + tid;
        if (e < E) {
            unsigned dst = (unsigned)ei[E + e];
            unsigned src = (unsigned)ei[e];
            unsigned k = (dst << 16) | src;
            keys[j] = k;
            atomicAdd(&hist[k >> 23], 1);
        } else keys[j] = 0xFFFFFFFFu;
    }
    __syncthreads();
    for (int i = tid; i < 512; i += 256) sa[i] = hist[i];
    __syncthreads();
    int* inc = scan_incl_512(sa, sb, tid);
    for (int i = tid; i < NBMAX; i += 256) {
        int ex = i ? inc[i - 1] : 0;
        excl[i] = ex;
        curl[i] = ex;
    }
    __syncthreads();
#pragma unroll
    for (int j = 0; j < TILE / 256; j++) {
        unsigned k = keys[j];
        if (k != 0xFFFFFFFFu) {
            int b = k >> 23;
            int p = atomicAdd(&curl[b], 1);
            staged[p] = k;
        }
    }
    __syncthreads();
    for (int i = tid; i < NBMAX; i += 256) {
        int cnt = hist[i];
        if (cnt) gbase[i] = atomicAdd(&cursor[i], cnt);
    }
    __syncthreads();
    int total = inc[511];
    for (int p = tid; p < total; p += 256) {
        unsigned k = staged[p];
        int b = k >> 23;
        binned[gbase[b] + (p - excl[b])] = k;
    }
}

// one block per bucket: scatter into per-dst segments (arbitrary order), then
// canonicalize each segment with a wave-parallel rank sort (broadcast LDS reads).
__global__ __launch_bounds__(256) void bucket_csr_k(const unsigned* __restrict__ binned,
                                                    const int* __restrict__ bbase,
                                                    int* __restrict__ rowptr,
                                                    int* __restrict__ csr,
                                                    int n, int NB) {
    __shared__ int outL[BCAP];
    __shared__ int sa[512], sb[512];
    __shared__ int lbase[129], cur[128];
    int b = blockIdx.x;
    int tid = threadIdx.x;
    int dst0 = b << 7;
    int ndst = min(128, n - dst0);
    int ebase = bbase[b], ecnt = bbase[b + 1] - ebase;
    // hist (+1 for the self loop of each dst)
    for (int i = tid; i < 512; i += 256) sa[i] = (i < ndst) ? 1 : 0;
    __syncthreads();
    for (int p = tid; p < ecnt; p += 256) {
        int ld = (int)(binned[ebase + p] >> 16) - dst0;
        atomicAdd(&sa[ld], 1);
    }
    __syncthreads();
    int* inc = scan_incl_512(sa, sb, tid);
    for (int i = tid; i < ndst; i += 256) {
        int ex = i ? inc[i - 1] : 0;
        lbase[i] = ex;
        cur[i] = ex;
    }
    if (tid == 0) lbase[ndst] = inc[ndst - 1];
    __syncthreads();
    int total = lbase[ndst];
    // scatter self loops + edges (arrival order arbitrary; rank sort fixes it)
    for (int i = tid; i < ndst; i += 256) {
        int p = atomicAdd(&cur[i], 1);
        outL[p] = dst0 + i;
    }
    for (int p = tid; p < ecnt; p += 256) {
        unsigned k = binned[ebase + p];
        int ld = (int)(k >> 16) - dst0;
        int pos = atomicAdd(&cur[ld], 1);
        outL[pos] = (int)(k & 0xFFFFu);
    }
    __syncthreads();
    // canonical order: one wave per dst, rank sort (ascending src, pos tie-break)
    int w = tid >> 6, lane = tid & 63;
    for (int d = w; d < ndst; d += 4) {
        int st = lbase[d], en = lbase[d + 1];
        int deg = en - st;
        if (deg <= 1) continue;
        if (deg <= 128) {
            int v0 = (lane < deg) ? outL[st + lane] : 0;
            int v1 = (64 + lane < deg) ? outL[st + 64 + lane] : 0;
            int r0 = 0, r1 = 0;
            for (int j = 0; j < deg; j++) {
                int kj = outL[st + j];   // same-address broadcast, conflict-free
                r0 += (kj < v0) || (kj == v0 && j < lane);
                r1 += (kj < v1) || (kj == v1 && j < 64 + lane);
            }
            // wave lockstep: all loop reads retired before these writes
            if (lane < deg) outL[st + r0] = v0;
            if (64 + lane < deg) outL[st + r1] = v1;
        } else if (lane == 0) {
            for (int q = st + 1; q < en; q++) {
                int key = outL[q];
                int r = q - 1;
                while (r >= st && outL[r] > key) { outL[r + 1] = outL[r]; r--; }
                outL[r + 1] = key;
            }
        }
    }
    __syncthreads();
    int gb = ebase + dst0;   // self loops of earlier buckets = dst0
    for (int p = tid; p < total; p += 256) csr[gb + p] = outL[p];
    for (int i = tid; i < ndst; i += 256) rowptr[dst0 + i] = gb + lbase[i];
    if (b == NB - 1 && tid == 0) rowptr[n] = gb + total;
}

// ---- fused softmax + aggregate + bias + act ----
__global__ __launch_bounds__(256) void attn_agg_k(const int* __restrict__ rowptr,
                                                  const int* __restrict__ csr,
                                                  const float* __restrict__ S,
                                                  const float* __restrict__ Dv,
                                                  const unsigned short* __restrict__ Hb,
                                                  const float* __restrict__ bias,
                                                  float* __restrict__ Out, int n) {
    __shared__ float al[DPB][CAP * 4];
    __shared__ float sm[DPB][4], srd[DPB][4], sdv[DPB][4];
    __shared__ int srp[DPB + 1];
    int base = blockIdx.x * DPB;
    if (threadIdx.x <= DPB) {
        int idx = base + threadIdx.x;
        srp[threadIdx.x] = rowptr[idx > n ? n : idx];
    }
    __syncthreads();

    // ---- phase 1: stats (16-lane group per dst) ----
    {
        int g = threadIdx.x >> 4;     // 0..15
        int l = threadIdx.x & 15;
        int dst = base + g;
        if (dst < n) {
            int st = srp[g], en = srp[g + 1];
            int deg = en - st;
            float4 dv = *(const float4*)&Dv[dst * 4];
            float4 m = make_float4(-INFINITY, -INFINITY, -INFINITY, -INFINITY);
            for (int pos = l; pos < deg; pos += 16) {
                int src = csr[st + pos];
                float4 sv = *(const float4*)&S[src * 4];
                float4 e;
                e.x = lrelu(sv.x + dv.x, LRELU_ATT);
                e.y = lrelu(sv.y + dv.y, LRELU_ATT);
                e.z = lrelu(sv.z + dv.z, LRELU_ATT);
                e.w = lrelu(sv.w + dv.w, LRELU_ATT);
                if (pos < CAP) *(float4*)&al[g][pos * 4] = e;
                m.x = fmaxf(m.x, e.x); m.y = fmaxf(m.y, e.y);
                m.z = fmaxf(m.z, e.z); m.w = fmaxf(m.w, e.w);
            }
#pragma unroll
            for (int o = 1; o < 16; o <<= 1) {
                m.x = fmaxf(m.x, __shfl_xor(m.x, o, 64));
                m.y = fmaxf(m.y, __shfl_xor(m.y, o, 64));
                m.z = fmaxf(m.z, __shfl_xor(m.z, o, 64));
                m.w = fmaxf(m.w, __shfl_xor(m.w, o, 64));
            }
            float4 den = make_float4(0.f, 0.f, 0.f, 0.f);
            for (int pos = l; pos < deg; pos += 16) {
                float4 e;
                if (pos < CAP) e = *(const float4*)&al[g][pos * 4];
                else {
                    int src = csr[st + pos];
                    float4 sv = *(const float4*)&S[src * 4];
                    e.x = lrelu(sv.x + dv.x, LRELU_ATT);
                    e.y = lrelu(sv.y + dv.y, LRELU_ATT);
                    e.z = lrelu(sv.z + dv.z, LRELU_ATT);
                    e.w = lrelu(sv.w + dv.w, LRELU_ATT);
                }
                float4 ex;
                ex.x = __expf(e.x - m.x); ex.y = __expf(e.y - m.y);
                ex.z = __expf(e.z - m.z); ex.w = __expf(e.w - m.w);
                den.x += ex.x; den.y += ex.y; den.z += ex.z; den.w += ex.w;
                if (pos < CAP) *(float4*)&al[g][pos * 4] = ex;
            }
#pragma unroll
            for (int o = 1; o < 16; o <<= 1) {
                den.x += __shfl_xor(den.x, o, 64);
                den.y += __shfl_xor(den.y, o, 64);
                den.z += __shfl_xor(den.z, o, 64);
                den.w += __shfl_xor(den.w, o, 64);
            }
            float4 rd;
            rd.x = 1.f / den.x; rd.y = 1.f / den.y;
            rd.z = 1.f / den.z; rd.w = 1.f / den.w;
            int lim = deg < CAP ? deg : CAP;
            for (int pos = l; pos < lim; pos += 16) {
                float4 ex = *(const float4*)&al[g][pos * 4];
                ex.x *= rd.x; ex.y *= rd.y; ex.z *= rd.z; ex.w *= rd.w;
                *(float4*)&al[g][pos * 4] = ex;
            }
            if (l == 0) {
                *(float4*)&sm[g][0] = m;
                *(float4*)&srd[g][0] = rd;
                *(float4*)&sdv[g][0] = dv;
            }
        }
    }
    __syncthreads();

    // ---- phase 2: aggregation, 4 dsts per wave, 4 edges/iter ----
    int w = threadIdx.x >> 6;
    int lane = threadIdx.x & 63;
    int slot = lane >> 4;        // edge slot 0..3
    int l16 = lane & 15;
    int ch0 = l16 * 8;           // 8 channels per lane
    int hd = l16 >> 2;           // head of this lane's channels
#pragma unroll
    for (int j = 0; j < 4; j++) {
        int g2 = w * 4 + j;
        int dst = base + g2;
        if (dst >= n) break;
        int st = srp[g2], en = srp[g2 + 1];
        int deg = en - st;
        float4 a0 = make_float4(0.f, 0.f, 0.f, 0.f);
        float4 a1 = make_float4(0.f, 0.f, 0.f, 0.f);
        for (int pos = slot; pos < deg; pos += 4) {
            int src = csr[st + pos];
            float a;
            if (pos < CAP) a = al[g2][pos * 4 + hd];
            else a = __expf(lrelu(S[src * 4 + hd] + sdv[g2][hd], LRELU_ATT) - sm[g2][hd]) * srd[g2][hd];
            uint4 hv = *(const uint4*)&Hb[src * 128 + ch0];
            a0.x = fmaf(a, bflo(hv.x), a0.x);
            a0.y = fmaf(a, bfhi(hv.x), a0.y);
            a0.z = fmaf(a, bflo(hv.y), a0.z);
            a0.w = fmaf(a, bfhi(hv.y), a0.w);
            a1.x = fmaf(a, bflo(hv.z), a1.x);
            a1.y = fmaf(a, bfhi(hv.z), a1.y);
            a1.z = fmaf(a, bflo(hv.w), a1.z);
            a1.w = fmaf(a, bfhi(hv.w), a1.w);
        }
#pragma unroll
        for (int o = 16; o <= 32; o <<= 1) {
            a0.x += __shfl_xor(a0.x, o, 64);
            a0.y += __shfl_xor(a0.y, o, 64);
            a0.z += __shfl_xor(a0.z, o, 64);
            a0.w += __shfl_xor(a0.w, o, 64);
            a1.x += __shfl_xor(a1.x, o, 64);
            a1.y += __shfl_xor(a1.y, o, 64);
            a1.z += __shfl_xor(a1.z, o, 64);
            a1.w += __shfl_xor(a1.w, o, 64);
        }
        if (slot == 0) {
            float4 b0 = *(const float4*)&bias[ch0];
            float4 b1 = *(const float4*)&bias[ch0 + 4];
            float4 o0, o1;
            o0.x = lrelu(a0.x + b0.x, LRELU_ACT);
            o0.y = lrelu(a0.y + b0.y, LRELU_ACT);
            o0.z = lrelu(a0.z + b0.z, LRELU_ACT);
            o0.w = lrelu(a0.w + b0.w, LRELU_ACT);
            o1.x = lrelu(a1.x + b1.x, LRELU_ACT);
            o1.y = lrelu(a1.y + b1.y, LRELU_ACT);
            o1.z = lrelu(a1.z + b1.z, LRELU_ACT);
            o1.w = lrelu(a1.w + b1.w, LRELU_ACT);
            *(float4*)&Out[dst * 128 + ch0] = o0;
            *(float4*)&Out[dst * 128 + ch0 + 4] = o1;
        }
    }
}

// ---------------- graph embedding: segment max over sorted batch ----------------
__global__ void ge_max_k(const float* __restrict__ Hf, const int* __restrict__ batch,
                         float* __restrict__ ge, int n) {
    int c = threadIdx.x & 127;
    int rh = threadIdx.x >> 7;  // 0..1
    int node0 = blockIdx.x * 128;
    int hi = min(node0 + 128, n);
    int gid = -1;
    float mv = -INFINITY;
    for (int r = node0 + rh; r < hi; r += 2) {
        int g = batch[r];
        if (g != gid) {
            if (gid >= 0) atomicMaxF(&ge[gid * 128 + c], mv);
            gid = g;
            mv = -INFINITY;
        }
        mv = fmaxf(mv, Hf[r * 128 + c]);
    }
    if (gid >= 0) atomicMaxF(&ge[gid * 128 + c], mv);
}

__global__ void ei_copy_k(const int* __restrict__ ei, float* __restrict__ out, int m) {
    int i = (blockIdx.x * blockDim.x + threadIdx.x) * 4;
    if (i + 3 < m) {
        int4 v = *(const int4*)&ei[i];
        float4 o = make_float4((float)v.x, (float)v.y, (float)v.z, (float)v.w);
        *(float4*)&out[i] = o;
    } else {
        for (; i < m; i++) out[i] = (float)ei[i];
    }
}

extern "C" void kernel_launch(void* const* d_in, const int* in_sizes, int n_in,
                              void* d_out, int out_size, void* d_ws, size_t ws_size,
                              hipStream_t stream) {
    const float* x = (const float*)d_in[0];
    const int* ei = (const int*)d_in[1];
    const int* batch = (const int*)d_in[2];
    const float* Wm[3]   = {(const float*)d_in[3], (const float*)d_in[7],  (const float*)d_in[11]};
    const float* asrc[3] = {(const float*)d_in[4], (const float*)d_in[8],  (const float*)d_in[12]};
    const float* adst[3] = {(const float*)d_in[5], (const float*)d_in[9],  (const float*)d_in[13]};
    const float* bias[3] = {(const float*)d_in[6], (const float*)d_in[10], (const float*)d_in[14]};

    const int n = in_sizes[2];          // 50000 nodes
    const int E = in_sizes[1] / 2;      // 800000 edges
    const int ne = E + n;               // + self loops
    const int G = (out_size - n * 128 - 2 * E) / 128;  // 64 graphs
    const int NB = (n + 127) >> 7;      // 391 buckets

    // workspace layout
    char* w = (char*)d_ws;
    float* Xact = (float*)w;          w += (size_t)n * 128 * 4;
    unsigned short* Hb = (unsigned short*)w; w += (size_t)n * 128 * 2;
    float* S    = (float*)w; w += (size_t)n * 4 * 4;
    float* D    = (float*)w; w += (size_t)n * 4 * 4;
    int* bcount = (int*)w;   w += NBMAX * 4;
    int* bbase  = (int*)w;   w += (NBMAX + 1) * 4;
    int* cursor = (int*)w;   w += NBMAX * 4;
    int* rowptr = (int*)w;   w += (size_t)(n + 1) * 4;
    unsigned* binned = (unsigned*)w; w += (size_t)E * 4;
    int* csr    = (int*)w;   w += (size_t)ne * 4;

    float* out   = (float*)d_out;
    float* ge    = out;
    float* hout  = out + (size_t)G * 128;
    float* eiout = out + (size_t)G * 128 + (size_t)n * 128;

    // ---- CSR build: binned counting sort ----
    fill_i_k<<<(NBMAX + 255) / 256, 256, 0, stream>>>(bcount, 0, NBMAX);
    bhist_k<<<256, 256, 0, stream>>>(ei, bcount, E);
    bscan_k<<<1, 256, 0, stream>>>(bcount, bbase, cursor, NB);
    bin_scatter_k<<<(E + TILE - 1) / TILE, 256, 0, stream>>>(ei, cursor, binned, E);
    bucket_csr_k<<<NB, 256, 0, stream>>>(binned, bbase, rowptr, csr, n, NB);

    // ---- 3 GAT layers ----
    const float* xin = x;
    for (int L = 0; L < 3; L++) {
        gemm_k<<<(n + 31) / 32, 256, 0, stream>>>(xin, Wm[L], asrc[L], adst[L], Hb, S, D, n);
        float* xnext = (L == 2) ? hout : Xact;
        attn_agg_k<<<(n + DPB - 1) / DPB, 256, 0, stream>>>(rowptr, csr, S, D, Hb, bias[L], xnext, n);
        xin = xnext;
    }

    // ---- readout ----
    fill_f_k<<<(G * 128 + 255) / 256, 256, 0, stream>>>(ge, -INFINITY, G * 128);
    ge_max_k<<<(n + 127) / 128, 256, 0, stream>>>(hout, batch, ge, n);
    ei_copy_k<<<(2 * E / 4 + 255) / 256, 256, 0, stream>>>(ei, eiout, 2 * E);
}

// Round 8
// 342.738 us; speedup vs baseline: 11.2997x; 1.0484x over previous
//
#include <hip/hip_runtime.h>
#include <math.h>
#include <limits.h>

#define LRELU_ATT 0.2f
#define LRELU_ACT 0.01f
#define CAP 64    // cached alphas per dst in LDS (deg > CAP falls back to recompute)
#define DPB 16    // dsts per block in attn_agg
#define NBMAX 512 // max buckets (n <= 65536, 128 dsts/bucket)
#define TILE 8192 // edges per bin_scatter block
#define BCAP 6528 // LDS capacity per bucket in bucket_csr (edges + selfs)

__device__ __forceinline__ float lrelu(float x, float s) { return x > 0.f ? x : x * s; }

__device__ __forceinline__ void atomicMaxF(float* addr, float val) {
    int* ai = (int*)addr;
    int old = *(volatile int*)ai;
    while (__int_as_float(old) < val) {
        int assumed = old;
        old = atomicCAS(ai, assumed, __float_as_int(val));
        if (old == assumed) break;
    }
}

__device__ __forceinline__ unsigned short f2bf(float f) {
    union { float f; unsigned u; } v; v.f = f;
    unsigned r = v.u + 0x7FFF + ((v.u >> 16) & 1);   // RNE
    return (unsigned short)(r >> 16);
}
__device__ __forceinline__ float bflo(unsigned u) {
    union { unsigned u; float f; } v; v.u = u << 16;
    return v.f;
}
__device__ __forceinline__ float bfhi(unsigned u) {
    union { unsigned u; float f; } v; v.u = u & 0xffff0000u;
    return v.f;
}

// inclusive scan of 512 ints in LDS; works for any blockDim >= 512... uses strided loops.
// caller must __syncthreads() after filling `a` and before calling.
__device__ __forceinline__ int* scan_incl_512(int* a, int* b, int tid, int nthr) {
    int* in = a; int* out = b;
    for (int off = 1; off < 512; off <<= 1) {
        for (int i = tid; i < 512; i += nthr)
            out[i] = in[i] + (i >= off ? in[i - off] : 0);
        __syncthreads();
        int* t = in; in = out; out = t;
    }
    return in;
}

// ---- GEMM + fused s/d epilogue: Hb[n,128](bf16) = X@W;  S,D[n,4] = head-dots ----
__global__ __launch_bounds__(256) void gemm_k(const float* __restrict__ X,
                                              const float* __restrict__ Wm,
                                              const float* __restrict__ a_src,
                                              const float* __restrict__ a_dst,
                                              unsigned short* __restrict__ Hb,
                                              float* __restrict__ S,
                                              float* __restrict__ D, int n) {
    __shared__ float sW[32 * 128];
    __shared__ float sX[32 * 32];
    __shared__ float sa[128], sb[128];
    if (threadIdx.x < 128) {
        sa[threadIdx.x] = a_src[threadIdx.x];
        sb[threadIdx.x] = a_dst[threadIdx.x];
    }
    int row0 = blockIdx.x * 32;
    int rt = threadIdx.x >> 5;   // 0..7 -> rows rt*4..rt*4+3
    int ct = threadIdx.x & 31;   // cols ct*4..ct*4+3
    int c0 = ct * 4;
    float4 acc[4];
#pragma unroll
    for (int i = 0; i < 4; i++) acc[i] = make_float4(0.f, 0.f, 0.f, 0.f);

    for (int k0 = 0; k0 < 128; k0 += 32) {
        __syncthreads();
        for (int i = threadIdx.x * 4; i < 32 * 128; i += 1024)
            *(float4*)&sW[i] = *(const float4*)&Wm[(k0 + (i >> 7)) * 128 + (i & 127)];
        {
            int i = threadIdx.x * 4;   // covers 32*32 exactly
            int r = i >> 5, kk = i & 31;
            int gr = row0 + r;
            float4 v = make_float4(0.f, 0.f, 0.f, 0.f);
            if (gr < n) v = *(const float4*)&X[gr * 128 + k0 + kk];
            *(float4*)&sX[i] = v;
        }
        __syncthreads();
#pragma unroll
        for (int kk = 0; kk < 32; kk += 4) {
            float4 w0 = *(const float4*)&sW[(kk + 0) * 128 + c0];
            float4 w1 = *(const float4*)&sW[(kk + 1) * 128 + c0];
            float4 w2 = *(const float4*)&sW[(kk + 2) * 128 + c0];
            float4 w3 = *(const float4*)&sW[(kk + 3) * 128 + c0];
#pragma unroll
            for (int i = 0; i < 4; i++) {
                float4 xv = *(const float4*)&sX[(rt * 4 + i) * 32 + kk];
                acc[i].x = fmaf(xv.x, w0.x, acc[i].x);
                acc[i].y = fmaf(xv.x, w0.y, acc[i].y);
                acc[i].z = fmaf(xv.x, w0.z, acc[i].z);
                acc[i].w = fmaf(xv.x, w0.w, acc[i].w);
                acc[i].x = fmaf(xv.y, w1.x, acc[i].x);
                acc[i].y = fmaf(xv.y, w1.y, acc[i].y);
                acc[i].z = fmaf(xv.y, w1.z, acc[i].z);
                acc[i].w = fmaf(xv.y, w1.w, acc[i].w);
                acc[i].x = fmaf(xv.z, w2.x, acc[i].x);
                acc[i].y = fmaf(xv.z, w2.y, acc[i].y);
                acc[i].z = fmaf(xv.z, w2.z, acc[i].z);
                acc[i].w = fmaf(xv.z, w2.w, acc[i].w);
                acc[i].x = fmaf(xv.w, w3.x, acc[i].x);
                acc[i].y = fmaf(xv.w, w3.y, acc[i].y);
                acc[i].z = fmaf(xv.w, w3.z, acc[i].z);
                acc[i].w = fmaf(xv.w, w3.w, acc[i].w);
            }
        }
    }
    // fused s/d epilogue: reduce over the 8 lanes sharing a head (ct bits 0..2)
    float sp[4], dp[4];
    const float* ap = &sa[c0];
    const float* bp = &sb[c0];
#pragma unroll
    for (int i = 0; i < 4; i++) {
        sp[i] = acc[i].x * ap[0] + acc[i].y * ap[1] + acc[i].z * ap[2] + acc[i].w * ap[3];
        dp[i] = acc[i].x * bp[0] + acc[i].y * bp[1] + acc[i].z * bp[2] + acc[i].w * bp[3];
    }
#pragma unroll
    for (int o = 1; o < 8; o <<= 1) {
#pragma unroll
        for (int i = 0; i < 4; i++) {
            sp[i] += __shfl_xor(sp[i], o, 64);
            dp[i] += __shfl_xor(dp[i], o, 64);
        }
    }
    int hd = ct >> 3;
#pragma unroll
    for (int i = 0; i < 4; i++) {
        int gr = row0 + rt * 4 + i;
        if (gr < n) {
            ushort4 hb;
            hb.x = f2bf(acc[i].x); hb.y = f2bf(acc[i].y);
            hb.z = f2bf(acc[i].z); hb.w = f2bf(acc[i].w);
            *(ushort4*)&Hb[gr * 128 + c0] = hb;
            if ((ct & 7) == 0) {
                S[gr * 4 + hd] = sp[i];
                D[gr * 4 + hd] = dp[i];
            }
        }
    }
}

__global__ void fill_f_k(float* __restrict__ p, float v, int cnt) {
    int i = blockIdx.x * blockDim.x + threadIdx.x;
    if (i < cnt) p[i] = v;
}
__global__ void fill_i_k(int* __restrict__ p, int v, int cnt) {
    int i = blockIdx.x * blockDim.x + threadIdx.x;
    if (i < cnt) p[i] = v;
}

// ---------------- CSR build: binned counting sort ----------------
// bucket = dst >> 7 (128 dsts per bucket)

__global__ void bhist_k(const int* __restrict__ ei, int* __restrict__ bcount, int E) {
    __shared__ int h[NBMAX];
    for (int i = threadIdx.x; i < NBMAX; i += 256) h[i] = 0;
    __syncthreads();
    for (int e = blockIdx.x * blockDim.x + threadIdx.x; e < E; e += gridDim.x * blockDim.x)
        atomicAdd(&h[ei[E + e] >> 7], 1);
    __syncthreads();
    for (int i = threadIdx.x; i < NBMAX; i += 256)
        if (h[i]) atomicAdd(&bcount[i], h[i]);
}

__global__ void bscan_k(const int* __restrict__ bcount, int* __restrict__ bbase,
                        int* __restrict__ cursor, int NB) {
    __shared__ int sa[512], sb[512];
    int tid = threadIdx.x;
    for (int i = tid; i < 512; i += 256) sa[i] = (i < NB) ? bcount[i] : 0;
    __syncthreads();
    int* inc = scan_incl_512(sa, sb, tid, 256);
    for (int i = tid; i < NB; i += 256) {
        int ex = i ? inc[i - 1] : 0;
        bbase[i] = ex;
        cursor[i] = ex;
    }
    if (tid == 0) bbase[NB] = inc[NB - 1];
}

// tile -> LDS counting-sort by bucket -> bucket-grouped coalesced flush
__global__ __launch_bounds__(256) void bin_scatter_k(const int* __restrict__ ei,
                                                     int* __restrict__ cursor,
                                                     unsigned* __restrict__ binned, int E) {
    __shared__ int hist[NBMAX], excl[NBMAX], curl[NBMAX], gbase[NBMAX];
    __shared__ int sa[512], sb[512];
    __shared__ unsigned staged[TILE];
    int tid = threadIdx.x;
    int e0 = blockIdx.x * TILE;
    for (int i = tid; i < NBMAX; i += 256) hist[i] = 0;
    __syncthreads();
    unsigned keys[TILE / 256];
#pragma unroll
    for (int j = 0; j < TILE / 256; j++) {
        int e = e0 + j * 256 + tid;
        if (e < E) {
            unsigned dst = (unsigned)ei[E + e];
            unsigned src = (unsigned)ei[e];
            unsigned k = (dst << 16) | src;
            keys[j] = k;
            atomicAdd(&hist[k >> 23], 1);
        } else keys[j] = 0xFFFFFFFFu;
    }
    __syncthreads();
    for (int i = tid; i < 512; i += 256) sa[i] = hist[i];
    __syncthreads();
    int* inc = scan_incl_512(sa, sb, tid, 256);
    for (int i = tid; i < NBMAX; i += 256) {
        int ex = i ? inc[i - 1] : 0;
        excl[i] = ex;
        curl[i] = ex;
    }
    __syncthreads();
#pragma unroll
    for (int j = 0; j < TILE / 256; j++) {
        unsigned k = keys[j];
        if (k != 0xFFFFFFFFu) {
            int b = k >> 23;
            int p = atomicAdd(&curl[b], 1);
            staged[p] = k;
        }
    }
    __syncthreads();
    for (int i = tid; i < NBMAX; i += 256) {
        int cnt = hist[i];
        if (cnt) gbase[i] = atomicAdd(&cursor[i], cnt);
    }
    __syncthreads();
    int total = inc[511];
    for (int p = tid; p < total; p += 256) {
        unsigned k = staged[p];
        int b = k >> 23;
        binned[gbase[b] + (p - excl[b])] = k;
    }
}

// one block (1024 thr) per bucket: scatter into per-dst segments (arbitrary order),
// then canonicalize each segment with a register shuffle rank sort (no LDS in loop).
__global__ __launch_bounds__(1024) void bucket_csr_k(const unsigned* __restrict__ binned,
                                                     const int* __restrict__ bbase,
                                                     int* __restrict__ rowptr,
                                                     int* __restrict__ csr,
                                                     int n, int NB) {
    __shared__ int outL[BCAP];
    __shared__ int sa[512], sb[512];
    __shared__ int lbase[129], cur[128];
    int b = blockIdx.x;
    int tid = threadIdx.x;
    int dst0 = b << 7;
    int ndst = min(128, n - dst0);
    int ebase = bbase[b], ecnt = bbase[b + 1] - ebase;
    // hist (+1 for the self loop of each dst)
    for (int i = tid; i < 512; i += 1024) sa[i] = (i < ndst) ? 1 : 0;
    __syncthreads();
    for (int p = tid; p < ecnt; p += 1024) {
        int ld = (int)(binned[ebase + p] >> 16) - dst0;
        atomicAdd(&sa[ld], 1);
    }
    __syncthreads();
    int* inc = scan_incl_512(sa, sb, tid, 1024);
    for (int i = tid; i < ndst; i += 1024) {
        int ex = i ? inc[i - 1] : 0;
        lbase[i] = ex;
        cur[i] = ex;
    }
    if (tid == 0) lbase[ndst] = inc[ndst - 1];
    __syncthreads();
    int total = lbase[ndst];
    // scatter self loops + edges (arrival order arbitrary; rank sort fixes it)
    for (int i = tid; i < ndst; i += 1024) {
        int p = atomicAdd(&cur[i], 1);
        outL[p] = dst0 + i;
    }
    for (int p = tid; p < ecnt; p += 1024) {
        unsigned k = binned[ebase + p];
        int ld = (int)(k >> 16) - dst0;
        int pos = atomicAdd(&cur[ld], 1);
        outL[pos] = (int)(k & 0xFFFFu);
    }
    __syncthreads();
    // canonical order: one wave per dst, register shuffle rank sort
    // (ties = equal src contribute identically, so tie order is fp-irrelevant;
    //  pos tie-break still gives distinct ranks)
    int w = tid >> 6, lane = tid & 63;
    for (int d = w; d < ndst; d += 16) {
        int st = lbase[d], en = lbase[d + 1];
        int deg = en - st;
        if (deg <= 1) continue;
        if (deg <= 64) {
            int v = (lane < deg) ? outL[st + lane] : INT_MAX;
            int r = 0;
            for (int j = 0; j < deg; j++) {
                int kj = __shfl(v, j, 64);
                r += (kj < v) || (kj == v && j < lane);
            }
            if (lane < deg) outL[st + r] = v;
        } else if (deg <= 128) {
            int v0 = (lane < deg) ? outL[st + lane] : 0;
            int v1 = (64 + lane < deg) ? outL[st + 64 + lane] : 0;
            int r0 = 0, r1 = 0;
            for (int j = 0; j < deg; j++) {
                int kj = outL[st + j];
                r0 += (kj < v0) || (kj == v0 && j < lane);
                r1 += (kj < v1) || (kj == v1 && j < 64 + lane);
            }
            if (lane < deg) outL[st + r0] = v0;
            if (64 + lane < deg) outL[st + r1] = v1;
        } else if (lane == 0) {
            for (int q = st + 1; q < en; q++) {
                int key = outL[q];
                int r = q - 1;
                while (r >= st && outL[r] > key) { outL[r + 1] = outL[r]; r--; }
                outL[r + 1] = key;
            }
        }
    }
    __syncthreads();
    int gb = ebase + dst0;   // self loops of earlier buckets = dst0
    for (int p = tid; p < total; p += 1024) csr[gb + p] = outL[p];
    for (int i = tid; i < ndst; i += 1024) rowptr[dst0 + i] = gb + lbase[i];
    if (b == NB - 1 && tid == 0) rowptr[n] = gb + total;
}

// ---- fused softmax + aggregate + bias + act ----
__global__ __launch_bounds__(256) void attn_agg_k(const int* __restrict__ rowptr,
                                                  const int* __restrict__ csr,
                                                  const float* __restrict__ S,
                                                  const float* __restrict__ Dv,
                                                  const unsigned short* __restrict__ Hb,
                                                  const float* __restrict__ bias,
                                                  float* __restrict__ Out, int n) {
    __shared__ float al[DPB][CAP * 4];
    __shared__ float sm[DPB][4], srd[DPB][4], sdv[DPB][4];
    __shared__ int srp[DPB + 1];
    int base = blockIdx.x * DPB;
    if (threadIdx.x <= DPB) {
        int idx = base + threadIdx.x;
        srp[threadIdx.x] = rowptr[idx > n ? n : idx];
    }
    __syncthreads();

    // ---- phase 1: stats (16-lane group per dst) ----
    {
        int g = threadIdx.x >> 4;     // 0..15
        int l = threadIdx.x & 15;
        int dst = base + g;
        if (dst < n) {
            int st = srp[g], en = srp[g + 1];
            int deg = en - st;
            float4 dv = *(const float4*)&Dv[dst * 4];
            float4 m = make_float4(-INFINITY, -INFINITY, -INFINITY, -INFINITY);
            for (int pos = l; pos < deg; pos += 16) {
                int src = csr[st + pos];
                float4 sv = *(const float4*)&S[src * 4];
                float4 e;
                e.x = lrelu(sv.x + dv.x, LRELU_ATT);
                e.y = lrelu(sv.y + dv.y, LRELU_ATT);
                e.z = lrelu(sv.z + dv.z, LRELU_ATT);
                e.w = lrelu(sv.w + dv.w, LRELU_ATT);
                if (pos < CAP) *(float4*)&al[g][pos * 4] = e;
                m.x = fmaxf(m.x, e.x); m.y = fmaxf(m.y, e.y);
                m.z = fmaxf(m.z, e.z); m.w = fmaxf(m.w, e.w);
            }
#pragma unroll
            for (int o = 1; o < 16; o <<= 1) {
                m.x = fmaxf(m.x, __shfl_xor(m.x, o, 64));
                m.y = fmaxf(m.y, __shfl_xor(m.y, o, 64));
                m.z = fmaxf(m.z, __shfl_xor(m.z, o, 64));
                m.w = fmaxf(m.w, __shfl_xor(m.w, o, 64));
            }
            float4 den = make_float4(0.f, 0.f, 0.f, 0.f);
            for (int pos = l; pos < deg; pos += 16) {
                float4 e;
                if (pos < CAP) e = *(const float4*)&al[g][pos * 4];
                else {
                    int src = csr[st + pos];
                    float4 sv = *(const float4*)&S[src * 4];
                    e.x = lrelu(sv.x + dv.x, LRELU_ATT);
                    e.y = lrelu(sv.y + dv.y, LRELU_ATT);
                    e.z = lrelu(sv.z + dv.z, LRELU_ATT);
                    e.w = lrelu(sv.w + dv.w, LRELU_ATT);
                }
                float4 ex;
                ex.x = __expf(e.x - m.x); ex.y = __expf(e.y - m.y);
                ex.z = __expf(e.z - m.z); ex.w = __expf(e.w - m.w);
                den.x += ex.x; den.y += ex.y; den.z += ex.z; den.w += ex.w;
                if (pos < CAP) *(float4*)&al[g][pos * 4] = ex;
            }
#pragma unroll
            for (int o = 1; o < 16; o <<= 1) {
                den.x += __shfl_xor(den.x, o, 64);
                den.y += __shfl_xor(den.y, o, 64);
                den.z += __shfl_xor(den.z, o, 64);
                den.w += __shfl_xor(den.w, o, 64);
            }
            float4 rd;
            rd.x = 1.f / den.x; rd.y = 1.f / den.y;
            rd.z = 1.f / den.z; rd.w = 1.f / den.w;
            int lim = deg < CAP ? deg : CAP;
            for (int pos = l; pos < lim; pos += 16) {
                float4 ex = *(const float4*)&al[g][pos * 4];
                ex.x *= rd.x; ex.y *= rd.y; ex.z *= rd.z; ex.w *= rd.w;
                *(float4*)&al[g][pos * 4] = ex;
            }
            if (l == 0) {
                *(float4*)&sm[g][0] = m;
                *(float4*)&srd[g][0] = rd;
                *(float4*)&sdv[g][0] = dv;
            }
        }
    }
    __syncthreads();

    // ---- phase 2: aggregation, 4 dsts per wave, 4 edges/iter ----
    int w = threadIdx.x >> 6;
    int lane = threadIdx.x & 63;
    int slot = lane >> 4;        // edge slot 0..3
    int l16 = lane & 15;
    int ch0 = l16 * 8;           // 8 channels per lane
    int hd = l16 >> 2;           // head of this lane's channels
#pragma unroll
    for (int j = 0; j < 4; j++) {
        int g2 = w * 4 + j;
        int dst = base + g2;
        if (dst >= n) break;
        int st = srp[g2], en = srp[g2 + 1];
        int deg = en - st;
        float4 a0 = make_float4(0.f, 0.f, 0.f, 0.f);
        float4 a1 = make_float4(0.f, 0.f, 0.f, 0.f);
        for (int pos = slot; pos < deg; pos += 4) {
            int src = csr[st + pos];
            float a;
            if (pos < CAP) a = al[g2][pos * 4 + hd];
            else a = __expf(lrelu(S[src * 4 + hd] + sdv[g2][hd], LRELU_ATT) - sm[g2][hd]) * srd[g2][hd];
            uint4 hv = *(const uint4*)&Hb[src * 128 + ch0];
            a0.x = fmaf(a, bflo(hv.x), a0.x);
            a0.y = fmaf(a, bfhi(hv.x), a0.y);
            a0.z = fmaf(a, bflo(hv.y), a0.z);
            a0.w = fmaf(a, bfhi(hv.y), a0.w);
            a1.x = fmaf(a, bflo(hv.z), a1.x);
            a1.y = fmaf(a, bfhi(hv.z), a1.y);
            a1.z = fmaf(a, bflo(hv.w), a1.z);
            a1.w = fmaf(a, bfhi(hv.w), a1.w);
        }
#pragma unroll
        for (int o = 16; o <= 32; o <<= 1) {
            a0.x += __shfl_xor(a0.x, o, 64);
            a0.y += __shfl_xor(a0.y, o, 64);
            a0.z += __shfl_xor(a0.z, o, 64);
            a0.w += __shfl_xor(a0.w, o, 64);
            a1.x += __shfl_xor(a1.x, o, 64);
            a1.y += __shfl_xor(a1.y, o, 64);
            a1.z += __shfl_xor(a1.z, o, 64);
            a1.w += __shfl_xor(a1.w, o, 64);
        }
        if (slot == 0) {
            float4 b0 = *(const float4*)&bias[ch0];
            float4 b1 = *(const float4*)&bias[ch0 + 4];
            float4 o0, o1;
            o0.x = lrelu(a0.x + b0.x, LRELU_ACT);
            o0.y = lrelu(a0.y + b0.y, LRELU_ACT);
            o0.z = lrelu(a0.z + b0.z, LRELU_ACT);
            o0.w = lrelu(a0.w + b0.w, LRELU_ACT);
            o1.x = lrelu(a1.x + b1.x, LRELU_ACT);
            o1.y = lrelu(a1.y + b1.y, LRELU_ACT);
            o1.z = lrelu(a1.z + b1.z, LRELU_ACT);
            o1.w = lrelu(a1.w + b1.w, LRELU_ACT);
            *(float4*)&Out[dst * 128 + ch0] = o0;
            *(float4*)&Out[dst * 128 + ch0 + 4] = o1;
        }
    }
}

// ---------------- graph embedding: segment max over sorted batch ----------------
__global__ void ge_max_k(const float* __restrict__ Hf, const int* __restrict__ batch,
                         float* __restrict__ ge, int n) {
    int c = threadIdx.x & 127;
    int rh = threadIdx.x >> 7;  // 0..1
    int node0 = blockIdx.x * 128;
    int hi = min(node0 + 128, n);
    int gid = -1;
    float mv = -INFINITY;
    for (int r = node0 + rh; r < hi; r += 2) {
        int g = batch[r];
        if (g != gid) {
            if (gid >= 0) atomicMaxF(&ge[gid * 128 + c], mv);
            gid = g;
            mv = -INFINITY;
        }
        mv = fmaxf(mv, Hf[r * 128 + c]);
    }
    if (gid >= 0) atomicMaxF(&ge[gid * 128 + c], mv);
}

__global__ void ei_copy_k(const int* __restrict__ ei, float* __restrict__ out, int m) {
    int i = (blockIdx.x * blockDim.x + threadIdx.x) * 4;
    if (i + 3 < m) {
        int4 v = *(const int4*)&ei[i];
        float4 o = make_float4((float)v.x, (float)v.y, (float)v.z, (float)v.w);
        *(float4*)&out[i] = o;
    } else {
        for (; i < m; i++) out[i] = (float)ei[i];
    }
}

extern "C" void kernel_launch(void* const* d_in, const int* in_sizes, int n_in,
                              void* d_out, int out_size, void* d_ws, size_t ws_size,
                              hipStream_t stream) {
    const float* x = (const float*)d_in[0];
    const int* ei = (const int*)d_in[1];
    const int* batch = (const int*)d_in[2];
    const float* Wm[3]   = {(const float*)d_in[3], (const float*)d_in[7],  (const float*)d_in[11]};
    const float* asrc[3] = {(const float*)d_in[4], (const float*)d_in[8],  (const float*)d_in[12]};
    const float* adst[3] = {(const float*)d_in[5], (const float*)d_in[9],  (const float*)d_in[13]};
    const float* bias[3] = {(const float*)d_in[6], (const float*)d_in[10], (const float*)d_in[14]};

    const int n = in_sizes[2];          // 50000 nodes
    const int E = in_sizes[1] / 2;      // 800000 edges
    const int ne = E + n;               // + self loops
    const int G = (out_size - n * 128 - 2 * E) / 128;  // 64 graphs
    const int NB = (n + 127) >> 7;      // 391 buckets

    // workspace layout
    char* w = (char*)d_ws;
    float* Xact = (float*)w;          w += (size_t)n * 128 * 4;
    unsigned short* Hb = (unsigned short*)w; w += (size_t)n * 128 * 2;
    float* S    = (float*)w; w += (size_t)n * 4 * 4;
    float* D    = (float*)w; w += (size_t)n * 4 * 4;
    int* bcount = (int*)w;   w += NBMAX * 4;
    int* bbase  = (int*)w;   w += (NBMAX + 1) * 4;
    int* cursor = (int*)w;   w += NBMAX * 4;
    int* rowptr = (int*)w;   w += (size_t)(n + 1) * 4;
    unsigned* binned = (unsigned*)w; w += (size_t)E * 4;
    int* csr    = (int*)w;   w += (size_t)ne * 4;

    float* out   = (float*)d_out;
    float* ge    = out;
    float* hout  = out + (size_t)G * 128;
    float* eiout = out + (size_t)G * 128 + (size_t)n * 128;

    // ---- CSR build: binned counting sort ----
    fill_i_k<<<(NBMAX + 255) / 256, 256, 0, stream>>>(bcount, 0, NBMAX);
    bhist_k<<<256, 256, 0, stream>>>(ei, bcount, E);
    bscan_k<<<1, 256, 0, stream>>>(bcount, bbase, cursor, NB);
    bin_scatter_k<<<(E + TILE - 1) / TILE, 256, 0, stream>>>(ei, cursor, binned, E);
    bucket_csr_k<<<NB, 1024, 0, stream>>>(binned, bbase, rowptr, csr, n, NB);

    // ---- 3 GAT layers ----
    const float* xin = x;
    for (int L = 0; L < 3; L++) {
        gemm_k<<<(n + 31) / 32, 256, 0, stream>>>(xin, Wm[L], asrc[L], adst[L], Hb, S, D, n);
        float* xnext = (L == 2) ? hout : Xact;
        attn_agg_k<<<(n + DPB - 1) / DPB, 256, 0, stream>>>(rowptr, csr, S, D, Hb, bias[L], xnext, n);
        xin = xnext;
    }

    // ---- readout ----
    fill_f_k<<<(G * 128 + 255) / 256, 256, 0, stream>>>(ge, -INFINITY, G * 128);
    ge_max_k<<<(n + 127) / 128, 256, 0, stream>>>(hout, batch, ge, n);
    ei_copy_k<<<(2 * E / 4 + 255) / 256, 256, 0, stream>>>(ei, eiout, 2 * E);
}

// Round 9
// 321.150 us; speedup vs baseline: 12.0594x; 1.0672x over previous
//
#include <hip/hip_runtime.h>
#include <math.h>
#include <limits.h>

#define LRELU_ATT 0.2f
#define LRELU_ACT 0.01f
#define CAP 64    // cached alphas per dst in LDS (deg > CAP falls back to recompute)
#define DPB 16    // dsts per block in attn_agg
#define LCAP (DPB * CAP)  // flat per-block src cache entries
#define NBMAX 512 // max buckets (n <= 65536, 128 dsts/bucket)
#define TILE 8192 // edges per bin_scatter block
#define BCAP 6528 // LDS capacity per bucket in bucket_csr (edges + selfs)

__device__ __forceinline__ float lrelu(float x, float s) { return x > 0.f ? x : x * s; }

__device__ __forceinline__ void atomicMaxF(float* addr, float val) {
    int* ai = (int*)addr;
    int old = *(volatile int*)ai;
    while (__int_as_float(old) < val) {
        int assumed = old;
        old = atomicCAS(ai, assumed, __float_as_int(val));
        if (old == assumed) break;
    }
}

__device__ __forceinline__ unsigned short f2bf(float f) {
    union { float f; unsigned u; } v; v.f = f;
    unsigned r = v.u + 0x7FFF + ((v.u >> 16) & 1);   // RNE
    return (unsigned short)(r >> 16);
}
__device__ __forceinline__ float bflo(unsigned u) {
    union { unsigned u; float f; } v; v.u = u << 16;
    return v.f;
}
__device__ __forceinline__ float bfhi(unsigned u) {
    union { unsigned u; float f; } v; v.u = u & 0xffff0000u;
    return v.f;
}

// inclusive scan of 512 ints in LDS; strided for any blockDim.
__device__ __forceinline__ int* scan_incl_512(int* a, int* b, int tid, int nthr) {
    int* in = a; int* out = b;
    for (int off = 1; off < 512; off <<= 1) {
        for (int i = tid; i < 512; i += nthr)
            out[i] = in[i] + (i >= off ? in[i - off] : 0);
        __syncthreads();
        int* t = in; in = out; out = t;
    }
    return in;
}

// ---- GEMM + fused s/d epilogue: Hb[n,128](bf16) = X@W;  S,D[n,4] = head-dots ----
__global__ __launch_bounds__(256) void gemm_k(const float* __restrict__ X,
                                              const float* __restrict__ Wm,
                                              const float* __restrict__ a_src,
                                              const float* __restrict__ a_dst,
                                              unsigned short* __restrict__ Hb,
                                              float* __restrict__ S,
                                              float* __restrict__ D, int n) {
    __shared__ float sW[32 * 128];
    __shared__ float sX[32 * 32];
    __shared__ float sa[128], sb[128];
    if (threadIdx.x < 128) {
        sa[threadIdx.x] = a_src[threadIdx.x];
        sb[threadIdx.x] = a_dst[threadIdx.x];
    }
    int row0 = blockIdx.x * 32;
    int rt = threadIdx.x >> 5;   // 0..7 -> rows rt*4..rt*4+3
    int ct = threadIdx.x & 31;   // cols ct*4..ct*4+3
    int c0 = ct * 4;
    float4 acc[4];
#pragma unroll
    for (int i = 0; i < 4; i++) acc[i] = make_float4(0.f, 0.f, 0.f, 0.f);

    for (int k0 = 0; k0 < 128; k0 += 32) {
        __syncthreads();
        for (int i = threadIdx.x * 4; i < 32 * 128; i += 1024)
            *(float4*)&sW[i] = *(const float4*)&Wm[(k0 + (i >> 7)) * 128 + (i & 127)];
        {
            int i = threadIdx.x * 4;   // covers 32*32 exactly
            int r = i >> 5, kk = i & 31;
            int gr = row0 + r;
            float4 v = make_float4(0.f, 0.f, 0.f, 0.f);
            if (gr < n) v = *(const float4*)&X[gr * 128 + k0 + kk];
            *(float4*)&sX[i] = v;
        }
        __syncthreads();
#pragma unroll
        for (int kk = 0; kk < 32; kk += 4) {
            float4 w0 = *(const float4*)&sW[(kk + 0) * 128 + c0];
            float4 w1 = *(const float4*)&sW[(kk + 1) * 128 + c0];
            float4 w2 = *(const float4*)&sW[(kk + 2) * 128 + c0];
            float4 w3 = *(const float4*)&sW[(kk + 3) * 128 + c0];
#pragma unroll
            for (int i = 0; i < 4; i++) {
                float4 xv = *(const float4*)&sX[(rt * 4 + i) * 32 + kk];
                acc[i].x = fmaf(xv.x, w0.x, acc[i].x);
                acc[i].y = fmaf(xv.x, w0.y, acc[i].y);
                acc[i].z = fmaf(xv.x, w0.z, acc[i].z);
                acc[i].w = fmaf(xv.x, w0.w, acc[i].w);
                acc[i].x = fmaf(xv.y, w1.x, acc[i].x);
                acc[i].y = fmaf(xv.y, w1.y, acc[i].y);
                acc[i].z = fmaf(xv.y, w1.z, acc[i].z);
                acc[i].w = fmaf(xv.y, w1.w, acc[i].w);
                acc[i].x = fmaf(xv.z, w2.x, acc[i].x);
                acc[i].y = fmaf(xv.z, w2.y, acc[i].y);
                acc[i].z = fmaf(xv.z, w2.z, acc[i].z);
                acc[i].w = fmaf(xv.z, w2.w, acc[i].w);
                acc[i].x = fmaf(xv.w, w3.x, acc[i].x);
                acc[i].y = fmaf(xv.w, w3.y, acc[i].y);
                acc[i].z = fmaf(xv.w, w3.z, acc[i].z);
                acc[i].w = fmaf(xv.w, w3.w, acc[i].w);
            }
        }
    }
    // fused s/d epilogue: reduce over the 8 lanes sharing a head (ct bits 0..2)
    float sp[4], dp[4];
    const float* ap = &sa[c0];
    const float* bp = &sb[c0];
#pragma unroll
    for (int i = 0; i < 4; i++) {
        sp[i] = acc[i].x * ap[0] + acc[i].y * ap[1] + acc[i].z * ap[2] + acc[i].w * ap[3];
        dp[i] = acc[i].x * bp[0] + acc[i].y * bp[1] + acc[i].z * bp[2] + acc[i].w * bp[3];
    }
#pragma unroll
    for (int o = 1; o < 8; o <<= 1) {
#pragma unroll
        for (int i = 0; i < 4; i++) {
            sp[i] += __shfl_xor(sp[i], o, 64);
            dp[i] += __shfl_xor(dp[i], o, 64);
        }
    }
    int hd = ct >> 3;
#pragma unroll
    for (int i = 0; i < 4; i++) {
        int gr = row0 + rt * 4 + i;
        if (gr < n) {
            ushort4 hb;
            hb.x = f2bf(acc[i].x); hb.y = f2bf(acc[i].y);
            hb.z = f2bf(acc[i].z); hb.w = f2bf(acc[i].w);
            *(ushort4*)&Hb[gr * 128 + c0] = hb;
            if ((ct & 7) == 0) {
                S[gr * 4 + hd] = sp[i];
                D[gr * 4 + hd] = dp[i];
            }
        }
    }
}

__global__ void fill_f_k(float* __restrict__ p, float v, int cnt) {
    int i = blockIdx.x * blockDim.x + threadIdx.x;
    if (i < cnt) p[i] = v;
}
__global__ void fill_i_k(int* __restrict__ p, int v, int cnt) {
    int i = blockIdx.x * blockDim.x + threadIdx.x;
    if (i < cnt) p[i] = v;
}

// ---------------- CSR build: binned counting sort ----------------
// bucket = dst >> 7 (128 dsts per bucket)

__global__ void bhist_k(const int* __restrict__ ei, int* __restrict__ bcount, int E) {
    __shared__ int h[NBMAX];
    for (int i = threadIdx.x; i < NBMAX; i += 256) h[i] = 0;
    __syncthreads();
    for (int e = blockIdx.x * blockDim.x + threadIdx.x; e < E; e += gridDim.x * blockDim.x)
        atomicAdd(&h[ei[E + e] >> 7], 1);
    __syncthreads();
    for (int i = threadIdx.x; i < NBMAX; i += 256)
        if (h[i]) atomicAdd(&bcount[i], h[i]);
}

__global__ void bscan_k(const int* __restrict__ bcount, int* __restrict__ bbase,
                        int* __restrict__ cursor, int NB) {
    __shared__ int sa[512], sb[512];
    int tid = threadIdx.x;
    for (int i = tid; i < 512; i += 256) sa[i] = (i < NB) ? bcount[i] : 0;
    __syncthreads();
    int* inc = scan_incl_512(sa, sb, tid, 256);
    for (int i = tid; i < NB; i += 256) {
        int ex = i ? inc[i - 1] : 0;
        bbase[i] = ex;
        cursor[i] = ex;
    }
    if (tid == 0) bbase[NB] = inc[NB - 1];
}

// tile -> LDS counting-sort by bucket -> bucket-grouped coalesced flush
__global__ __launch_bounds__(256) void bin_scatter_k(const int* __restrict__ ei,
                                                     int* __restrict__ cursor,
                                                     unsigned* __restrict__ binned, int E) {
    __shared__ int hist[NBMAX], excl[NBMAX], curl[NBMAX], gbase[NBMAX];
    __shared__ int sa[512], sb[512];
    __shared__ unsigned staged[TILE];
    int tid = threadIdx.x;
    int e0 = blockIdx.x * TILE;
    for (int i = tid; i < NBMAX; i += 256) hist[i] = 0;
    __syncthreads();
    unsigned keys[TILE / 256];
#pragma unroll
    for (int j = 0; j < TILE / 256; j++) {
        int e = e0 + j * 256 + tid;
        if (e < E) {
            unsigned dst = (unsigned)ei[E + e];
            unsigned src = (unsigned)ei[e];
            unsigned k = (dst << 16) | src;
            keys[j] = k;
            atomicAdd(&hist[k >> 23], 1);
        } else keys[j] = 0xFFFFFFFFu;
    }
    __syncthreads();
    for (int i = tid; i < 512; i += 256) sa[i] = hist[i];
    __syncthreads();
    int* inc = scan_incl_512(sa, sb, tid, 256);
    for (int i = tid; i < NBMAX; i += 256) {
        int ex = i ? inc[i - 1] : 0;
        excl[i] = ex;
        curl[i] = ex;
    }
    __syncthreads();
#pragma unroll
    for (int j = 0; j < TILE / 256; j++) {
        unsigned k = keys[j];
        if (k != 0xFFFFFFFFu) {
            int b = k >> 23;
            int p = atomicAdd(&curl[b], 1);
            staged[p] = k;
        }
    }
    __syncthreads();
    for (int i = tid; i < NBMAX; i += 256) {
        int cnt = hist[i];
        if (cnt) gbase[i] = atomicAdd(&cursor[i], cnt);
    }
    __syncthreads();
    int total = inc[511];
    for (int p = tid; p < total; p += 256) {
        unsigned k = staged[p];
        int b = k >> 23;
        binned[gbase[b] + (p - excl[b])] = k;
    }
}

// one block (1024 thr) per bucket: scatter into per-dst segments (arbitrary order),
// then canonicalize each segment with a register shuffle rank sort (no LDS in loop).
__global__ __launch_bounds__(1024) void bucket_csr_k(const unsigned* __restrict__ binned,
                                                     const int* __restrict__ bbase,
                                                     int* __restrict__ rowptr,
                                                     int* __restrict__ csr,
                                                     int n, int NB) {
    __shared__ int outL[BCAP];
    __shared__ int sa[512], sb[512];
    __shared__ int lbase[129], cur[128];
    int b = blockIdx.x;
    int tid = threadIdx.x;
    int dst0 = b << 7;
    int ndst = min(128, n - dst0);
    int ebase = bbase[b], ecnt = bbase[b + 1] - ebase;
    // hist (+1 for the self loop of each dst)
    for (int i = tid; i < 512; i += 1024) sa[i] = (i < ndst) ? 1 : 0;
    __syncthreads();
    for (int p = tid; p < ecnt; p += 1024) {
        int ld = (int)(binned[ebase + p] >> 16) - dst0;
        atomicAdd(&sa[ld], 1);
    }
    __syncthreads();
    int* inc = scan_incl_512(sa, sb, tid, 1024);
    for (int i = tid; i < ndst; i += 1024) {
        int ex = i ? inc[i - 1] : 0;
        lbase[i] = ex;
        cur[i] = ex;
    }
    if (tid == 0) lbase[ndst] = inc[ndst - 1];
    __syncthreads();
    int total = lbase[ndst];
    // scatter self loops + edges (arrival order arbitrary; rank sort fixes it)
    for (int i = tid; i < ndst; i += 1024) {
        int p = atomicAdd(&cur[i], 1);
        outL[p] = dst0 + i;
    }
    for (int p = tid; p < ecnt; p += 1024) {
        unsigned k = binned[ebase + p];
        int ld = (int)(k >> 16) - dst0;
        int pos = atomicAdd(&cur[ld], 1);
        outL[pos] = (int)(k & 0xFFFFu);
    }
    __syncthreads();
    // canonical order: one wave per dst, register shuffle rank sort
    int w = tid >> 6, lane = tid & 63;
    for (int d = w; d < ndst; d += 16) {
        int st = lbase[d], en = lbase[d + 1];
        int deg = en - st;
        if (deg <= 1) continue;
        if (deg <= 64) {
            int v = (lane < deg) ? outL[st + lane] : INT_MAX;
            int r = 0;
            for (int j = 0; j < deg; j++) {
                int kj = __shfl(v, j, 64);
                r += (kj < v) || (kj == v && j < lane);
            }
            if (lane < deg) outL[st + r] = v;
        } else if (deg <= 128) {
            int v0 = (lane < deg) ? outL[st + lane] : 0;
            int v1 = (64 + lane < deg) ? outL[st + 64 + lane] : 0;
            int r0 = 0, r1 = 0;
            for (int j = 0; j < deg; j++) {
                int kj = outL[st + j];
                r0 += (kj < v0) || (kj == v0 && j < lane);
                r1 += (kj < v1) || (kj == v1 && j < 64 + lane);
            }
            if (lane < deg) outL[st + r0] = v0;
            if (64 + lane < deg) outL[st + r1] = v1;
        } else if (lane == 0) {
            for (int q = st + 1; q < en; q++) {
                int key = outL[q];
                int r = q - 1;
                while (r >= st && outL[r] > key) { outL[r + 1] = outL[r]; r--; }
                outL[r + 1] = key;
            }
        }
    }
    __syncthreads();
    int gb = ebase + dst0;   // self loops of earlier buckets = dst0
    for (int p = tid; p < total; p += 1024) csr[gb + p] = outL[p];
    for (int i = tid; i < ndst; i += 1024) rowptr[dst0 + i] = gb + lbase[i];
    if (b == NB - 1 && tid == 0) rowptr[n] = gb + total;
}

// ---- fused softmax + aggregate + bias + act ----
// Phase 0: coalesced preload of the block's contiguous csr range into LDS.
// Phase 1: 16-lane group per dst -> alpha (pre-divided) in LDS.
// Phase 2: 4 dsts per wave; 2x-unrolled edge loop, 8 Hb gathers in flight/wave.
__global__ __launch_bounds__(256) void attn_agg_k(const int* __restrict__ rowptr,
                                                  const int* __restrict__ csr,
                                                  const float* __restrict__ S,
                                                  const float* __restrict__ Dv,
                                                  const unsigned short* __restrict__ Hb,
                                                  const float* __restrict__ bias,
                                                  float* __restrict__ Out, int n) {
    __shared__ float al[DPB][CAP * 4];
    __shared__ int srcs[LCAP];
    __shared__ float sm[DPB][4], srd[DPB][4], sdv[DPB][4];
    __shared__ int srp[DPB + 1];
    int tid = threadIdx.x;
    int base = blockIdx.x * DPB;
    if (tid <= DPB) {
        int idx = base + tid;
        srp[tid] = rowptr[idx > n ? n : idx];
    }
    __syncthreads();
    int st0 = srp[0];
    int etot = srp[DPB] - st0;
    for (int i = tid; i < etot && i < LCAP; i += 256) srcs[i] = csr[st0 + i];
    __syncthreads();

    // ---- phase 1: stats (16-lane group per dst) ----
    {
        int g = tid >> 4;     // 0..15
        int l = tid & 15;
        int dst = base + g;
        if (dst < n) {
            int lst = srp[g] - st0;
            int deg = srp[g + 1] - srp[g];
            float4 dv = *(const float4*)&Dv[dst * 4];
            float4 m = make_float4(-INFINITY, -INFINITY, -INFINITY, -INFINITY);
            for (int pos = l; pos < deg; pos += 16) {
                int idx = lst + pos;
                int src = (idx < LCAP) ? srcs[idx] : csr[st0 + idx];
                float4 sv = *(const float4*)&S[src * 4];
                float4 e;
                e.x = lrelu(sv.x + dv.x, LRELU_ATT);
                e.y = lrelu(sv.y + dv.y, LRELU_ATT);
                e.z = lrelu(sv.z + dv.z, LRELU_ATT);
                e.w = lrelu(sv.w + dv.w, LRELU_ATT);
                if (pos < CAP) *(float4*)&al[g][pos * 4] = e;
                m.x = fmaxf(m.x, e.x); m.y = fmaxf(m.y, e.y);
                m.z = fmaxf(m.z, e.z); m.w = fmaxf(m.w, e.w);
            }
#pragma unroll
            for (int o = 1; o < 16; o <<= 1) {
                m.x = fmaxf(m.x, __shfl_xor(m.x, o, 64));
                m.y = fmaxf(m.y, __shfl_xor(m.y, o, 64));
                m.z = fmaxf(m.z, __shfl_xor(m.z, o, 64));
                m.w = fmaxf(m.w, __shfl_xor(m.w, o, 64));
            }
            float4 den = make_float4(0.f, 0.f, 0.f, 0.f);
            for (int pos = l; pos < deg; pos += 16) {
                float4 e;
                if (pos < CAP) e = *(const float4*)&al[g][pos * 4];
                else {
                    int idx = lst + pos;
                    int src = (idx < LCAP) ? srcs[idx] : csr[st0 + idx];
                    float4 sv = *(const float4*)&S[src * 4];
                    e.x = lrelu(sv.x + dv.x, LRELU_ATT);
                    e.y = lrelu(sv.y + dv.y, LRELU_ATT);
                    e.z = lrelu(sv.z + dv.z, LRELU_ATT);
                    e.w = lrelu(sv.w + dv.w, LRELU_ATT);
                }
                float4 ex;
                ex.x = __expf(e.x - m.x); ex.y = __expf(e.y - m.y);
                ex.z = __expf(e.z - m.z); ex.w = __expf(e.w - m.w);
                den.x += ex.x; den.y += ex.y; den.z += ex.z; den.w += ex.w;
                if (pos < CAP) *(float4*)&al[g][pos * 4] = ex;
            }
#pragma unroll
            for (int o = 1; o < 16; o <<= 1) {
                den.x += __shfl_xor(den.x, o, 64);
                den.y += __shfl_xor(den.y, o, 64);
                den.z += __shfl_xor(den.z, o, 64);
                den.w += __shfl_xor(den.w, o, 64);
            }
            float4 rd;
            rd.x = 1.f / den.x; rd.y = 1.f / den.y;
            rd.z = 1.f / den.z; rd.w = 1.f / den.w;
            int lim = deg < CAP ? deg : CAP;
            for (int pos = l; pos < lim; pos += 16) {
                float4 ex = *(const float4*)&al[g][pos * 4];
                ex.x *= rd.x; ex.y *= rd.y; ex.z *= rd.z; ex.w *= rd.w;
                *(float4*)&al[g][pos * 4] = ex;
            }
            if (l == 0) {
                *(float4*)&sm[g][0] = m;
                *(float4*)&srd[g][0] = rd;
                *(float4*)&sdv[g][0] = dv;
            }
        }
    }
    __syncthreads();

    // ---- phase 2: aggregation, 4 dsts per wave, 8 gathers in flight ----
    int w = tid >> 6;
    int lane = tid & 63;
    int slot = lane >> 4;        // edge slot 0..3
    int l16 = lane & 15;
    int ch0 = l16 * 8;           // 8 channels per lane
    int hd = l16 >> 2;           // head of this lane's channels
#pragma unroll
    for (int j = 0; j < 4; j++) {
        int g2 = w * 4 + j;
        int dst = base + g2;
        if (dst >= n) break;
        int lst = srp[g2] - st0;
        int deg = srp[g2 + 1] - srp[g2];
        float4 a0 = make_float4(0.f, 0.f, 0.f, 0.f);
        float4 a1 = make_float4(0.f, 0.f, 0.f, 0.f);
        float4 b0 = make_float4(0.f, 0.f, 0.f, 0.f);
        float4 b1 = make_float4(0.f, 0.f, 0.f, 0.f);
        int pos = slot;
        for (; pos + 4 < deg; pos += 8) {
            int iA = lst + pos, iB = iA + 4;
            int srcA = (iA < LCAP) ? srcs[iA] : csr[st0 + iA];
            int srcB = (iB < LCAP) ? srcs[iB] : csr[st0 + iB];
            float aA = (pos < CAP) ? al[g2][pos * 4 + hd]
                : __expf(lrelu(S[srcA * 4 + hd] + sdv[g2][hd], LRELU_ATT) - sm[g2][hd]) * srd[g2][hd];
            float aB = (pos + 4 < CAP) ? al[g2][(pos + 4) * 4 + hd]
                : __expf(lrelu(S[srcB * 4 + hd] + sdv[g2][hd], LRELU_ATT) - sm[g2][hd]) * srd[g2][hd];
            uint4 hvA = *(const uint4*)&Hb[srcA * 128 + ch0];
            uint4 hvB = *(const uint4*)&Hb[srcB * 128 + ch0];
            a0.x = fmaf(aA, bflo(hvA.x), a0.x);
            a0.y = fmaf(aA, bfhi(hvA.x), a0.y);
            a0.z = fmaf(aA, bflo(hvA.y), a0.z);
            a0.w = fmaf(aA, bfhi(hvA.y), a0.w);
            a1.x = fmaf(aA, bflo(hvA.z), a1.x);
            a1.y = fmaf(aA, bfhi(hvA.z), a1.y);
            a1.z = fmaf(aA, bflo(hvA.w), a1.z);
            a1.w = fmaf(aA, bfhi(hvA.w), a1.w);
            b0.x = fmaf(aB, bflo(hvB.x), b0.x);
            b0.y = fmaf(aB, bfhi(hvB.x), b0.y);
            b0.z = fmaf(aB, bflo(hvB.y), b0.z);
            b0.w = fmaf(aB, bfhi(hvB.y), b0.w);
            b1.x = fmaf(aB, bflo(hvB.z), b1.x);
            b1.y = fmaf(aB, bfhi(hvB.z), b1.y);
            b1.z = fmaf(aB, bflo(hvB.w), b1.z);
            b1.w = fmaf(aB, bfhi(hvB.w), b1.w);
        }
        if (pos < deg) {
            int iA = lst + pos;
            int srcA = (iA < LCAP) ? srcs[iA] : csr[st0 + iA];
            float aA = (pos < CAP) ? al[g2][pos * 4 + hd]
                : __expf(lrelu(S[srcA * 4 + hd] + sdv[g2][hd], LRELU_ATT) - sm[g2][hd]) * srd[g2][hd];
            uint4 hvA = *(const uint4*)&Hb[srcA * 128 + ch0];
            a0.x = fmaf(aA, bflo(hvA.x), a0.x);
            a0.y = fmaf(aA, bfhi(hvA.x), a0.y);
            a0.z = fmaf(aA, bflo(hvA.y), a0.z);
            a0.w = fmaf(aA, bfhi(hvA.y), a0.w);
            a1.x = fmaf(aA, bflo(hvA.z), a1.x);
            a1.y = fmaf(aA, bfhi(hvA.z), a1.y);
            a1.z = fmaf(aA, bflo(hvA.w), a1.z);
            a1.w = fmaf(aA, bfhi(hvA.w), a1.w);
        }
        a0.x += b0.x; a0.y += b0.y; a0.z += b0.z; a0.w += b0.w;
        a1.x += b1.x; a1.y += b1.y; a1.z += b1.z; a1.w += b1.w;
#pragma unroll
        for (int o = 16; o <= 32; o <<= 1) {
            a0.x += __shfl_xor(a0.x, o, 64);
            a0.y += __shfl_xor(a0.y, o, 64);
            a0.z += __shfl_xor(a0.z, o, 64);
            a0.w += __shfl_xor(a0.w, o, 64);
            a1.x += __shfl_xor(a1.x, o, 64);
            a1.y += __shfl_xor(a1.y, o, 64);
            a1.z += __shfl_xor(a1.z, o, 64);
            a1.w += __shfl_xor(a1.w, o, 64);
        }
        if (slot == 0) {
            float4 c0v = *(const float4*)&bias[ch0];
            float4 c1v = *(const float4*)&bias[ch0 + 4];
            float4 o0, o1;
            o0.x = lrelu(a0.x + c0v.x, LRELU_ACT);
            o0.y = lrelu(a0.y + c0v.y, LRELU_ACT);
            o0.z = lrelu(a0.z + c0v.z, LRELU_ACT);
            o0.w = lrelu(a0.w + c0v.w, LRELU_ACT);
            o1.x = lrelu(a1.x + c1v.x, LRELU_ACT);
            o1.y = lrelu(a1.y + c1v.y, LRELU_ACT);
            o1.z = lrelu(a1.z + c1v.z, LRELU_ACT);
            o1.w = lrelu(a1.w + c1v.w, LRELU_ACT);
            *(float4*)&Out[dst * 128 + ch0] = o0;
            *(float4*)&Out[dst * 128 + ch0 + 4] = o1;
        }
    }
}

// ---------------- graph embedding: segment max over sorted batch ----------------
__global__ void ge_max_k(const float* __restrict__ Hf, const int* __restrict__ batch,
                         float* __restrict__ ge, int n) {
    int c = threadIdx.x & 127;
    int rh = threadIdx.x >> 7;  // 0..1
    int node0 = blockIdx.x * 128;
    int hi = min(node0 + 128, n);
    int gid = -1;
    float mv = -INFINITY;
    for (int r = node0 + rh; r < hi; r += 2) {
        int g = batch[r];
        if (g != gid) {
            if (gid >= 0) atomicMaxF(&ge[gid * 128 + c], mv);
            gid = g;
            mv = -INFINITY;
        }
        mv = fmaxf(mv, Hf[r * 128 + c]);
    }
    if (gid >= 0) atomicMaxF(&ge[gid * 128 + c], mv);
}

__global__ void ei_copy_k(const int* __restrict__ ei, float* __restrict__ out, int m) {
    int i = (blockIdx.x * blockDim.x + threadIdx.x) * 4;
    if (i + 3 < m) {
        int4 v = *(const int4*)&ei[i];
        float4 o = make_float4((float)v.x, (float)v.y, (float)v.z, (float)v.w);
        *(float4*)&out[i] = o;
    } else {
        for (; i < m; i++) out[i] = (float)ei[i];
    }
}

extern "C" void kernel_launch(void* const* d_in, const int* in_sizes, int n_in,
                              void* d_out, int out_size, void* d_ws, size_t ws_size,
                              hipStream_t stream) {
    const float* x = (const float*)d_in[0];
    const int* ei = (const int*)d_in[1];
    const int* batch = (const int*)d_in[2];
    const float* Wm[3]   = {(const float*)d_in[3], (const float*)d_in[7],  (const float*)d_in[11]};
    const float* asrc[3] = {(const float*)d_in[4], (const float*)d_in[8],  (const float*)d_in[12]};
    const float* adst[3] = {(const float*)d_in[5], (const float*)d_in[9],  (const float*)d_in[13]};
    const float* bias[3] = {(const float*)d_in[6], (const float*)d_in[10], (const float*)d_in[14]};

    const int n = in_sizes[2];          // 50000 nodes
    const int E = in_sizes[1] / 2;      // 800000 edges
    const int ne = E + n;               // + self loops
    const int G = (out_size - n * 128 - 2 * E) / 128;  // 64 graphs
    const int NB = (n + 127) >> 7;      // 391 buckets

    // workspace layout
    char* w = (char*)d_ws;
    float* Xact = (float*)w;          w += (size_t)n * 128 * 4;
    unsigned short* Hb = (unsigned short*)w; w += (size_t)n * 128 * 2;
    float* S    = (float*)w; w += (size_t)n * 4 * 4;
    float* D    = (float*)w; w += (size_t)n * 4 * 4;
    int* bcount = (int*)w;   w += NBMAX * 4;
    int* bbase  = (int*)w;   w += (NBMAX + 1) * 4;
    int* cursor = (int*)w;   w += NBMAX * 4;
    int* rowptr = (int*)w;   w += (size_t)(n + 1) * 4;
    unsigned* binned = (unsigned*)w; w += (size_t)E * 4;
    int* csr    = (int*)w;   w += (size_t)ne * 4;

    float* out   = (float*)d_out;
    float* ge    = out;
    float* hout  = out + (size_t)G * 128;
    float* eiout = out + (size_t)G * 128 + (size_t)n * 128;

    // ---- CSR build: binned counting sort ----
    fill_i_k<<<(NBMAX + 255) / 256, 256, 0, stream>>>(bcount, 0, NBMAX);
    bhist_k<<<256, 256, 0, stream>>>(ei, bcount, E);
    bscan_k<<<1, 256, 0, stream>>>(bcount, bbase, cursor, NB);
    bin_scatter_k<<<(E + TILE - 1) / TILE, 256, 0, stream>>>(ei, cursor, binned, E);
    bucket_csr_k<<<NB, 1024, 0, stream>>>(binned, bbase, rowptr, csr, n, NB);

    // ---- 3 GAT layers ----
    const float* xin = x;
    for (int L = 0; L < 3; L++) {
        gemm_k<<<(n + 31) / 32, 256, 0, stream>>>(xin, Wm[L], asrc[L], adst[L], Hb, S, D, n);
        float* xnext = (L == 2) ? hout : Xact;
        attn_agg_k<<<(n + DPB - 1) / DPB, 256, 0, stream>>>(rowptr, csr, S, D, Hb, bias[L], xnext, n);
        xin = xnext;
    }

    // ---- readout ----
    fill_f_k<<<(G * 128 + 255) / 256, 256, 0, stream>>>(ge, -INFINITY, G * 128);
    ge_max_k<<<(n + 127) / 128, 256, 0, stream>>>(hout, batch, ge, n);
    ei_copy_k<<<(2 * E / 4 + 255) / 256, 256, 0, stream>>>(ei, eiout, 2 * E);
}

// Round 10
// 308.523 us; speedup vs baseline: 12.5529x; 1.0409x over previous
//
#include <hip/hip_runtime.h>
#include <math.h>
#include <limits.h>

#define LRELU_ATT 0.2f
#define LRELU_ACT 0.01f
#define CAP 64    // cached alphas per dst in LDS (deg > CAP falls back to recompute)
#define DPB 16    // dsts per block in attn_agg
#define LCAP (DPB * CAP)  // flat per-block src cache entries
#define NBMAX 512 // max buckets (n <= 65536, 128 dsts/bucket)
#define TILE 8192 // edges per bin_scatter block
#define BCAP 6528 // LDS capacity per bucket in bucket_csr (edges + selfs)
#define WPAD 136  // padded K-stride (bf16 elems) for MFMA LDS tiles

typedef __attribute__((ext_vector_type(8))) short bf16x8;
typedef __attribute__((ext_vector_type(4))) float f32x4;

__device__ __forceinline__ float lrelu(float x, float s) { return x > 0.f ? x : x * s; }

__device__ __forceinline__ void atomicMaxF(float* addr, float val) {
    int* ai = (int*)addr;
    int old = *(volatile int*)ai;
    while (__int_as_float(old) < val) {
        int assumed = old;
        old = atomicCAS(ai, assumed, __float_as_int(val));
        if (old == assumed) break;
    }
}

__device__ __forceinline__ unsigned short f2bf(float f) {
    union { float f; unsigned u; } v; v.f = f;
    unsigned r = v.u + 0x7FFF + ((v.u >> 16) & 1);   // RNE
    return (unsigned short)(r >> 16);
}
__device__ __forceinline__ float bflo(unsigned u) {
    union { unsigned u; float f; } v; v.u = u << 16;
    return v.f;
}
__device__ __forceinline__ float bfhi(unsigned u) {
    union { unsigned u; float f; } v; v.u = u & 0xffff0000u;
    return v.f;
}

// inclusive scan of 512 ints in LDS; strided for any blockDim.
__device__ __forceinline__ int* scan_incl_512(int* a, int* b, int tid, int nthr) {
    int* in = a; int* out = b;
    for (int off = 1; off < 512; off <<= 1) {
        for (int i = tid; i < 512; i += nthr)
            out[i] = in[i] + (i >= off ? in[i - off] : 0);
        __syncthreads();
        int* t = in; in = out; out = t;
    }
    return in;
}

// ---- MFMA GEMM + fused s/d epilogue: Hb[n,128](bf16) = X@W;  S,D[n,4] ----
// 64 rows/block, 4 waves; W transposed to LDS bf16 (Wt[n][k], pad 136);
// per wave: 16-row tile x 128 cols = 8 col-tiles, 4 K-steps of 16x16x32 MFMA.
__global__ __launch_bounds__(256) void gemm_k(const float* __restrict__ X,
                                              const float* __restrict__ Wm,
                                              const float* __restrict__ a_src,
                                              const float* __restrict__ a_dst,
                                              unsigned short* __restrict__ Hb,
                                              float* __restrict__ S,
                                              float* __restrict__ D, int n) {
    __shared__ unsigned short sWt[128 * WPAD];   // Wt[n][k]
    __shared__ unsigned short sXt[64 * WPAD];    // X[r][k]
    __shared__ float sa[128], sb[128];
    int tid = threadIdx.x;
    if (tid < 128) { sa[tid] = a_src[tid]; sb[tid] = a_dst[tid]; }
    int row0 = blockIdx.x * 64;
    // stage W transposed as bf16
#pragma unroll
    for (int i = 0; i < 16; i++) {
        int idx4 = tid + 256 * i;            // 4096 float4 groups over 128x128
        int k = idx4 >> 5;
        int n0 = (idx4 & 31) * 4;
        float4 wv = *(const float4*)&Wm[k * 128 + n0];
        sWt[(n0 + 0) * WPAD + k] = f2bf(wv.x);
        sWt[(n0 + 1) * WPAD + k] = f2bf(wv.y);
        sWt[(n0 + 2) * WPAD + k] = f2bf(wv.z);
        sWt[(n0 + 3) * WPAD + k] = f2bf(wv.w);
    }
    // stage X rows as bf16
#pragma unroll
    for (int i = 0; i < 8; i++) {
        int idx4 = tid + 256 * i;            // 2048 float4 groups over 64x128
        int r = idx4 >> 5;
        int koff = (idx4 & 31) * 4;
        int gr = row0 + r;
        float4 xv = make_float4(0.f, 0.f, 0.f, 0.f);
        if (gr < n) xv = *(const float4*)&X[gr * 128 + koff];
        ushort4 xb;
        xb.x = f2bf(xv.x); xb.y = f2bf(xv.y); xb.z = f2bf(xv.z); xb.w = f2bf(xv.w);
        *(ushort4*)&sXt[r * WPAD + koff] = xb;
    }
    __syncthreads();
    int w = tid >> 6, l = tid & 63;
    int lr = l & 15, lk = l >> 4;            // lr: row/col-in-tile, lk: k-group
    f32x4 acc[8];
#pragma unroll
    for (int ct = 0; ct < 8; ct++) acc[ct] = (f32x4){0.f, 0.f, 0.f, 0.f};
#pragma unroll
    for (int ks = 0; ks < 4; ks++) {
        int kbase = ks * 32 + lk * 8;
        bf16x8 afrag = *(const bf16x8*)&sXt[(w * 16 + lr) * WPAD + kbase];
#pragma unroll
        for (int ct = 0; ct < 8; ct++) {
            bf16x8 bfrag = *(const bf16x8*)&sWt[(ct * 16 + lr) * WPAD + kbase];
            acc[ct] = __builtin_amdgcn_mfma_f32_16x16x32_bf16(afrag, bfrag, acc[ct], 0, 0, 0);
        }
    }
    // fused s/d: lane holds rows (lk*4+reg) of this wave's tile, cols ct*16+lr.
    float sp[4][4], dp[4][4];   // [reg][head]
#pragma unroll
    for (int reg = 0; reg < 4; reg++) {
#pragma unroll
        for (int hd = 0; hd < 4; hd++) {
            int c0 = (2 * hd) * 16 + lr;
            int c1 = (2 * hd + 1) * 16 + lr;
            sp[reg][hd] = acc[2 * hd][reg] * sa[c0] + acc[2 * hd + 1][reg] * sa[c1];
            dp[reg][hd] = acc[2 * hd][reg] * sb[c0] + acc[2 * hd + 1][reg] * sb[c1];
        }
    }
#pragma unroll
    for (int o = 1; o < 16; o <<= 1) {
#pragma unroll
        for (int reg = 0; reg < 4; reg++) {
#pragma unroll
            for (int hd = 0; hd < 4; hd++) {
                sp[reg][hd] += __shfl_xor(sp[reg][hd], o, 64);
                dp[reg][hd] += __shfl_xor(dp[reg][hd], o, 64);
            }
        }
    }
#pragma unroll
    for (int reg = 0; reg < 4; reg++) {
        int gr = row0 + w * 16 + lk * 4 + reg;
        if (gr < n) {
#pragma unroll
            for (int ct = 0; ct < 8; ct++)
                Hb[gr * 128 + ct * 16 + lr] = f2bf(acc[ct][reg]);
            if (lr == 0) {
                *(float4*)&S[gr * 4] = make_float4(sp[reg][0], sp[reg][1], sp[reg][2], sp[reg][3]);
                *(float4*)&D[gr * 4] = make_float4(dp[reg][0], dp[reg][1], dp[reg][2], dp[reg][3]);
            }
        }
    }
}

__global__ void fill_f_k(float* __restrict__ p, float v, int cnt) {
    int i = blockIdx.x * blockDim.x + threadIdx.x;
    if (i < cnt) p[i] = v;
}
__global__ void fill_i_k(int* __restrict__ p, int v, int cnt) {
    int i = blockIdx.x * blockDim.x + threadIdx.x;
    if (i < cnt) p[i] = v;
}

// ---------------- CSR build: binned counting sort ----------------
__global__ void bhist_k(const int* __restrict__ ei, int* __restrict__ bcount, int E) {
    __shared__ int h[NBMAX];
    for (int i = threadIdx.x; i < NBMAX; i += 256) h[i] = 0;
    __syncthreads();
    for (int e = blockIdx.x * blockDim.x + threadIdx.x; e < E; e += gridDim.x * blockDim.x)
        atomicAdd(&h[ei[E + e] >> 7], 1);
    __syncthreads();
    for (int i = threadIdx.x; i < NBMAX; i += 256)
        if (h[i]) atomicAdd(&bcount[i], h[i]);
}

__global__ void bscan_k(const int* __restrict__ bcount, int* __restrict__ bbase,
                        int* __restrict__ cursor, int NB) {
    __shared__ int sa[512], sb[512];
    int tid = threadIdx.x;
    for (int i = tid; i < 512; i += 256) sa[i] = (i < NB) ? bcount[i] : 0;
    __syncthreads();
    int* inc = scan_incl_512(sa, sb, tid, 256);
    for (int i = tid; i < NB; i += 256) {
        int ex = i ? inc[i - 1] : 0;
        bbase[i] = ex;
        cursor[i] = ex;
    }
    if (tid == 0) bbase[NB] = inc[NB - 1];
}

__global__ __launch_bounds__(256) void bin_scatter_k(const int* __restrict__ ei,
                                                     int* __restrict__ cursor,
                                                     unsigned* __restrict__ binned, int E) {
    __shared__ int hist[NBMAX], excl[NBMAX], curl[NBMAX], gbase[NBMAX];
    __shared__ int sa[512], sb[512];
    __shared__ unsigned staged[TILE];
    int tid = threadIdx.x;
    int e0 = blockIdx.x * TILE;
    for (int i = tid; i < NBMAX; i += 256) hist[i] = 0;
    __syncthreads();
    unsigned keys[TILE / 256];
#pragma unroll
    for (int j = 0; j < TILE / 256; j++) {
        int e = e0 + j * 256 + tid;
        if (e < E) {
            unsigned dst = (unsigned)ei[E + e];
            unsigned src = (unsigned)ei[e];
            unsigned k = (dst << 16) | src;
            keys[j] = k;
            atomicAdd(&hist[k >> 23], 1);
        } else keys[j] = 0xFFFFFFFFu;
    }
    __syncthreads();
    for (int i = tid; i < 512; i += 256) sa[i] = hist[i];
    __syncthreads();
    int* inc = scan_incl_512(sa, sb, tid, 256);
    for (int i = tid; i < NBMAX; i += 256) {
        int ex = i ? inc[i - 1] : 0;
        excl[i] = ex;
        curl[i] = ex;
    }
    __syncthreads();
#pragma unroll
    for (int j = 0; j < TILE / 256; j++) {
        unsigned k = keys[j];
        if (k != 0xFFFFFFFFu) {
            int b = k >> 23;
            int p = atomicAdd(&curl[b], 1);
            staged[p] = k;
        }
    }
    __syncthreads();
    for (int i = tid; i < NBMAX; i += 256) {
        int cnt = hist[i];
        if (cnt) gbase[i] = atomicAdd(&cursor[i], cnt);
    }
    __syncthreads();
    int total = inc[511];
    for (int p = tid; p < total; p += 256) {
        unsigned k = staged[p];
        int b = k >> 23;
        binned[gbase[b] + (p - excl[b])] = k;
    }
}

__global__ __launch_bounds__(1024) void bucket_csr_k(const unsigned* __restrict__ binned,
                                                     const int* __restrict__ bbase,
                                                     int* __restrict__ rowptr,
                                                     int* __restrict__ csr,
                                                     int n, int NB) {
    __shared__ int outL[BCAP];
    __shared__ int sa[512], sb[512];
    __shared__ int lbase[129], cur[128];
    int b = blockIdx.x;
    int tid = threadIdx.x;
    int dst0 = b << 7;
    int ndst = min(128, n - dst0);
    int ebase = bbase[b], ecnt = bbase[b + 1] - ebase;
    for (int i = tid; i < 512; i += 1024) sa[i] = (i < ndst) ? 1 : 0;
    __syncthreads();
    for (int p = tid; p < ecnt; p += 1024) {
        int ld = (int)(binned[ebase + p] >> 16) - dst0;
        atomicAdd(&sa[ld], 1);
    }
    __syncthreads();
    int* inc = scan_incl_512(sa, sb, tid, 1024);
    for (int i = tid; i < ndst; i += 1024) {
        int ex = i ? inc[i - 1] : 0;
        lbase[i] = ex;
        cur[i] = ex;
    }
    if (tid == 0) lbase[ndst] = inc[ndst - 1];
    __syncthreads();
    int total = lbase[ndst];
    for (int i = tid; i < ndst; i += 1024) {
        int p = atomicAdd(&cur[i], 1);
        outL[p] = dst0 + i;
    }
    for (int p = tid; p < ecnt; p += 1024) {
        unsigned k = binned[ebase + p];
        int ld = (int)(k >> 16) - dst0;
        int pos = atomicAdd(&cur[ld], 1);
        outL[pos] = (int)(k & 0xFFFFu);
    }
    __syncthreads();
    int w = tid >> 6, lane = tid & 63;
    for (int d = w; d < ndst; d += 16) {
        int st = lbase[d], en = lbase[d + 1];
        int deg = en - st;
        if (deg <= 1) continue;
        if (deg <= 64) {
            int v = (lane < deg) ? outL[st + lane] : INT_MAX;
            int r = 0;
            for (int j = 0; j < deg; j++) {
                int kj = __shfl(v, j, 64);
                r += (kj < v) || (kj == v && j < lane);
            }
            if (lane < deg) outL[st + r] = v;
        } else if (deg <= 128) {
            int v0 = (lane < deg) ? outL[st + lane] : 0;
            int v1 = (64 + lane < deg) ? outL[st + 64 + lane] : 0;
            int r0 = 0, r1 = 0;
            for (int j = 0; j < deg; j++) {
                int kj = outL[st + j];
                r0 += (kj < v0) || (kj == v0 && j < lane);
                r1 += (kj < v1) || (kj == v1 && j < 64 + lane);
            }
            if (lane < deg) outL[st + r0] = v0;
            if (64 + lane < deg) outL[st + r1] = v1;
        } else if (lane == 0) {
            for (int q = st + 1; q < en; q++) {
                int key = outL[q];
                int r = q - 1;
                while (r >= st && outL[r] > key) { outL[r + 1] = outL[r]; r--; }
                outL[r + 1] = key;
            }
        }
    }
    __syncthreads();
    int gb = ebase + dst0;
    for (int p = tid; p < total; p += 1024) csr[gb + p] = outL[p];
    for (int i = tid; i < ndst; i += 1024) rowptr[dst0 + i] = gb + lbase[i];
    if (b == NB - 1 && tid == 0) rowptr[n] = gb + total;
}

// ---- fused softmax + aggregate + bias + act ----
__global__ __launch_bounds__(256) void attn_agg_k(const int* __restrict__ rowptr,
                                                  const int* __restrict__ csr,
                                                  const float* __restrict__ S,
                                                  const float* __restrict__ Dv,
                                                  const unsigned short* __restrict__ Hb,
                                                  const float* __restrict__ bias,
                                                  float* __restrict__ Out, int n) {
    __shared__ float al[DPB][CAP * 4];
    __shared__ int srcs[LCAP];
    __shared__ float sm[DPB][4], srd[DPB][4], sdv[DPB][4];
    __shared__ int srp[DPB + 1];
    int tid = threadIdx.x;
    int base = blockIdx.x * DPB;
    if (tid <= DPB) {
        int idx = base + tid;
        srp[tid] = rowptr[idx > n ? n : idx];
    }
    __syncthreads();
    int st0 = srp[0];
    int etot = srp[DPB] - st0;
    for (int i = tid; i < etot && i < LCAP; i += 256) srcs[i] = csr[st0 + i];
    __syncthreads();

    {
        int g = tid >> 4;
        int l = tid & 15;
        int dst = base + g;
        if (dst < n) {
            int lst = srp[g] - st0;
            int deg = srp[g + 1] - srp[g];
            float4 dv = *(const float4*)&Dv[dst * 4];
            float4 m = make_float4(-INFINITY, -INFINITY, -INFINITY, -INFINITY);
            for (int pos = l; pos < deg; pos += 16) {
                int idx = lst + pos;
                int src = (idx < LCAP) ? srcs[idx] : csr[st0 + idx];
                float4 sv = *(const float4*)&S[src * 4];
                float4 e;
                e.x = lrelu(sv.x + dv.x, LRELU_ATT);
                e.y = lrelu(sv.y + dv.y, LRELU_ATT);
                e.z = lrelu(sv.z + dv.z, LRELU_ATT);
                e.w = lrelu(sv.w + dv.w, LRELU_ATT);
                if (pos < CAP) *(float4*)&al[g][pos * 4] = e;
                m.x = fmaxf(m.x, e.x); m.y = fmaxf(m.y, e.y);
                m.z = fmaxf(m.z, e.z); m.w = fmaxf(m.w, e.w);
            }
#pragma unroll
            for (int o = 1; o < 16; o <<= 1) {
                m.x = fmaxf(m.x, __shfl_xor(m.x, o, 64));
                m.y = fmaxf(m.y, __shfl_xor(m.y, o, 64));
                m.z = fmaxf(m.z, __shfl_xor(m.z, o, 64));
                m.w = fmaxf(m.w, __shfl_xor(m.w, o, 64));
            }
            float4 den = make_float4(0.f, 0.f, 0.f, 0.f);
            for (int pos = l; pos < deg; pos += 16) {
                float4 e;
                if (pos < CAP) e = *(const float4*)&al[g][pos * 4];
                else {
                    int idx = lst + pos;
                    int src = (idx < LCAP) ? srcs[idx] : csr[st0 + idx];
                    float4 sv = *(const float4*)&S[src * 4];
                    e.x = lrelu(sv.x + dv.x, LRELU_ATT);
                    e.y = lrelu(sv.y + dv.y, LRELU_ATT);
                    e.z = lrelu(sv.z + dv.z, LRELU_ATT);
                    e.w = lrelu(sv.w + dv.w, LRELU_ATT);
                }
                float4 ex;
                ex.x = __expf(e.x - m.x); ex.y = __expf(e.y - m.y);
                ex.z = __expf(e.z - m.z); ex.w = __expf(e.w - m.w);
                den.x += ex.x; den.y += ex.y; den.z += ex.z; den.w += ex.w;
                if (pos < CAP) *(float4*)&al[g][pos * 4] = ex;
            }
#pragma unroll
            for (int o = 1; o < 16; o <<= 1) {
                den.x += __shfl_xor(den.x, o, 64);
                den.y += __shfl_xor(den.y, o, 64);
                den.z += __shfl_xor(den.z, o, 64);
                den.w += __shfl_xor(den.w, o, 64);
            }
            float4 rd;
            rd.x = 1.f / den.x; rd.y = 1.f / den.y;
            rd.z = 1.f / den.z; rd.w = 1.f / den.w;
            int lim = deg < CAP ? deg : CAP;
            for (int pos = l; pos < lim; pos += 16) {
                float4 ex = *(const float4*)&al[g][pos * 4];
                ex.x *= rd.x; ex.y *= rd.y; ex.z *= rd.z; ex.w *= rd.w;
                *(float4*)&al[g][pos * 4] = ex;
            }
            if (l == 0) {
                *(float4*)&sm[g][0] = m;
                *(float4*)&srd[g][0] = rd;
                *(float4*)&sdv[g][0] = dv;
            }
        }
    }
    __syncthreads();

    int w = tid >> 6;
    int lane = tid & 63;
    int slot = lane >> 4;
    int l16 = lane & 15;
    int ch0 = l16 * 8;
    int hd = l16 >> 2;
#pragma unroll
    for (int j = 0; j < 4; j++) {
        int g2 = w * 4 + j;
        int dst = base + g2;
        if (dst >= n) break;
        int lst = srp[g2] - st0;
        int deg = srp[g2 + 1] - srp[g2];
        float4 a0 = make_float4(0.f, 0.f, 0.f, 0.f);
        float4 a1 = make_float4(0.f, 0.f, 0.f, 0.f);
        float4 b0 = make_float4(0.f, 0.f, 0.f, 0.f);
        float4 b1 = make_float4(0.f, 0.f, 0.f, 0.f);
        int pos = slot;
        for (; pos + 4 < deg; pos += 8) {
            int iA = lst + pos, iB = iA + 4;
            int srcA = (iA < LCAP) ? srcs[iA] : csr[st0 + iA];
            int srcB = (iB < LCAP) ? srcs[iB] : csr[st0 + iB];
            float aA = (pos < CAP) ? al[g2][pos * 4 + hd]
                : __expf(lrelu(S[srcA * 4 + hd] + sdv[g2][hd], LRELU_ATT) - sm[g2][hd]) * srd[g2][hd];
            float aB = (pos + 4 < CAP) ? al[g2][(pos + 4) * 4 + hd]
                : __expf(lrelu(S[srcB * 4 + hd] + sdv[g2][hd], LRELU_ATT) - sm[g2][hd]) * srd[g2][hd];
            uint4 hvA = *(const uint4*)&Hb[srcA * 128 + ch0];
            uint4 hvB = *(const uint4*)&Hb[srcB * 128 + ch0];
            a0.x = fmaf(aA, bflo(hvA.x), a0.x);
            a0.y = fmaf(aA, bfhi(hvA.x), a0.y);
            a0.z = fmaf(aA, bflo(hvA.y), a0.z);
            a0.w = fmaf(aA, bfhi(hvA.y), a0.w);
            a1.x = fmaf(aA, bflo(hvA.z), a1.x);
            a1.y = fmaf(aA, bfhi(hvA.z), a1.y);
            a1.z = fmaf(aA, bflo(hvA.w), a1.z);
            a1.w = fmaf(aA, bfhi(hvA.w), a1.w);
            b0.x = fmaf(aB, bflo(hvB.x), b0.x);
            b0.y = fmaf(aB, bfhi(hvB.x), b0.y);
            b0.z = fmaf(aB, bflo(hvB.y), b0.z);
            b0.w = fmaf(aB, bfhi(hvB.y), b0.w);
            b1.x = fmaf(aB, bflo(hvB.z), b1.x);
            b1.y = fmaf(aB, bfhi(hvB.z), b1.y);
            b1.z = fmaf(aB, bflo(hvB.w), b1.z);
            b1.w = fmaf(aB, bfhi(hvB.w), b1.w);
        }
        if (pos < deg) {
            int iA = lst + pos;
            int srcA = (iA < LCAP) ? srcs[iA] : csr[st0 + iA];
            float aA = (pos < CAP) ? al[g2][pos * 4 + hd]
                : __expf(lrelu(S[srcA * 4 + hd] + sdv[g2][hd], LRELU_ATT) - sm[g2][hd]) * srd[g2][hd];
            uint4 hvA = *(const uint4*)&Hb[srcA * 128 + ch0];
            a0.x = fmaf(aA, bflo(hvA.x), a0.x);
            a0.y = fmaf(aA, bfhi(hvA.x), a0.y);
            a0.z = fmaf(aA, bflo(hvA.y), a0.z);
            a0.w = fmaf(aA, bfhi(hvA.y), a0.w);
            a1.x = fmaf(aA, bflo(hvA.z), a1.x);
            a1.y = fmaf(aA, bfhi(hvA.z), a1.y);
            a1.z = fmaf(aA, bflo(hvA.w), a1.z);
            a1.w = fmaf(aA, bfhi(hvA.w), a1.w);
        }
        a0.x += b0.x; a0.y += b0.y; a0.z += b0.z; a0.w += b0.w;
        a1.x += b1.x; a1.y += b1.y; a1.z += b1.z; a1.w += b1.w;
#pragma unroll
        for (int o = 16; o <= 32; o <<= 1) {
            a0.x += __shfl_xor(a0.x, o, 64);
            a0.y += __shfl_xor(a0.y, o, 64);
            a0.z += __shfl_xor(a0.z, o, 64);
            a0.w += __shfl_xor(a0.w, o, 64);
            a1.x += __shfl_xor(a1.x, o, 64);
            a1.y += __shfl_xor(a1.y, o, 64);
            a1.z += __shfl_xor(a1.z, o, 64);
            a1.w += __shfl_xor(a1.w, o, 64);
        }
        if (slot == 0) {
            float4 c0v = *(const float4*)&bias[ch0];
            float4 c1v = *(const float4*)&bias[ch0 + 4];
            float4 o0, o1;
            o0.x = lrelu(a0.x + c0v.x, LRELU_ACT);
            o0.y = lrelu(a0.y + c0v.y, LRELU_ACT);
            o0.z = lrelu(a0.z + c0v.z, LRELU_ACT);
            o0.w = lrelu(a0.w + c0v.w, LRELU_ACT);
            o1.x = lrelu(a1.x + c1v.x, LRELU_ACT);
            o1.y = lrelu(a1.y + c1v.y, LRELU_ACT);
            o1.z = lrelu(a1.z + c1v.z, LRELU_ACT);
            o1.w = lrelu(a1.w + c1v.w, LRELU_ACT);
            *(float4*)&Out[dst * 128 + ch0] = o0;
            *(float4*)&Out[dst * 128 + ch0 + 4] = o1;
        }
    }
}

// ---------------- graph embedding: segment max over sorted batch ----------------
__global__ void ge_max_k(const float* __restrict__ Hf, const int* __restrict__ batch,
                         float* __restrict__ ge, int n) {
    int c = threadIdx.x & 127;
    int rh = threadIdx.x >> 7;
    int node0 = blockIdx.x * 128;
    int hi = min(node0 + 128, n);
    int gid = -1;
    float mv = -INFINITY;
    for (int r = node0 + rh; r < hi; r += 2) {
        int g = batch[r];
        if (g != gid) {
            if (gid >= 0) atomicMaxF(&ge[gid * 128 + c], mv);
            gid = g;
            mv = -INFINITY;
        }
        mv = fmaxf(mv, Hf[r * 128 + c]);
    }
    if (gid >= 0) atomicMaxF(&ge[gid * 128 + c], mv);
}

__global__ void ei_copy_k(const int* __restrict__ ei, float* __restrict__ out, int m) {
    int i = (blockIdx.x * blockDim.x + threadIdx.x) * 4;
    if (i + 3 < m) {
        int4 v = *(const int4*)&ei[i];
        float4 o = make_float4((float)v.x, (float)v.y, (float)v.z, (float)v.w);
        *(float4*)&out[i] = o;
    } else {
        for (; i < m; i++) out[i] = (float)ei[i];
    }
}

extern "C" void kernel_launch(void* const* d_in, const int* in_sizes, int n_in,
                              void* d_out, int out_size, void* d_ws, size_t ws_size,
                              hipStream_t stream) {
    const float* x = (const float*)d_in[0];
    const int* ei = (const int*)d_in[1];
    const int* batch = (const int*)d_in[2];
    const float* Wm[3]   = {(const float*)d_in[3], (const float*)d_in[7],  (const float*)d_in[11]};
    const float* asrc[3] = {(const float*)d_in[4], (const float*)d_in[8],  (const float*)d_in[12]};
    const float* adst[3] = {(const float*)d_in[5], (const float*)d_in[9],  (const float*)d_in[13]};
    const float* bias[3] = {(const float*)d_in[6], (const float*)d_in[10], (const float*)d_in[14]};

    const int n = in_sizes[2];          // 50000 nodes
    const int E = in_sizes[1] / 2;      // 800000 edges
    const int ne = E + n;               // + self loops
    const int G = (out_size - n * 128 - 2 * E) / 128;  // 64 graphs
    const int NB = (n + 127) >> 7;      // 391 buckets

    // workspace layout
    char* w = (char*)d_ws;
    float* Xact = (float*)w;          w += (size_t)n * 128 * 4;
    unsigned short* Hb = (unsigned short*)w; w += (size_t)n * 128 * 2;
    float* S    = (float*)w; w += (size_t)n * 4 * 4;
    float* D    = (float*)w; w += (size_t)n * 4 * 4;
    int* bcount = (int*)w;   w += NBMAX * 4;
    int* bbase  = (int*)w;   w += (NBMAX + 1) * 4;
    int* cursor = (int*)w;   w += NBMAX * 4;
    int* rowptr = (int*)w;   w += (size_t)(n + 1) * 4;
    unsigned* binned = (unsigned*)w; w += (size_t)E * 4;
    int* csr    = (int*)w;   w += (size_t)ne * 4;

    float* out   = (float*)d_out;
    float* ge    = out;
    float* hout  = out + (size_t)G * 128;
    float* eiout = out + (size_t)G * 128 + (size_t)n * 128;

    // ---- CSR build: binned counting sort ----
    fill_i_k<<<(NBMAX + 255) / 256, 256, 0, stream>>>(bcount, 0, NBMAX);
    bhist_k<<<256, 256, 0, stream>>>(ei, bcount, E);
    bscan_k<<<1, 256, 0, stream>>>(bcount, bbase, cursor, NB);
    bin_scatter_k<<<(E + TILE - 1) / TILE, 256, 0, stream>>>(ei, cursor, binned, E);
    bucket_csr_k<<<NB, 1024, 0, stream>>>(binned, bbase, rowptr, csr, n, NB);

    // ---- 3 GAT layers ----
    const float* xin = x;
    for (int L = 0; L < 3; L++) {
        gemm_k<<<(n + 63) / 64, 256, 0, stream>>>(xin, Wm[L], asrc[L], adst[L], Hb, S, D, n);
        float* xnext = (L == 2) ? hout : Xact;
        attn_agg_k<<<(n + DPB - 1) / DPB, 256, 0, stream>>>(rowptr, csr, S, D, Hb, bias[L], xnext, n);
        xin = xnext;
    }

    // ---- readout ----
    fill_f_k<<<(G * 128 + 255) / 256, 256, 0, stream>>>(ge, -INFINITY, G * 128);
    ge_max_k<<<(n + 127) / 128, 256, 0, stream>>>(hout, batch, ge, n);
    ei_copy_k<<<(2 * E / 4 + 255) / 256, 256, 0, stream>>>(ei, eiout, 2 * E);
}

// Round 11
// 299.120 us; speedup vs baseline: 12.9475x; 1.0314x over previous
//
#include <hip/hip_runtime.h>
#include <math.h>
#include <limits.h>

#define LRELU_ATT 0.2f
#define LRELU_ACT 0.01f
#define CAP 48    // cached alphas per dst in LDS (deg > CAP falls back to recompute)
#define ALST (CAP * 4 + 4)  // padded ushort row stride: 8B-aligned, bank-staggered
#define DPB 16    // dsts per block in attn_agg
#define LCAP 768  // flat per-block src cache entries
#define NBMAX 512 // max buckets (n <= 65536, 128 dsts/bucket)
#define TILE 8192 // edges per bin_scatter block
#define BCAP 6528 // LDS capacity per bucket in bucket_csr (edges + selfs)
#define WPAD 136  // padded K-stride (bf16 elems) for MFMA LDS tiles

typedef __attribute__((ext_vector_type(8))) short bf16x8;
typedef __attribute__((ext_vector_type(4))) float f32x4;

__device__ __forceinline__ float lrelu(float x, float s) { return x > 0.f ? x : x * s; }

__device__ __forceinline__ void atomicMaxF(float* addr, float val) {
    int* ai = (int*)addr;
    int old = *(volatile int*)ai;
    while (__int_as_float(old) < val) {
        int assumed = old;
        old = atomicCAS(ai, assumed, __float_as_int(val));
        if (old == assumed) break;
    }
}

__device__ __forceinline__ unsigned short f2bf(float f) {
    union { float f; unsigned u; } v; v.f = f;
    unsigned r = v.u + 0x7FFF + ((v.u >> 16) & 1);   // RNE
    return (unsigned short)(r >> 16);
}
__device__ __forceinline__ float bf2f(unsigned short u) {
    union { unsigned u; float f; } v; v.u = ((unsigned)u) << 16;
    return v.f;
}
__device__ __forceinline__ float bflo(unsigned u) {
    union { unsigned u; float f; } v; v.u = u << 16;
    return v.f;
}
__device__ __forceinline__ float bfhi(unsigned u) {
    union { unsigned u; float f; } v; v.u = u & 0xffff0000u;
    return v.f;
}

// inclusive scan of 512 ints in LDS; strided for any blockDim.
__device__ __forceinline__ int* scan_incl_512(int* a, int* b, int tid, int nthr) {
    int* in = a; int* out = b;
    for (int off = 1; off < 512; off <<= 1) {
        for (int i = tid; i < 512; i += nthr)
            out[i] = in[i] + (i >= off ? in[i - off] : 0);
        __syncthreads();
        int* t = in; in = out; out = t;
    }
    return in;
}

// ---- MFMA GEMM + fused s/d epilogue: Hb[n,128](bf16) = X@W;  S,D[n,4] ----
__global__ __launch_bounds__(256) void gemm_k(const float* __restrict__ X,
                                              const float* __restrict__ Wm,
                                              const float* __restrict__ a_src,
                                              const float* __restrict__ a_dst,
                                              unsigned short* __restrict__ Hb,
                                              float* __restrict__ S,
                                              float* __restrict__ D, int n) {
    __shared__ unsigned short sWt[128 * WPAD];   // Wt[n][k]
    __shared__ unsigned short sXt[64 * WPAD];    // X[r][k]
    __shared__ float sa[128], sb[128];
    int tid = threadIdx.x;
    if (tid < 128) { sa[tid] = a_src[tid]; sb[tid] = a_dst[tid]; }
    int row0 = blockIdx.x * 64;
#pragma unroll
    for (int i = 0; i < 16; i++) {
        int idx4 = tid + 256 * i;
        int k = idx4 >> 5;
        int n0 = (idx4 & 31) * 4;
        float4 wv = *(const float4*)&Wm[k * 128 + n0];
        sWt[(n0 + 0) * WPAD + k] = f2bf(wv.x);
        sWt[(n0 + 1) * WPAD + k] = f2bf(wv.y);
        sWt[(n0 + 2) * WPAD + k] = f2bf(wv.z);
        sWt[(n0 + 3) * WPAD + k] = f2bf(wv.w);
    }
#pragma unroll
    for (int i = 0; i < 8; i++) {
        int idx4 = tid + 256 * i;
        int r = idx4 >> 5;
        int koff = (idx4 & 31) * 4;
        int gr = row0 + r;
        float4 xv = make_float4(0.f, 0.f, 0.f, 0.f);
        if (gr < n) xv = *(const float4*)&X[gr * 128 + koff];
        ushort4 xb;
        xb.x = f2bf(xv.x); xb.y = f2bf(xv.y); xb.z = f2bf(xv.z); xb.w = f2bf(xv.w);
        *(ushort4*)&sXt[r * WPAD + koff] = xb;
    }
    __syncthreads();
    int w = tid >> 6, l = tid & 63;
    int lr = l & 15, lk = l >> 4;
    f32x4 acc[8];
#pragma unroll
    for (int ct = 0; ct < 8; ct++) acc[ct] = (f32x4){0.f, 0.f, 0.f, 0.f};
#pragma unroll
    for (int ks = 0; ks < 4; ks++) {
        int kbase = ks * 32 + lk * 8;
        bf16x8 afrag = *(const bf16x8*)&sXt[(w * 16 + lr) * WPAD + kbase];
#pragma unroll
        for (int ct = 0; ct < 8; ct++) {
            bf16x8 bfrag = *(const bf16x8*)&sWt[(ct * 16 + lr) * WPAD + kbase];
            acc[ct] = __builtin_amdgcn_mfma_f32_16x16x32_bf16(afrag, bfrag, acc[ct], 0, 0, 0);
        }
    }
    float sp[4][4], dp[4][4];
#pragma unroll
    for (int reg = 0; reg < 4; reg++) {
#pragma unroll
        for (int hd = 0; hd < 4; hd++) {
            int c0 = (2 * hd) * 16 + lr;
            int c1 = (2 * hd + 1) * 16 + lr;
            sp[reg][hd] = acc[2 * hd][reg] * sa[c0] + acc[2 * hd + 1][reg] * sa[c1];
            dp[reg][hd] = acc[2 * hd][reg] * sb[c0] + acc[2 * hd + 1][reg] * sb[c1];
        }
    }
#pragma unroll
    for (int o = 1; o < 16; o <<= 1) {
#pragma unroll
        for (int reg = 0; reg < 4; reg++) {
#pragma unroll
            for (int hd = 0; hd < 4; hd++) {
                sp[reg][hd] += __shfl_xor(sp[reg][hd], o, 64);
                dp[reg][hd] += __shfl_xor(dp[reg][hd], o, 64);
            }
        }
    }
#pragma unroll
    for (int reg = 0; reg < 4; reg++) {
        int gr = row0 + w * 16 + lk * 4 + reg;
        if (gr < n) {
#pragma unroll
            for (int ct = 0; ct < 8; ct++)
                Hb[gr * 128 + ct * 16 + lr] = f2bf(acc[ct][reg]);
            if (lr == 0) {
                *(float4*)&S[gr * 4] = make_float4(sp[reg][0], sp[reg][1], sp[reg][2], sp[reg][3]);
                *(float4*)&D[gr * 4] = make_float4(dp[reg][0], dp[reg][1], dp[reg][2], dp[reg][3]);
            }
        }
    }
}

__global__ void fill_f_k(float* __restrict__ p, float v, int cnt) {
    int i = blockIdx.x * blockDim.x + threadIdx.x;
    if (i < cnt) p[i] = v;
}
__global__ void fill_i_k(int* __restrict__ p, int v, int cnt) {
    int i = blockIdx.x * blockDim.x + threadIdx.x;
    if (i < cnt) p[i] = v;
}

// ---------------- CSR build: binned counting sort ----------------
__global__ void bhist_k(const int* __restrict__ ei, int* __restrict__ bcount, int E) {
    __shared__ int h[NBMAX];
    for (int i = threadIdx.x; i < NBMAX; i += 256) h[i] = 0;
    __syncthreads();
    for (int e = blockIdx.x * blockDim.x + threadIdx.x; e < E; e += gridDim.x * blockDim.x)
        atomicAdd(&h[ei[E + e] >> 7], 1);
    __syncthreads();
    for (int i = threadIdx.x; i < NBMAX; i += 256)
        if (h[i]) atomicAdd(&bcount[i], h[i]);
}

__global__ void bscan_k(const int* __restrict__ bcount, int* __restrict__ bbase,
                        int* __restrict__ cursor, int NB) {
    __shared__ int sa[512], sb[512];
    int tid = threadIdx.x;
    for (int i = tid; i < 512; i += 256) sa[i] = (i < NB) ? bcount[i] : 0;
    __syncthreads();
    int* inc = scan_incl_512(sa, sb, tid, 256);
    for (int i = tid; i < NB; i += 256) {
        int ex = i ? inc[i - 1] : 0;
        bbase[i] = ex;
        cursor[i] = ex;
    }
    if (tid == 0) bbase[NB] = inc[NB - 1];
}

__global__ __launch_bounds__(256) void bin_scatter_k(const int* __restrict__ ei,
                                                     int* __restrict__ cursor,
                                                     unsigned* __restrict__ binned, int E) {
    __shared__ int hist[NBMAX], excl[NBMAX], curl[NBMAX], gbase[NBMAX];
    __shared__ int sa[512], sb[512];
    __shared__ unsigned staged[TILE];
    int tid = threadIdx.x;
    int e0 = blockIdx.x * TILE;
    for (int i = tid; i < NBMAX; i += 256) hist[i] = 0;
    __syncthreads();
    unsigned keys[TILE / 256];
#pragma unroll
    for (int j = 0; j < TILE / 256; j++) {
        int e = e0 + j * 256 + tid;
        if (e < E) {
            unsigned dst = (unsigned)ei[E + e];
            unsigned src = (unsigned)ei[e];
            unsigned k = (dst << 16) | src;
            keys[j] = k;
            atomicAdd(&hist[k >> 23], 1);
        } else keys[j] = 0xFFFFFFFFu;
    }
    __syncthreads();
    for (int i = tid; i < 512; i += 256) sa[i] = hist[i];
    __syncthreads();
    int* inc = scan_incl_512(sa, sb, tid, 256);
    for (int i = tid; i < NBMAX; i += 256) {
        int ex = i ? inc[i - 1] : 0;
        excl[i] = ex;
        curl[i] = ex;
    }
    __syncthreads();
#pragma unroll
    for (int j = 0; j < TILE / 256; j++) {
        unsigned k = keys[j];
        if (k != 0xFFFFFFFFu) {
            int b = k >> 23;
            int p = atomicAdd(&curl[b], 1);
            staged[p] = k;
        }
    }
    __syncthreads();
    for (int i = tid; i < NBMAX; i += 256) {
        int cnt = hist[i];
        if (cnt) gbase[i] = atomicAdd(&cursor[i], cnt);
    }
    __syncthreads();
    int total = inc[511];
    for (int p = tid; p < total; p += 256) {
        unsigned k = staged[p];
        int b = k >> 23;
        binned[gbase[b] + (p - excl[b])] = k;
    }
}

__global__ __launch_bounds__(1024) void bucket_csr_k(const unsigned* __restrict__ binned,
                                                     const int* __restrict__ bbase,
                                                     int* __restrict__ rowptr,
                                                     int* __restrict__ csr,
                                                     int n, int NB) {
    __shared__ int outL[BCAP];
    __shared__ int sa[512], sb[512];
    __shared__ int lbase[129], cur[128];
    int b = blockIdx.x;
    int tid = threadIdx.x;
    int dst0 = b << 7;
    int ndst = min(128, n - dst0);
    int ebase = bbase[b], ecnt = bbase[b + 1] - ebase;
    for (int i = tid; i < 512; i += 1024) sa[i] = (i < ndst) ? 1 : 0;
    __syncthreads();
    for (int p = tid; p < ecnt; p += 1024) {
        int ld = (int)(binned[ebase + p] >> 16) - dst0;
        atomicAdd(&sa[ld], 1);
    }
    __syncthreads();
    int* inc = scan_incl_512(sa, sb, tid, 1024);
    for (int i = tid; i < ndst; i += 1024) {
        int ex = i ? inc[i - 1] : 0;
        lbase[i] = ex;
        cur[i] = ex;
    }
    if (tid == 0) lbase[ndst] = inc[ndst - 1];
    __syncthreads();
    int total = lbase[ndst];
    for (int i = tid; i < ndst; i += 1024) {
        int p = atomicAdd(&cur[i], 1);
        outL[p] = dst0 + i;
    }
    for (int p = tid; p < ecnt; p += 1024) {
        unsigned k = binned[ebase + p];
        int ld = (int)(k >> 16) - dst0;
        int pos = atomicAdd(&cur[ld], 1);
        outL[pos] = (int)(k & 0xFFFFu);
    }
    __syncthreads();
    int w = tid >> 6, lane = tid & 63;
    for (int d = w; d < ndst; d += 16) {
        int st = lbase[d], en = lbase[d + 1];
        int deg = en - st;
        if (deg <= 1) continue;
        if (deg <= 64) {
            int v = (lane < deg) ? outL[st + lane] : INT_MAX;
            int r = 0;
            for (int j = 0; j < deg; j++) {
                int kj = __shfl(v, j, 64);
                r += (kj < v) || (kj == v && j < lane);
            }
            if (lane < deg) outL[st + r] = v;
        } else if (deg <= 128) {
            int v0 = (lane < deg) ? outL[st + lane] : 0;
            int v1 = (64 + lane < deg) ? outL[st + 64 + lane] : 0;
            int r0 = 0, r1 = 0;
            for (int j = 0; j < deg; j++) {
                int kj = outL[st + j];
                r0 += (kj < v0) || (kj == v0 && j < lane);
                r1 += (kj < v1) || (kj == v1 && j < 64 + lane);
            }
            if (lane < deg) outL[st + r0] = v0;
            if (64 + lane < deg) outL[st + r1] = v1;
        } else if (lane == 0) {
            for (int q = st + 1; q < en; q++) {
                int key = outL[q];
                int r = q - 1;
                while (r >= st && outL[r] > key) { outL[r + 1] = outL[r]; r--; }
                outL[r + 1] = key;
            }
        }
    }
    __syncthreads();
    int gb = ebase + dst0;
    for (int p = tid; p < total; p += 1024) csr[gb + p] = outL[p];
    for (int i = tid; i < ndst; i += 1024) rowptr[dst0 + i] = gb + lbase[i];
    if (b == NB - 1 && tid == 0) rowptr[n] = gb + total;
}

// ---- fused softmax + aggregate + bias + act ----
// Phase 0: coalesced preload of the block's contiguous csr range into LDS.
// Phase 1: 8-lane group per dst -> alpha (pre-divided, bf16) in LDS.
// Phase 2: 8-lane slot per dst (8 dsts/wave in parallel), 16 ch/lane,
//          16 independent 16B gathers in flight per wave, no cross-slot reduce.
__global__ __launch_bounds__(128) void attn_agg_k(const int* __restrict__ rowptr,
                                                  const int* __restrict__ csr,
                                                  const float* __restrict__ S,
                                                  const float* __restrict__ Dv,
                                                  const unsigned short* __restrict__ Hb,
                                                  const float* __restrict__ bias,
                                                  float* __restrict__ Out, int n) {
    __shared__ unsigned short al16[DPB][ALST];
    __shared__ int srcs[LCAP];
    __shared__ float sm[DPB][4], srd[DPB][4], sdv[DPB][4];
    __shared__ int srp[DPB + 1];
    int tid = threadIdx.x;
    int base = blockIdx.x * DPB;
    if (tid <= DPB) {
        int idx = base + tid;
        srp[tid] = rowptr[idx > n ? n : idx];
    }
    __syncthreads();
    int st0 = srp[0];
    int etot = srp[DPB] - st0;
    for (int i = tid; i < etot && i < LCAP; i += 128) srcs[i] = csr[st0 + i];
    __syncthreads();

    // ---- phase 1: stats (8-lane group per dst) ----
    {
        int g = tid >> 3;     // 0..15
        int l = tid & 7;
        int dst = base + g;
        if (dst < n) {
            int lst = srp[g] - st0;
            int deg = srp[g + 1] - srp[g];
            float4 dv = *(const float4*)&Dv[dst * 4];
            float4 m = make_float4(-INFINITY, -INFINITY, -INFINITY, -INFINITY);
            for (int pos = l; pos < deg; pos += 8) {
                int idx = lst + pos;
                int src = (idx < LCAP) ? srcs[idx] : csr[st0 + idx];
                float4 sv = *(const float4*)&S[src * 4];
                float4 e;
                e.x = lrelu(sv.x + dv.x, LRELU_ATT);
                e.y = lrelu(sv.y + dv.y, LRELU_ATT);
                e.z = lrelu(sv.z + dv.z, LRELU_ATT);
                e.w = lrelu(sv.w + dv.w, LRELU_ATT);
                if (pos < CAP) {
                    ushort4 eb;
                    eb.x = f2bf(e.x); eb.y = f2bf(e.y); eb.z = f2bf(e.z); eb.w = f2bf(e.w);
                    *(ushort4*)&al16[g][pos * 4] = eb;
                }
                m.x = fmaxf(m.x, e.x); m.y = fmaxf(m.y, e.y);
                m.z = fmaxf(m.z, e.z); m.w = fmaxf(m.w, e.w);
            }
#pragma unroll
            for (int o = 1; o < 8; o <<= 1) {
                m.x = fmaxf(m.x, __shfl_xor(m.x, o, 64));
                m.y = fmaxf(m.y, __shfl_xor(m.y, o, 64));
                m.z = fmaxf(m.z, __shfl_xor(m.z, o, 64));
                m.w = fmaxf(m.w, __shfl_xor(m.w, o, 64));
            }
            float4 den = make_float4(0.f, 0.f, 0.f, 0.f);
            for (int pos = l; pos < deg; pos += 8) {
                float4 e;
                if (pos < CAP) {
                    ushort4 eb = *(const ushort4*)&al16[g][pos * 4];
                    e.x = bf2f(eb.x); e.y = bf2f(eb.y); e.z = bf2f(eb.z); e.w = bf2f(eb.w);
                } else {
                    int idx = lst + pos;
                    int src = (idx < LCAP) ? srcs[idx] : csr[st0 + idx];
                    float4 sv = *(const float4*)&S[src * 4];
                    e.x = lrelu(sv.x + dv.x, LRELU_ATT);
                    e.y = lrelu(sv.y + dv.y, LRELU_ATT);
                    e.z = lrelu(sv.z + dv.z, LRELU_ATT);
                    e.w = lrelu(sv.w + dv.w, LRELU_ATT);
                }
                float4 ex;
                ex.x = __expf(e.x - m.x); ex.y = __expf(e.y - m.y);
                ex.z = __expf(e.z - m.z); ex.w = __expf(e.w - m.w);
                den.x += ex.x; den.y += ex.y; den.z += ex.z; den.w += ex.w;
                if (pos < CAP) {
                    ushort4 xb;
                    xb.x = f2bf(ex.x); xb.y = f2bf(ex.y); xb.z = f2bf(ex.z); xb.w = f2bf(ex.w);
                    *(ushort4*)&al16[g][pos * 4] = xb;
                }
            }
#pragma unroll
            for (int o = 1; o < 8; o <<= 1) {
                den.x += __shfl_xor(den.x, o, 64);
                den.y += __shfl_xor(den.y, o, 64);
                den.z += __shfl_xor(den.z, o, 64);
                den.w += __shfl_xor(den.w, o, 64);
            }
            float4 rd;
            rd.x = 1.f / den.x; rd.y = 1.f / den.y;
            rd.z = 1.f / den.z; rd.w = 1.f / den.w;
            int lim = deg < CAP ? deg : CAP;
            for (int pos = l; pos < lim; pos += 8) {
                ushort4 xb = *(const ushort4*)&al16[g][pos * 4];
                xb.x = f2bf(bf2f(xb.x) * rd.x);
                xb.y = f2bf(bf2f(xb.y) * rd.y);
                xb.z = f2bf(bf2f(xb.z) * rd.z);
                xb.w = f2bf(bf2f(xb.w) * rd.w);
                *(ushort4*)&al16[g][pos * 4] = xb;
            }
            if (l == 0) {
                *(float4*)&sm[g][0] = m;
                *(float4*)&srd[g][0] = rd;
                *(float4*)&sdv[g][0] = dv;
            }
        }
    }
    __syncthreads();

    // ---- phase 2: 8-lane slot per dst, lane owns 16 channels ----
    int w = tid >> 6;            // 0..1
    int lane = tid & 63;
    int s = lane >> 3;           // slot 0..7
    int p = lane & 7;
    int g2 = w * 8 + s;
    int dst = base + g2;
    if (dst >= n) return;
    int lst = srp[g2] - st0;
    int deg = srp[g2 + 1] - srp[g2];
    int ch0 = p * 16;
    int hd = p >> 1;
    float smh = sm[g2][hd], srdh = srd[g2][hd], sdvh = sdv[g2][hd];
    float4 a0 = make_float4(0.f, 0.f, 0.f, 0.f);
    float4 a1 = make_float4(0.f, 0.f, 0.f, 0.f);
    float4 a2 = make_float4(0.f, 0.f, 0.f, 0.f);
    float4 a3 = make_float4(0.f, 0.f, 0.f, 0.f);
    for (int pos = 0; pos < deg; pos++) {
        int idx = lst + pos;
        int src = (idx < LCAP) ? srcs[idx] : csr[st0 + idx];
        float a;
        if (pos < CAP) a = bf2f(al16[g2][pos * 4 + hd]);
        else a = __expf(lrelu(S[src * 4 + hd] + sdvh, LRELU_ATT) - smh) * srdh;
        uint4 hA = *(const uint4*)&Hb[src * 128 + ch0];
        uint4 hB = *(const uint4*)&Hb[src * 128 + ch0 + 8];
        a0.x = fmaf(a, bflo(hA.x), a0.x);
        a0.y = fmaf(a, bfhi(hA.x), a0.y);
        a0.z = fmaf(a, bflo(hA.y), a0.z);
        a0.w = fmaf(a, bfhi(hA.y), a0.w);
        a1.x = fmaf(a, bflo(hA.z), a1.x);
        a1.y = fmaf(a, bfhi(hA.z), a1.y);
        a1.z = fmaf(a, bflo(hA.w), a1.z);
        a1.w = fmaf(a, bfhi(hA.w), a1.w);
        a2.x = fmaf(a, bflo(hB.x), a2.x);
        a2.y = fmaf(a, bfhi(hB.x), a2.y);
        a2.z = fmaf(a, bflo(hB.y), a2.z);
        a2.w = fmaf(a, bfhi(hB.y), a2.w);
        a3.x = fmaf(a, bflo(hB.z), a3.x);
        a3.y = fmaf(a, bfhi(hB.z), a3.y);
        a3.z = fmaf(a, bflo(hB.w), a3.z);
        a3.w = fmaf(a, bfhi(hB.w), a3.w);
    }
    float4 b0 = *(const float4*)&bias[ch0];
    float4 b1 = *(const float4*)&bias[ch0 + 4];
    float4 b2 = *(const float4*)&bias[ch0 + 8];
    float4 b3 = *(const float4*)&bias[ch0 + 12];
    float4 o0, o1, o2, o3;
    o0.x = lrelu(a0.x + b0.x, LRELU_ACT); o0.y = lrelu(a0.y + b0.y, LRELU_ACT);
    o0.z = lrelu(a0.z + b0.z, LRELU_ACT); o0.w = lrelu(a0.w + b0.w, LRELU_ACT);
    o1.x = lrelu(a1.x + b1.x, LRELU_ACT); o1.y = lrelu(a1.y + b1.y, LRELU_ACT);
    o1.z = lrelu(a1.z + b1.z, LRELU_ACT); o1.w = lrelu(a1.w + b1.w, LRELU_ACT);
    o2.x = lrelu(a2.x + b2.x, LRELU_ACT); o2.y = lrelu(a2.y + b2.y, LRELU_ACT);
    o2.z = lrelu(a2.z + b2.z, LRELU_ACT); o2.w = lrelu(a2.w + b2.w, LRELU_ACT);
    o3.x = lrelu(a3.x + b3.x, LRELU_ACT); o3.y = lrelu(a3.y + b3.y, LRELU_ACT);
    o3.z = lrelu(a3.z + b3.z, LRELU_ACT); o3.w = lrelu(a3.w + b3.w, LRELU_ACT);
    float* op = &Out[(size_t)dst * 128 + ch0];
    *(float4*)&op[0] = o0;
    *(float4*)&op[4] = o1;
    *(float4*)&op[8] = o2;
    *(float4*)&op[12] = o3;
}

// ---------------- graph embedding: segment max over sorted batch ----------------
__global__ void ge_max_k(const float* __restrict__ Hf, const int* __restrict__ batch,
                         float* __restrict__ ge, int n) {
    int c = threadIdx.x & 127;
    int rh = threadIdx.x >> 7;
    int node0 = blockIdx.x * 128;
    int hi = min(node0 + 128, n);
    int gid = -1;
    float mv = -INFINITY;
    for (int r = node0 + rh; r < hi; r += 2) {
        int g = batch[r];
        if (g != gid) {
            if (gid >= 0) atomicMaxF(&ge[gid * 128 + c], mv);
            gid = g;
            mv = -INFINITY;
        }
        mv = fmaxf(mv, Hf[r * 128 + c]);
    }
    if (gid >= 0) atomicMaxF(&ge[gid * 128 + c], mv);
}

__global__ void ei_copy_k(const int* __restrict__ ei, float* __restrict__ out, int m) {
    int i = (blockIdx.x * blockDim.x + threadIdx.x) * 4;
    if (i + 3 < m) {
        int4 v = *(const int4*)&ei[i];
        float4 o = make_float4((float)v.x, (float)v.y, (float)v.z, (float)v.w);
        *(float4*)&out[i] = o;
    } else {
        for (; i < m; i++) out[i] = (float)ei[i];
    }
}

extern "C" void kernel_launch(void* const* d_in, const int* in_sizes, int n_in,
                              void* d_out, int out_size, void* d_ws, size_t ws_size,
                              hipStream_t stream) {
    const float* x = (const float*)d_in[0];
    const int* ei = (const int*)d_in[1];
    const int* batch = (const int*)d_in[2];
    const float* Wm[3]   = {(const float*)d_in[3], (const float*)d_in[7],  (const float*)d_in[11]};
    const float* asrc[3] = {(const float*)d_in[4], (const float*)d_in[8],  (const float*)d_in[12]};
    const float* adst[3] = {(const float*)d_in[5], (const float*)d_in[9],  (const float*)d_in[13]};
    const float* bias[3] = {(const float*)d_in[6], (const float*)d_in[10], (const float*)d_in[14]};

    const int n = in_sizes[2];          // 50000 nodes
    const int E = in_sizes[1] / 2;      // 800000 edges
    const int ne = E + n;               // + self loops
    const int G = (out_size - n * 128 - 2 * E) / 128;  // 64 graphs
    const int NB = (n + 127) >> 7;      // 391 buckets

    // workspace layout
    char* w = (char*)d_ws;
    float* Xact = (float*)w;          w += (size_t)n * 128 * 4;
    unsigned short* Hb = (unsigned short*)w; w += (size_t)n * 128 * 2;
    float* S    = (float*)w; w += (size_t)n * 4 * 4;
    float* D    = (float*)w; w += (size_t)n * 4 * 4;
    int* bcount = (int*)w;   w += NBMAX * 4;
    int* bbase  = (int*)w;   w += (NBMAX + 1) * 4;
    int* cursor = (int*)w;   w += NBMAX * 4;
    int* rowptr = (int*)w;   w += (size_t)(n + 1) * 4;
    unsigned* binned = (unsigned*)w; w += (size_t)E * 4;
    int* csr    = (int*)w;   w += (size_t)ne * 4;

    float* out   = (float*)d_out;
    float* ge    = out;
    float* hout  = out + (size_t)G * 128;
    float* eiout = out + (size_t)G * 128 + (size_t)n * 128;

    // ---- CSR build: binned counting sort ----
    fill_i_k<<<(NBMAX + 255) / 256, 256, 0, stream>>>(bcount, 0, NBMAX);
    bhist_k<<<256, 256, 0, stream>>>(ei, bcount, E);
    bscan_k<<<1, 256, 0, stream>>>(bcount, bbase, cursor, NB);
    bin_scatter_k<<<(E + TILE - 1) / TILE, 256, 0, stream>>>(ei, cursor, binned, E);
    bucket_csr_k<<<NB, 1024, 0, stream>>>(binned, bbase, rowptr, csr, n, NB);

    // ---- 3 GAT layers ----
    const float* xin = x;
    for (int L = 0; L < 3; L++) {
        gemm_k<<<(n + 63) / 64, 256, 0, stream>>>(xin, Wm[L], asrc[L], adst[L], Hb, S, D, n);
        float* xnext = (L == 2) ? hout : Xact;
        attn_agg_k<<<(n + DPB - 1) / DPB, 128, 0, stream>>>(rowptr, csr, S, D, Hb, bias[L], xnext, n);
        xin = xnext;
    }

    // ---- readout ----
    fill_f_k<<<(G * 128 + 255) / 256, 256, 0, stream>>>(ge, -INFINITY, G * 128);
    ge_max_k<<<(n + 127) / 128, 256, 0, stream>>>(hout, batch, ge, n);
    ei_copy_k<<<(2 * E / 4 + 255) / 256, 256, 0, stream>>>(ei, eiout, 2 * E);
}